// Round 1
// baseline (3023.984 us; speedup 1.0000x reference)
//
#include <hip/hip_runtime.h>
#include <hip/hip_bf16.h>

// ---------------------------------------------------------------------------
// Sizes
#define SEQ   100
#define BATCH 32
#define NH    4
#define HDIM  128
#define DMODEL 512
#define FLATIN 15873
#define KPAD1  15936        // FLATIN padded to multiple of 64
#define ROWS   3200         // BATCH*SEQ

typedef __attribute__((ext_vector_type(8))) short short8;
typedef __attribute__((ext_vector_type(4))) float f32x4;

__device__ __forceinline__ void gload_lds16(const void* g, void* l) {
  __builtin_amdgcn_global_load_lds((const __attribute__((address_space(1))) void*)g,
                                   (__attribute__((address_space(3))) void*)l, 16, 0, 0);
}

// ---------------------------------------------------------------------------
// bf16 MFMA GEMM, NT layout: C[m,n] = sum_k A[m,k] * W[n,k]  (+bias, opts)
// A: M x K bf16 (lda=K), W: N x K bf16 (ldb=K). M%128==0, N%128==0, K%64==0.
// grid = (N/128, M/128), block = 256 (4 waves, 2x2 wave grid, 64x64 per wave).
// TRPE: remap output row m=b*100+s -> s*32+b and add pe[s][n] (needs ldc=512).
template<int RELU, int TRPE, int OF32, int OB16>
__global__ __launch_bounds__(256)
void gemm_bf16(const __hip_bfloat16* __restrict__ A, const __hip_bfloat16* __restrict__ W,
               const float* __restrict__ bias, const float* __restrict__ pe,
               float* __restrict__ Cf, __hip_bfloat16* __restrict__ Cb,
               int K, int ldc)
{
  __shared__ __align__(16) short lds[16384];     // As 128x64 | Bs 128x64 (32KB)
  short* As = lds;
  short* Bs = lds + 8192;
  const int tid  = threadIdx.x;
  const int lane = tid & 63;
  const int wid  = tid >> 6;
  const int m0 = blockIdx.y << 7;
  const int n0 = blockIdx.x << 7;
  const int wr = (wid >> 1) << 6;
  const int wc = (wid & 1) << 6;

  f32x4 acc[4][4];
#pragma unroll
  for (int i = 0; i < 4; ++i)
#pragma unroll
    for (int j = 0; j < 4; ++j) acc[i][j] = (f32x4){0.f, 0.f, 0.f, 0.f};

  const int srow = (wid << 3) + (lane >> 3);   // 0..31 (row within 32-row group)
  const int scs  = lane & 7;                   // LDS slot (16B chunk) within row-half

  for (int k0 = 0; k0 < K; k0 += 64) {
    __syncthreads();
#pragma unroll
    for (int j = 0; j < 4; ++j) {
      const int row  = (j << 5) + srow;                  // 0..127
      // LDS dest is linear (base + lane*16). Slot (row,scs) must hold global
      // chunk (scs ^ (row&7)) so that swizzled reads below are conflict-light.
      const int gcol = ((scs ^ (row & 7)) << 3);         // bf16 col offset
      const __hip_bfloat16* ga = A + (size_t)(m0 + row) * K + (k0 + gcol);
      const __hip_bfloat16* gb = W + (size_t)(n0 + row) * K + (k0 + gcol);
      short* la = As + (((j << 2) + wid) << 9);          // wave-uniform base
      short* lb = Bs + (((j << 2) + wid) << 9);
      gload_lds16(ga, la);
      gload_lds16(gb, lb);
    }
    __syncthreads();
#pragma unroll
    for (int kk = 0; kk < 2; ++kk) {
      short8 af[4], bfv[4];
#pragma unroll
      for (int i = 0; i < 4; ++i) {
        const int mr = wr + (i << 4) + (lane & 15);
        const int cg = (kk << 2) + (lane >> 4);
        af[i]  = *(const short8*)(As + mr * 64 + ((cg ^ (mr & 7)) << 3));
        const int nr = wc + (i << 4) + (lane & 15);
        bfv[i] = *(const short8*)(Bs + nr * 64 + ((cg ^ (nr & 7)) << 3));
      }
#pragma unroll
      for (int i = 0; i < 4; ++i)
#pragma unroll
        for (int j = 0; j < 4; ++j)
          acc[i][j] = __builtin_amdgcn_mfma_f32_16x16x32_bf16(af[i], bfv[j], acc[i][j], 0, 0, 0);
    }
  }

  // epilogue: C/D mapping col = lane&15, row = (lane>>4)*4 + r   [m89/m91]
  const int fr = lane & 15, fq = lane >> 4;
#pragma unroll
  for (int j = 0; j < 4; ++j) {
    const int n = n0 + wc + (j << 4) + fr;
    const float bb = bias[n];
#pragma unroll
    for (int i = 0; i < 4; ++i) {
#pragma unroll
      for (int r = 0; r < 4; ++r) {
        const int m = m0 + wr + (i << 4) + (fq << 2) + r;
        float v = acc[i][j][r] + bb;
        if (RELU) v = fmaxf(v, 0.f);
        int orow = m;
        if (TRPE) {
          const int s = m % 100, bidx = m / 100;
          orow = s * 32 + bidx;
          v += pe[s * 512 + n];
        }
        if (OF32) Cf[(size_t)orow * ldc + n] = v;
        if (OB16) Cb[(size_t)orow * ldc + n] = __float2bfloat16(v);
      }
    }
  }
}

// ---------------------------------------------------------------------------
// x (B,S,143,111) fp32 -> xb (3200 x 15936) bf16 (zero pad), nz[b*S+s] flag
__global__ __launch_bounds__(256)
void conv_x_kernel(const float* __restrict__ x, __hip_bfloat16* __restrict__ xb,
                   int* __restrict__ nz)
{
  __shared__ int sred[4];
  const int m = blockIdx.x;
  const float* src = x + (size_t)m * FLATIN;
  __hip_bfloat16* dst = xb + (size_t)m * KPAD1;
  int any = 0;
  for (int i = threadIdx.x; i < KPAD1; i += 256) {
    float v = (i < FLATIN) ? src[i] : 0.f;
    any |= (v != 0.f) ? 1 : 0;
    dst[i] = __float2bfloat16(v);
  }
  any = __any(any) ? 1 : 0;
  if ((threadIdx.x & 63) == 0) sred[threadIdx.x >> 6] = any;
  __syncthreads();
  if (threadIdx.x == 0) nz[m] = sred[0] | sred[1] | sred[2] | sred[3];
}

// padding[b,s] = (s>0) && !any(nz[b,k] for k>=s)
__global__ void mask_kernel(const int* __restrict__ nz, int* __restrict__ pad)
{
  const int b = threadIdx.x;
  if (b >= 32) return;
  int any = 0;
  for (int s = 99; s >= 0; --s) {
    any |= nz[b * 100 + s];
    pad[b * 100 + s] = (s > 0 && !any) ? 1 : 0;
  }
}

__global__ void pe_kernel(float* __restrict__ pe)
{
  const int i = blockIdx.x * 256 + threadIdx.x;
  if (i >= SEQ * 512) return;
  const int s = i >> 9, d = i & 511;
  const int d2 = d >> 1;
  const float div = expf((float)(2 * d2) * (-logf(10000.f) / 512.f));
  const float arg = (float)s * div;
  pe[i] = (d & 1) ? cosf(arg) : sinf(arg);
}

// fp32 -> bf16, optional column pad (cout >= cin, pad cols are 0)
__global__ __launch_bounds__(256)
void cvt_pad_kernel(const float* __restrict__ in, __hip_bfloat16* __restrict__ out,
                    int cin, int cout)
{
  const int c = blockIdx.x * 256 + threadIdx.x;
  const int r = blockIdx.y;
  if (c >= cout) return;
  const float v = (c < cin) ? in[(size_t)r * cin + c] : 0.f;
  out[(size_t)r * cout + c] = __float2bfloat16(v);
}

__global__ void fill_kernel(float* __restrict__ p, int n, float v)
{
  const int i = blockIdx.x * 256 + threadIdx.x;
  if (i < n) p[i] = v;
}

// ---------------------------------------------------------------------------
// LayerNorm over D=512: y = LN(x (+res)) * g + b ; rows = grid.x, block = 256
__global__ __launch_bounds__(256)
void ln_kernel(const float* __restrict__ x, const float* __restrict__ res,
               const float* __restrict__ g, const float* __restrict__ bta,
               float* __restrict__ y, __hip_bfloat16* __restrict__ yb)
{
  __shared__ float rs[4], rss[4];
  const int row = blockIdx.x;
  const int t = threadIdx.x;
  const size_t base = (size_t)row * 512;
  float v0 = x[base + t];
  float v1 = x[base + t + 256];
  if (res) { v0 += res[base + t]; v1 += res[base + t + 256]; }
  float s = v0 + v1, ss = v0 * v0 + v1 * v1;
#pragma unroll
  for (int o = 32; o > 0; o >>= 1) { s += __shfl_xor(s, o); ss += __shfl_xor(ss, o); }
  if ((t & 63) == 0) { rs[t >> 6] = s; rss[t >> 6] = ss; }
  __syncthreads();
  s = rs[0] + rs[1] + rs[2] + rs[3];
  ss = rss[0] + rss[1] + rss[2] + rss[3];
  const float mean = s * (1.f / 512.f);
  const float var = ss * (1.f / 512.f) - mean * mean;
  const float inv = rsqrtf(var + 1e-5f);
  const float o0 = (v0 - mean) * inv * g[t] + bta[t];
  const float o1 = (v1 - mean) * inv * g[t + 256] + bta[t + 256];
  y[base + t] = o0;
  y[base + t + 256] = o1;
  if (yb) {
    yb[base + t] = __float2bfloat16(o0);
    yb[base + t + 256] = __float2bfloat16(o1);
  }
}

// ---------------------------------------------------------------------------
// Encoder self-attention. qkv: (3200 rows = s*32+b, 1536) fp32: q|k|v blocks.
// grid = (128 = b*4+h, 4 q-chunks), block 256. Output ob bf16 (3200 x 512).
__global__ __launch_bounds__(256)
void enc_attn_kernel(const float* __restrict__ qkv, const int* __restrict__ pad,
                     __hip_bfloat16* __restrict__ ob)
{
  __shared__ float Ks[100][129];      // +1 pad: conflict-free column reads
  __shared__ float Qs[128];
  __shared__ float Ps[100];
  __shared__ float red[4];
  const int bh = blockIdx.x;
  const int b = bh >> 2, h = bh & 3;
  const int q0 = blockIdx.y * 25;
  const int t = threadIdx.x;
  for (int i = t; i < 12800; i += 256) {
    const int s = i >> 7, d = i & 127;
    Ks[s][d] = qkv[(size_t)(s * 32 + b) * 1536 + 512 + h * 128 + d];
  }
  const int masked = (t < 100) ? pad[b * 100 + t] : 0;
  const float scale = 0.08838834764831845f;   // 1/sqrt(128)
  for (int qi = 0; qi < 25; ++qi) {
    const int q = q0 + qi;
    __syncthreads();                              // prev iter done (also covers K staging)
    if (t < 128) Qs[t] = qkv[(size_t)(q * 32 + b) * 1536 + h * 128 + t];
    __syncthreads();
    float sc = -3e38f;
    if (t < 100) {
      const float* kr = &Ks[t][0];
      float a = 0.f;
#pragma unroll 16
      for (int d = 0; d < 128; ++d) a += Qs[d] * kr[d];
      sc = masked ? -1e9f : (a * scale);
    }
    float mx = sc;
#pragma unroll
    for (int o = 32; o > 0; o >>= 1) mx = fmaxf(mx, __shfl_xor(mx, o));
    if ((t & 63) == 0) red[t >> 6] = mx;
    __syncthreads();
    mx = fmaxf(fmaxf(red[0], red[1]), fmaxf(red[2], red[3]));
    const float e = (t < 100) ? expf(sc - mx) : 0.f;
    float sm = e;
#pragma unroll
    for (int o = 32; o > 0; o >>= 1) sm += __shfl_xor(sm, o);
    __syncthreads();
    if ((t & 63) == 0) red[t >> 6] = sm;
    __syncthreads();
    sm = red[0] + red[1] + red[2] + red[3];
    if (t < 100) Ps[t] = e;
    __syncthreads();
    if (t < 128) {
      float a = 0.f;
      const float* vb = qkv + 1024 + h * 128 + t;
      for (int k = 0; k < 100; ++k) a += Ps[k] * vb[(size_t)(k * 32 + b) * 1536];
      ob[(size_t)(q * 32 + b) * 512 + h * 128 + t] = __float2bfloat16(a / sm);
    }
  }
}

// Decoder cross-attention (Sq=1). qd: (32 x 512) fp32. kv: (3200 x 1024) k|v.
// grid = 128 (b*4+h), block 256. ca: (32 x 512) fp32.
__global__ __launch_bounds__(256)
void dec_attn_kernel(const float* __restrict__ qd, const float* __restrict__ kv,
                     float* __restrict__ ca)
{
  __shared__ float Qs[128];
  __shared__ float Ps[100];
  __shared__ float red[4];
  const int bh = blockIdx.x;
  const int b = bh >> 2, h = bh & 3;
  const int t = threadIdx.x;
  if (t < 128) Qs[t] = qd[b * 512 + h * 128 + t];
  __syncthreads();
  float sc = -3e38f;
  if (t < 100) {
    const float* kr = kv + (size_t)(t * 32 + b) * 1024 + h * 128;
    float a = 0.f;
#pragma unroll 16
    for (int d = 0; d < 128; ++d) a += Qs[d] * kr[d];
    sc = a * 0.08838834764831845f;
  }
  float mx = sc;
#pragma unroll
  for (int o = 32; o > 0; o >>= 1) mx = fmaxf(mx, __shfl_xor(mx, o));
  if ((t & 63) == 0) red[t >> 6] = mx;
  __syncthreads();
  mx = fmaxf(fmaxf(red[0], red[1]), fmaxf(red[2], red[3]));
  const float e = (t < 100) ? expf(sc - mx) : 0.f;
  float sm = e;
#pragma unroll
  for (int o = 32; o > 0; o >>= 1) sm += __shfl_xor(sm, o);
  __syncthreads();
  if ((t & 63) == 0) red[t >> 6] = sm;
  __syncthreads();
  sm = red[0] + red[1] + red[2] + red[3];
  if (t < 100) Ps[t] = e;
  __syncthreads();
  if (t < 128) {
    float a = 0.f;
    const float* vb = kv + 512 + h * 128 + t;
    for (int k = 0; k < 100; ++k) a += Ps[k] * vb[(size_t)(k * 32 + b) * 1024];
    ca[b * 512 + h * 128 + t] = a / sm;
  }
}

// ---------------------------------------------------------------------------
// Small fp32 GEMM, M=32 fixed: C(32,N) = A(32,K) @ W(N,K)^T + bias [, relu]
// block 256: lane->n (64 per block), wave->8 m-rows. A reads are wave-uniform
// (readfirstlane -> s_load), W reads per-lane contiguous float4.
template<int RELU>
__global__ __launch_bounds__(256)
void sgemm32(const float* __restrict__ A, const float* __restrict__ W,
             const float* __restrict__ bias, float* __restrict__ C, int N, int K)
{
  const int t = threadIdx.x;
  const int n = t & 63;
  const int mg = __builtin_amdgcn_readfirstlane(t >> 6);
  const int gn = blockIdx.x * 64 + n;
  const size_t wrow = (gn < N) ? (size_t)gn : 0;
  const float4* wp = (const float4*)(W + wrow * K);
  const float* Abase = A + (size_t)mg * 8 * K;
  float acc[8] = {0.f, 0.f, 0.f, 0.f, 0.f, 0.f, 0.f, 0.f};
  const int nk4 = K >> 2;
  for (int k4 = 0; k4 < nk4; ++k4) {
    const float4 wv = wp[k4];
#pragma unroll
    for (int i = 0; i < 8; ++i) {
      const float4 av = *(const float4*)(Abase + (size_t)i * K + k4 * 4);
      acc[i] += av.x * wv.x + av.y * wv.y + av.z * wv.z + av.w * wv.w;
    }
  }
  if (gn < N) {
    const float bb = bias[gn];
#pragma unroll
    for (int i = 0; i < 8; ++i) {
      float v = acc[i] + bb;
      if (RELU) v = fmaxf(v, 0.f);
      C[(size_t)(mg * 8 + i) * N + gn] = v;
    }
  }
}

// ---------------------------------------------------------------------------
// Adaptive avg pool (143,111) -> (135,103), fp32
__global__ __launch_bounds__(256)
void pool_kernel(const float* __restrict__ o3, float* __restrict__ out)
{
  const int i = blockIdx.x * 256 + threadIdx.x;
  if (i >= 32 * 135 * 103) return;
  const int j = i % 103;
  const int tmp = i / 103;
  const int r = tmp % 135;
  const int b = tmp / 135;
  const int rs = (r * 143) / 135, re = ((r + 1) * 143 + 134) / 135;
  const int cs = (j * 111) / 103, ce = ((j + 1) * 111 + 102) / 103;
  float s = 0.f;
  for (int rr = rs; rr < re; ++rr)
    for (int cc = cs; cc < ce; ++cc)
      s += o3[(size_t)b * FLATIN + rr * 111 + cc];
  out[i] = s / (float)((re - rs) * (ce - cs));
}

// ---------------------------------------------------------------------------
extern "C" void kernel_launch(void* const* d_in, const int* in_sizes, int n_in,
                              void* d_out, int out_size, void* d_ws, size_t ws_size,
                              hipStream_t stream)
{
  (void)in_sizes; (void)n_in; (void)out_size; (void)ws_size;

  const float* x          = (const float*)d_in[0];
  const float* fc1_w      = (const float*)d_in[1];
  const float* fc1_b      = (const float*)d_in[2];
  const float* fc2_w      = (const float*)d_in[3];
  const float* fc2_b      = (const float*)d_in[4];
  const float* fc3_w      = (const float*)d_in[5];
  const float* fc3_b      = (const float*)d_in[6];
  const float* out1_w     = (const float*)d_in[7];
  const float* out1_b     = (const float*)d_in[8];
  const float* out2_w     = (const float*)d_in[9];
  const float* out2_b     = (const float*)d_in[10];
  const float* out3_w     = (const float*)d_in[11];
  const float* out3_b     = (const float*)d_in[12];
  const float* enc_qkv_w  = (const float*)d_in[13];
  const float* enc_qkv_b  = (const float*)d_in[14];
  const float* enc_proj_w = (const float*)d_in[15];
  const float* enc_proj_b = (const float*)d_in[16];
  const float* enc_ff1_w  = (const float*)d_in[17];
  const float* enc_ff1_b  = (const float*)d_in[18];
  const float* enc_ff2_w  = (const float*)d_in[19];
  const float* enc_ff2_b  = (const float*)d_in[20];
  const float* enc_ln1_g  = (const float*)d_in[21];
  const float* enc_ln1_b  = (const float*)d_in[22];
  const float* enc_ln2_g  = (const float*)d_in[23];
  const float* enc_ln2_b  = (const float*)d_in[24];
  const float* enc_lnf_g  = (const float*)d_in[25];
  const float* enc_lnf_b  = (const float*)d_in[26];
  const float* dec_sa_qkv_w  = (const float*)d_in[27];
  const float* dec_sa_qkv_b  = (const float*)d_in[28];
  const float* dec_sa_proj_w = (const float*)d_in[29];
  const float* dec_sa_proj_b = (const float*)d_in[30];
  const float* dec_ca_qkv_w  = (const float*)d_in[31];
  const float* dec_ca_qkv_b  = (const float*)d_in[32];
  const float* dec_ca_proj_w = (const float*)d_in[33];
  const float* dec_ca_proj_b = (const float*)d_in[34];
  const float* dec_ff1_w  = (const float*)d_in[35];
  const float* dec_ff1_b  = (const float*)d_in[36];
  const float* dec_ff2_w  = (const float*)d_in[37];
  const float* dec_ff2_b  = (const float*)d_in[38];
  const float* dec_ln1_g  = (const float*)d_in[39];
  const float* dec_ln1_b  = (const float*)d_in[40];
  const float* dec_ln2_g  = (const float*)d_in[41];
  const float* dec_ln2_b  = (const float*)d_in[42];
  const float* dec_ln3_g  = (const float*)d_in[43];
  const float* dec_ln3_b  = (const float*)d_in[44];
  const float* dec_lnf_g  = (const float*)d_in[45];
  const float* dec_lnf_b  = (const float*)d_in[46];

  char* wsp = (char*)d_ws;
  size_t off = 0;
  auto alloc = [&](size_t nbytes) -> char* {
    char* p = wsp + off;
    off += (nbytes + 255) & ~(size_t)255;
    return p;
  };

  __hip_bfloat16* xb     = (__hip_bfloat16*)alloc((size_t)ROWS * KPAD1 * 2);
  __hip_bfloat16* Wb1    = (__hip_bfloat16*)alloc((size_t)4096 * KPAD1 * 2);
  __hip_bfloat16* Wb2    = (__hip_bfloat16*)alloc((size_t)2048 * 4096 * 2);
  __hip_bfloat16* Wb3    = (__hip_bfloat16*)alloc((size_t)512 * 2048 * 2);
  __hip_bfloat16* Wqkvb  = (__hip_bfloat16*)alloc((size_t)2 * 1536 * 512 * 2);
  __hip_bfloat16* Wprojb = (__hip_bfloat16*)alloc((size_t)2 * 512 * 512 * 2);
  __hip_bfloat16* Wff1b  = (__hip_bfloat16*)alloc((size_t)2 * 1024 * 512 * 2);
  __hip_bfloat16* Wff2b  = (__hip_bfloat16*)alloc((size_t)2 * 512 * 1024 * 2);
  __hip_bfloat16* Wdkvb  = (__hip_bfloat16*)alloc((size_t)2 * 1536 * 512 * 2);
  int*   nz      = (int*)alloc(ROWS * 4);
  int*   padmask = (int*)alloc(ROWS * 4);
  float* pe      = (float*)alloc((size_t)SEQ * 512 * 4);
  __hip_bfloat16* h1b = (__hip_bfloat16*)alloc((size_t)ROWS * 4096 * 2);
  __hip_bfloat16* h2b = (__hip_bfloat16*)alloc((size_t)ROWS * 2048 * 2);
  float* hf  = (float*)alloc((size_t)ROWS * 512 * 4);
  __hip_bfloat16* hb = (__hip_bfloat16*)alloc((size_t)ROWS * 512 * 2);
  float* qkvbuf = (float*)alloc((size_t)ROWS * 1536 * 4);
  __hip_bfloat16* attnb = (__hip_bfloat16*)alloc((size_t)ROWS * 512 * 2);
  float* pjf  = (float*)alloc((size_t)ROWS * 512 * 4);
  __hip_bfloat16* f1b = (__hip_bfloat16*)alloc((size_t)ROWS * 1024 * 2);
  float* f2f  = (float*)alloc((size_t)ROWS * 512 * 4);
  float* memf = (float*)alloc((size_t)ROWS * 512 * 4);
  __hip_bfloat16* memb = (__hip_bfloat16*)alloc((size_t)ROWS * 512 * 2);
  float* kvbuf = (float*)alloc((size_t)ROWS * 1024 * 4);
  float* tbuf = (float*)alloc(32 * 512 * 4);
  float* tv   = (float*)alloc(32 * 512 * 4);
  float* so   = (float*)alloc(32 * 512 * 4);
  float* qdv  = (float*)alloc(32 * 512 * 4);
  float* cav  = (float*)alloc(32 * 512 * 4);
  float* cov  = (float*)alloc(32 * 512 * 4);
  float* tf1  = (float*)alloc(32 * 1024 * 4);
  float* tf2  = (float*)alloc(32 * 512 * 4);
  float* o1   = (float*)alloc(32 * 2048 * 4);
  float* o2   = (float*)alloc(32 * 4096 * 4);
  float* o3   = (float*)alloc((size_t)32 * FLATIN * 4);

  // ---- phase 0: conversions, mask, PE ----
  conv_x_kernel<<<ROWS, 256, 0, stream>>>(x, xb, nz);
  mask_kernel<<<1, 64, 0, stream>>>(nz, padmask);
  pe_kernel<<<(SEQ * 512 + 255) / 256, 256, 0, stream>>>(pe);

  auto cvt = [&](const float* in, __hip_bfloat16* out, int rows, int cin, int cout) {
    cvt_pad_kernel<<<dim3((cout + 255) / 256, rows), 256, 0, stream>>>(in, out, cin, cout);
  };
  cvt(fc1_w, Wb1, 4096, FLATIN, KPAD1);
  cvt(fc2_w, Wb2, 2048, 4096, 4096);
  cvt(fc3_w, Wb3, 512, 2048, 2048);
  cvt(enc_qkv_w, Wqkvb, 2 * 1536, 512, 512);
  cvt(enc_proj_w, Wprojb, 2 * 512, 512, 512);
  cvt(enc_ff1_w, Wff1b, 2 * 1024, 512, 512);
  cvt(enc_ff2_w, Wff2b, 2 * 512, 1024, 1024);
  cvt(dec_ca_qkv_w, Wdkvb, 2 * 1536, 512, 512);

  // ---- phase 1: input MLP ----
  gemm_bf16<1, 0, 0, 1><<<dim3(32, 25), 256, 0, stream>>>(xb, Wb1, fc1_b, nullptr, nullptr, h1b, KPAD1, 4096);
  gemm_bf16<1, 0, 0, 1><<<dim3(16, 25), 256, 0, stream>>>(h1b, Wb2, fc2_b, nullptr, nullptr, h2b, 4096, 2048);
  gemm_bf16<1, 1, 1, 1><<<dim3(4, 25), 256, 0, stream>>>(h2b, Wb3, fc3_b, pe, hf, hb, 2048, 512);

  // ---- phase 2: encoder ----
  for (int L = 0; L < 2; ++L) {
    gemm_bf16<0, 0, 1, 0><<<dim3(12, 25), 256, 0, stream>>>(
        hb, Wqkvb + (size_t)L * 1536 * 512, enc_qkv_b + L * 1536, nullptr, qkvbuf, nullptr, 512, 1536);
    enc_attn_kernel<<<dim3(128, 4), 256, 0, stream>>>(qkvbuf, padmask, attnb);
    gemm_bf16<0, 0, 1, 0><<<dim3(4, 25), 256, 0, stream>>>(
        attnb, Wprojb + (size_t)L * 512 * 512, enc_proj_b + L * 512, nullptr, pjf, nullptr, 512, 512);
    ln_kernel<<<ROWS, 256, 0, stream>>>(hf, pjf, enc_ln1_g + L * 512, enc_ln1_b + L * 512, hf, hb);
    gemm_bf16<1, 0, 0, 1><<<dim3(8, 25), 256, 0, stream>>>(
        hb, Wff1b + (size_t)L * 1024 * 512, enc_ff1_b + L * 1024, nullptr, nullptr, f1b, 512, 1024);
    gemm_bf16<0, 0, 1, 0><<<dim3(4, 25), 256, 0, stream>>>(
        f1b, Wff2b + (size_t)L * 512 * 1024, enc_ff2_b + L * 512, nullptr, f2f, nullptr, 1024, 512);
    ln_kernel<<<ROWS, 256, 0, stream>>>(hf, f2f, enc_ln2_g + L * 512, enc_ln2_b + L * 512, hf, hb);
  }
  ln_kernel<<<ROWS, 256, 0, stream>>>(hf, nullptr, enc_lnf_g, enc_lnf_b, memf, memb);

  // ---- phase 3: decoder (Sq=1; self-attn softmax over 1 key == 1 -> out=V) ----
  fill_kernel<<<(32 * 512 + 255) / 256, 256, 0, stream>>>(tbuf, 32 * 512, 1.0f);
  for (int L = 0; L < 2; ++L) {
    sgemm32<0><<<8, 256, 0, stream>>>(tbuf, dec_sa_qkv_w + (size_t)L * 1536 * 512 + (size_t)1024 * 512,
                                      dec_sa_qkv_b + L * 1536 + 1024, tv, 512, 512);
    sgemm32<0><<<8, 256, 0, stream>>>(tv, dec_sa_proj_w + (size_t)L * 512 * 512,
                                      dec_sa_proj_b + L * 512, so, 512, 512);
    ln_kernel<<<32, 256, 0, stream>>>(tbuf, so, dec_ln1_g + L * 512, dec_ln1_b + L * 512, tbuf, nullptr);

    sgemm32<0><<<8, 256, 0, stream>>>(tbuf, dec_ca_qkv_w + (size_t)L * 1536 * 512,
                                      dec_ca_qkv_b + L * 1536, qdv, 512, 512);
    gemm_bf16<0, 0, 1, 0><<<dim3(8, 25), 256, 0, stream>>>(
        memb, Wdkvb + ((size_t)L * 1536 + 512) * 512, dec_ca_qkv_b + L * 1536 + 512,
        nullptr, kvbuf, nullptr, 512, 1024);
    dec_attn_kernel<<<128, 256, 0, stream>>>(qdv, kvbuf, cav);
    sgemm32<0><<<8, 256, 0, stream>>>(cav, dec_ca_proj_w + (size_t)L * 512 * 512,
                                      dec_ca_proj_b + L * 512, cov, 512, 512);
    ln_kernel<<<32, 256, 0, stream>>>(tbuf, cov, dec_ln2_g + L * 512, dec_ln2_b + L * 512, tbuf, nullptr);

    sgemm32<1><<<16, 256, 0, stream>>>(tbuf, dec_ff1_w + (size_t)L * 1024 * 512,
                                       dec_ff1_b + L * 1024, tf1, 1024, 512);
    sgemm32<0><<<8, 256, 0, stream>>>(tf1, dec_ff2_w + (size_t)L * 512 * 1024,
                                      dec_ff2_b + L * 512, tf2, 512, 1024);
    ln_kernel<<<32, 256, 0, stream>>>(tbuf, tf2, dec_ln3_g + L * 512, dec_ln3_b + L * 512, tbuf, nullptr);
  }
  ln_kernel<<<32, 256, 0, stream>>>(tbuf, nullptr, dec_lnf_g, dec_lnf_b, tbuf, nullptr);

  // ---- phase 4: output MLP + pool ----
  sgemm32<1><<<32, 256, 0, stream>>>(tbuf, out1_w, out1_b, o1, 2048, 512);
  sgemm32<1><<<64, 256, 0, stream>>>(o1, out2_w, out2_b, o2, 4096, 2048);
  sgemm32<1><<<249, 256, 0, stream>>>(o2, out3_w, out3_b, o3, FLATIN, 4096);
  pool_kernel<<<(32 * 135 * 103 + 255) / 256, 256, 0, stream>>>(o3, (float*)d_out);
}

// Round 2
// 3018.670 us; speedup vs baseline: 1.0018x; 1.0018x over previous
//
#include <hip/hip_runtime.h>
#include <hip/hip_bf16.h>

// ---------------------------------------------------------------------------
// Sizes
#define SEQ   100
#define BATCH 32
#define NH    4
#define HDIM  128
#define DMODEL 512
#define FLATIN 15873
#define KPAD1  15936        // FLATIN padded to multiple of 64
#define ROWS   3200         // BATCH*SEQ
#define MPAD   3328         // ROWS (+1 zero row) padded to multiple of 128

typedef __attribute__((ext_vector_type(8))) short short8;
typedef __attribute__((ext_vector_type(4))) float f32x4;

__device__ __forceinline__ void gload_lds16(const void* g, void* l) {
  __builtin_amdgcn_global_load_lds((const __attribute__((address_space(1))) void*)g,
                                   (__attribute__((address_space(3))) void*)l, 16, 0, 0);
}

// bijective XCD chunk swizzle (m204): consecutive output ids land on one XCD
__device__ __forceinline__ int xcd_swizzle(int id, int nwg) {
  const int q = nwg >> 3, r = nwg & 7;
  const int x = id & 7, p = id >> 3;
  return (x < r ? x * (q + 1) : r * (q + 1) + (x - r) * q) + p;
}

// ---------------------------------------------------------------------------
// bf16 MFMA GEMM, NT layout: C[m,n] = sum_k A[m,k] * W[n,k]  (+bias, opts)
// A: M x K bf16 (lda=K), W: N x K bf16 (ldb=K). K%64==0.
// grid = 1-D (mtiles*ntile), block = 256 (4 waves, 2x2, 64x64 per wave).
// GATHER: A row = idx[m0+row].  cnt: early-exit blocks with m0 >= *cnt.
// Block id linearized A-panel-major (consecutive ids share the A panel).
template<int RELU, int GATHER, int OF32, int OB16>
__global__ __launch_bounds__(256)
void gemm_bf16(const __hip_bfloat16* __restrict__ A, const __hip_bfloat16* __restrict__ W,
               const float* __restrict__ bias, const int* __restrict__ idx,
               const int* __restrict__ cnt,
               float* __restrict__ Cf, __hip_bfloat16* __restrict__ Cb,
               int K, int ldc, int ntile)
{
  __shared__ __align__(16) short lds[16384];     // As 128x64 | Bs 128x64 (32KB)
  short* As = lds;
  short* Bs = lds + 8192;
  const int wg = xcd_swizzle(blockIdx.x, gridDim.x);
  const int m0 = (wg / ntile) << 7;
  const int n0 = (wg % ntile) << 7;
  if (cnt && m0 >= cnt[0]) return;

  const int tid  = threadIdx.x;
  const int lane = tid & 63;
  const int wid  = tid >> 6;
  const int wr = (wid >> 1) << 6;
  const int wc = (wid & 1) << 6;

  f32x4 acc[4][4];
#pragma unroll
  for (int i = 0; i < 4; ++i)
#pragma unroll
    for (int j = 0; j < 4; ++j) acc[i][j] = (f32x4){0.f, 0.f, 0.f, 0.f};

  const int srow = (wid << 3) + (lane >> 3);   // 0..31
  const int scs  = lane & 7;                   // 16B chunk slot
  // (j<<5) ≡ 0 mod 8, so the XOR column depends only on srow
  const int gcol = ((scs ^ (srow & 7)) << 3);  // bf16 col offset of this lane's chunk

  const __hip_bfloat16* arow[4];
  const __hip_bfloat16* brow[4];
#pragma unroll
  for (int j = 0; j < 4; ++j) {
    const int row = (j << 5) + srow;
    const int gr = GATHER ? idx[m0 + row] : (m0 + row);
    arow[j] = A + (size_t)gr * K + gcol;
    brow[j] = W + (size_t)(n0 + row) * K + gcol;
  }

  for (int k0 = 0; k0 < K; k0 += 64) {
    __syncthreads();
#pragma unroll
    for (int j = 0; j < 4; ++j) {
      short* la = As + (((j << 2) + wid) << 9);          // wave-uniform base
      short* lb = Bs + (((j << 2) + wid) << 9);
      gload_lds16(arow[j] + k0, la);
      gload_lds16(brow[j] + k0, lb);
    }
    __syncthreads();
#pragma unroll
    for (int kk = 0; kk < 2; ++kk) {
      short8 af[4], bfv[4];
#pragma unroll
      for (int i = 0; i < 4; ++i) {
        const int mr = wr + (i << 4) + (lane & 15);
        const int cg = (kk << 2) + (lane >> 4);
        af[i]  = *(const short8*)(As + mr * 64 + ((cg ^ (mr & 7)) << 3));
        const int nr = wc + (i << 4) + (lane & 15);
        bfv[i] = *(const short8*)(Bs + nr * 64 + ((cg ^ (nr & 7)) << 3));
      }
#pragma unroll
      for (int i = 0; i < 4; ++i)
#pragma unroll
        for (int j = 0; j < 4; ++j)
          acc[i][j] = __builtin_amdgcn_mfma_f32_16x16x32_bf16(af[i], bfv[j], acc[i][j], 0, 0, 0);
    }
  }

  // epilogue: C/D mapping col = lane&15, row = (lane>>4)*4 + r   [m89/m91]
  const int fr = lane & 15, fq = lane >> 4;
#pragma unroll
  for (int j = 0; j < 4; ++j) {
    const int n = n0 + wc + (j << 4) + fr;
    const float bb = bias[n];
#pragma unroll
    for (int i = 0; i < 4; ++i) {
#pragma unroll
      for (int r = 0; r < 4; ++r) {
        const int m = m0 + wr + (i << 4) + (fq << 2) + r;
        float v = acc[i][j][r] + bb;
        if (RELU) v = fmaxf(v, 0.f);
        if (OF32) Cf[(size_t)m * ldc + n] = v;
        if (OB16) Cb[(size_t)m * ldc + n] = __float2bfloat16(v);
      }
    }
  }
}

// ---------------------------------------------------------------------------
// x (B,S,143,111) fp32 -> xb (MPAD x 15936) bf16 (zero pad), nz[b*S+s] flag
__global__ __launch_bounds__(256)
void conv_x_kernel(const float* __restrict__ x, __hip_bfloat16* __restrict__ xb,
                   int* __restrict__ nz)
{
  __shared__ int sred[4];
  const int m = blockIdx.x;               // 0..MPAD-1
  const int valid = (m < ROWS);
  const float* src = x + (size_t)m * FLATIN;
  __hip_bfloat16* dst = xb + (size_t)m * KPAD1;
  int any = 0;
  for (int c = threadIdx.x; c < (KPAD1 >> 1); c += 256) {
    const int c0 = 2 * c;
    const float v0 = (valid && c0 < FLATIN) ? src[c0] : 0.f;
    const float v1 = (valid && c0 + 1 < FLATIN) ? src[c0 + 1] : 0.f;
    any |= (v0 != 0.f) | (v1 != 0.f);
    __hip_bfloat162 pr;
    pr.x = __float2bfloat16(v0);
    pr.y = __float2bfloat16(v1);
    *(__hip_bfloat162*)(dst + c0) = pr;
  }
  any = __any(any) ? 1 : 0;
  if ((threadIdx.x & 63) == 0) sred[threadIdx.x >> 6] = any;
  __syncthreads();
  if (valid && threadIdx.x == 0) nz[m] = sred[0] | sred[1] | sred[2] | sred[3];
}

// padding[b,s] = (s>0) && !any(nz[b,k] for k>=s)
__global__ void mask_kernel(const int* __restrict__ nz, int* __restrict__ pad)
{
  const int b = threadIdx.x;
  if (b >= 32) return;
  int any = 0;
  for (int s = 99; s >= 0; --s) {
    any |= nz[b * 100 + s];
    pad[b * 100 + s] = (s > 0 && !any) ? 1 : 0;
  }
}

// Compaction: idx[p] = p-th nonzero row; pos[m] = compact slot of row m
// (zero rows -> count); cnt[0] = count+1 (incl. canonical zero row at slot
// count, which gathers xb row 3200 = zeros). idx[count..MPAD-1] = 3200.
__global__ __launch_bounds__(256)
void compact_kernel(const int* __restrict__ nz, int* __restrict__ idx,
                    int* __restrict__ pos, int* __restrict__ cnt)
{
  __shared__ int wsum[4];
  __shared__ int total;
  const int t = threadIdx.x;
  int loc[13];
  int c = 0;
#pragma unroll
  for (int i = 0; i < 13; ++i) {
    const int m = t * 13 + i;
    loc[i] = (m < ROWS) ? nz[m] : 0;
    c += loc[i];
  }
  int v = c;
#pragma unroll
  for (int o = 1; o < 64; o <<= 1) {
    const int u = __shfl_up(v, o);
    if ((t & 63) >= o) v += u;
  }
  if ((t & 63) == 63) wsum[t >> 6] = v;
  __syncthreads();
  int wbase = 0;
  for (int w = 0; w < (t >> 6); ++w) wbase += wsum[w];
  int p = wbase + v - c;                 // exclusive prefix
#pragma unroll
  for (int i = 0; i < 13; ++i) {
    const int m = t * 13 + i;
    if (m < ROWS) {
      if (loc[i]) { idx[p] = m; pos[m] = p; ++p; }
      else pos[m] = -1;
    }
  }
  if (t == 255) total = p;
  __syncthreads();
  const int count = total;
  if (t == 0) cnt[0] = count + 1;
  for (int i = count + t; i < MPAD; i += 256) idx[i] = ROWS;
  for (int m = t; m < ROWS; m += 256) if (pos[m] < 0) pos[m] = count;
}

__global__ void pe_kernel(float* __restrict__ pe)
{
  const int i = blockIdx.x * 256 + threadIdx.x;
  if (i >= SEQ * 512) return;
  const int s = i >> 9, d = i & 511;
  const int d2 = d >> 1;
  const float div = expf((float)(2 * d2) * (-logf(10000.f) / 512.f));
  const float arg = (float)s * div;
  pe[i] = (d & 1) ? cosf(arg) : sinf(arg);
}

// fp32 -> bf16 pairwise, optional column pad (cout even, pad cols are 0)
__global__ __launch_bounds__(256)
void cvt_pad_kernel(const float* __restrict__ in, __hip_bfloat16* __restrict__ out,
                    int cin, int cout)
{
  const int c = (blockIdx.x * 256 + threadIdx.x) * 2;
  const int r = blockIdx.y;
  if (c >= cout) return;
  const float v0 = (c < cin) ? in[(size_t)r * cin + c] : 0.f;
  const float v1 = (c + 1 < cin) ? in[(size_t)r * cin + c + 1] : 0.f;
  __hip_bfloat162 pr;
  pr.x = __float2bfloat16(v0);
  pr.y = __float2bfloat16(v1);
  *(__hip_bfloat162*)(out + (size_t)r * cout + c) = pr;
}

__global__ void fill_kernel(float* __restrict__ p, int n, float v)
{
  const int i = blockIdx.x * 256 + threadIdx.x;
  if (i < n) p[i] = v;
}

// Scatter compact MLP output to (s*32+b) layout, + PE, fp32 + bf16 mirrors
__global__ __launch_bounds__(256)
void scatter_pe_kernel(const float* __restrict__ h3c, const int* __restrict__ pos,
                       const float* __restrict__ pe, float* __restrict__ hf,
                       __hip_bfloat16* __restrict__ hb)
{
  const int m = blockIdx.x;               // orig row b*100+s
  const int s = m % 100, b = m / 100;
  const int src = pos[m];
  const int t = threadIdx.x;
  const size_t sb = (size_t)src * 512;
  const size_t db = (size_t)(s * 32 + b) * 512;
#pragma unroll
  for (int u = 0; u < 2; ++u) {
    const int d = t + u * 256;
    const float v = h3c[sb + d] + pe[s * 512 + d];
    hf[db + d] = v;
    hb[db + d] = __float2bfloat16(v);
  }
}

// ---------------------------------------------------------------------------
// LayerNorm over D=512
__global__ __launch_bounds__(256)
void ln_kernel(const float* __restrict__ x, const float* __restrict__ res,
               const float* __restrict__ g, const float* __restrict__ bta,
               float* __restrict__ y, __hip_bfloat16* __restrict__ yb)
{
  __shared__ float rs[4], rss[4];
  const int row = blockIdx.x;
  const int t = threadIdx.x;
  const size_t base = (size_t)row * 512;
  float v0 = x[base + t];
  float v1 = x[base + t + 256];
  if (res) { v0 += res[base + t]; v1 += res[base + t + 256]; }
  float s = v0 + v1, ss = v0 * v0 + v1 * v1;
#pragma unroll
  for (int o = 32; o > 0; o >>= 1) { s += __shfl_xor(s, o); ss += __shfl_xor(ss, o); }
  if ((t & 63) == 0) { rs[t >> 6] = s; rss[t >> 6] = ss; }
  __syncthreads();
  s = rs[0] + rs[1] + rs[2] + rs[3];
  ss = rss[0] + rss[1] + rss[2] + rss[3];
  const float mean = s * (1.f / 512.f);
  const float var = ss * (1.f / 512.f) - mean * mean;
  const float inv = rsqrtf(var + 1e-5f);
  const float o0 = (v0 - mean) * inv * g[t] + bta[t];
  const float o1 = (v1 - mean) * inv * g[t + 256] + bta[t + 256];
  y[base + t] = o0;
  y[base + t + 256] = o1;
  if (yb) {
    yb[base + t] = __float2bfloat16(o0);
    yb[base + t + 256] = __float2bfloat16(o1);
  }
}

// ---------------------------------------------------------------------------
// Encoder self-attention. qkv: (3200 rows = s*32+b, 1536) fp32: q|k|v.
__global__ __launch_bounds__(256)
void enc_attn_kernel(const float* __restrict__ qkv, const int* __restrict__ pad,
                     __hip_bfloat16* __restrict__ ob)
{
  __shared__ float Ks[100][129];
  __shared__ float Qs[128];
  __shared__ float Ps[100];
  __shared__ float red[4];
  const int bh = blockIdx.x;
  const int b = bh >> 2, h = bh & 3;
  const int q0 = blockIdx.y * 25;
  const int t = threadIdx.x;
  for (int i = t; i < 12800; i += 256) {
    const int s = i >> 7, d = i & 127;
    Ks[s][d] = qkv[(size_t)(s * 32 + b) * 1536 + 512 + h * 128 + d];
  }
  const int masked = (t < 100) ? pad[b * 100 + t] : 0;
  const float scale = 0.08838834764831845f;
  for (int qi = 0; qi < 25; ++qi) {
    const int q = q0 + qi;
    __syncthreads();
    if (t < 128) Qs[t] = qkv[(size_t)(q * 32 + b) * 1536 + h * 128 + t];
    __syncthreads();
    float sc = -3e38f;
    if (t < 100) {
      const float* kr = &Ks[t][0];
      float a = 0.f;
#pragma unroll 16
      for (int d = 0; d < 128; ++d) a += Qs[d] * kr[d];
      sc = masked ? -1e9f : (a * scale);
    }
    float mx = sc;
#pragma unroll
    for (int o = 32; o > 0; o >>= 1) mx = fmaxf(mx, __shfl_xor(mx, o));
    if ((t & 63) == 0) red[t >> 6] = mx;
    __syncthreads();
    mx = fmaxf(fmaxf(red[0], red[1]), fmaxf(red[2], red[3]));
    const float e = (t < 100) ? expf(sc - mx) : 0.f;
    float sm = e;
#pragma unroll
    for (int o = 32; o > 0; o >>= 1) sm += __shfl_xor(sm, o);
    __syncthreads();
    if ((t & 63) == 0) red[t >> 6] = sm;
    __syncthreads();
    sm = red[0] + red[1] + red[2] + red[3];
    if (t < 100) Ps[t] = e;
    __syncthreads();
    if (t < 128) {
      float a = 0.f;
      const float* vb = qkv + 1024 + h * 128 + t;
      for (int k = 0; k < 100; ++k) a += Ps[k] * vb[(size_t)(k * 32 + b) * 1536];
      ob[(size_t)(q * 32 + b) * 512 + h * 128 + t] = __float2bfloat16(a / sm);
    }
  }
}

// Decoder cross-attention (Sq=1). qd: (32 x 512). kv: (3200 x 1024) k|v.
__global__ __launch_bounds__(256)
void dec_attn_kernel(const float* __restrict__ qd, const float* __restrict__ kv,
                     float* __restrict__ ca)
{
  __shared__ float Qs[128];
  __shared__ float Ps[100];
  __shared__ float red[4];
  const int bh = blockIdx.x;
  const int b = bh >> 2, h = bh & 3;
  const int t = threadIdx.x;
  if (t < 128) Qs[t] = qd[b * 512 + h * 128 + t];
  __syncthreads();
  float sc = -3e38f;
  if (t < 100) {
    const float* kr = kv + (size_t)(t * 32 + b) * 1024 + h * 128;
    float a = 0.f;
#pragma unroll 16
    for (int d = 0; d < 128; ++d) a += Qs[d] * kr[d];
    sc = a * 0.08838834764831845f;
  }
  float mx = sc;
#pragma unroll
  for (int o = 32; o > 0; o >>= 1) mx = fmaxf(mx, __shfl_xor(mx, o));
  if ((t & 63) == 0) red[t >> 6] = mx;
  __syncthreads();
  mx = fmaxf(fmaxf(red[0], red[1]), fmaxf(red[2], red[3]));
  const float e = (t < 100) ? expf(sc - mx) : 0.f;
  float sm = e;
#pragma unroll
  for (int o = 32; o > 0; o >>= 1) sm += __shfl_xor(sm, o);
  __syncthreads();
  if ((t & 63) == 0) red[t >> 6] = sm;
  __syncthreads();
  sm = red[0] + red[1] + red[2] + red[3];
  if (t < 100) Ps[t] = e;
  __syncthreads();
  if (t < 128) {
    float a = 0.f;
    const float* vb = kv + 512 + h * 128 + t;
    for (int k = 0; k < 100; ++k) a += Ps[k] * vb[(size_t)(k * 32 + b) * 1024];
    ca[b * 512 + h * 128 + t] = a / sm;
  }
}

// ---------------------------------------------------------------------------
// Small fp32 GEMM, M=32: C(32,N) = A(32,K) @ W(N,K)^T + bias [, relu]
template<int RELU>
__global__ __launch_bounds__(256)
void sgemm32(const float* __restrict__ A, const float* __restrict__ W,
             const float* __restrict__ bias, float* __restrict__ C, int N, int K)
{
  const int t = threadIdx.x;
  const int n = t & 63;
  const int mg = __builtin_amdgcn_readfirstlane(t >> 6);
  const int gn = blockIdx.x * 64 + n;
  const size_t wrow = (gn < N) ? (size_t)gn : 0;
  const float4* wp = (const float4*)(W + wrow * K);
  const float* Abase = A + (size_t)mg * 8 * K;
  float acc[8] = {0.f, 0.f, 0.f, 0.f, 0.f, 0.f, 0.f, 0.f};
  const int nk4 = K >> 2;
  for (int k4 = 0; k4 < nk4; ++k4) {
    const float4 wv = wp[k4];
#pragma unroll
    for (int i = 0; i < 8; ++i) {
      const float4 av = *(const float4*)(Abase + (size_t)i * K + k4 * 4);
      acc[i] += av.x * wv.x + av.y * wv.y + av.z * wv.z + av.w * wv.w;
    }
  }
  if (gn < N) {
    const float bb = bias[gn];
#pragma unroll
    for (int i = 0; i < 8; ++i) {
      float v = acc[i] + bb;
      if (RELU) v = fmaxf(v, 0.f);
      C[(size_t)(mg * 8 + i) * N + gn] = v;
    }
  }
}

// ---------------------------------------------------------------------------
// Adaptive avg pool (143,111) -> (135,103), fp32
__global__ __launch_bounds__(256)
void pool_kernel(const float* __restrict__ o3, float* __restrict__ out)
{
  const int i = blockIdx.x * 256 + threadIdx.x;
  if (i >= 32 * 135 * 103) return;
  const int j = i % 103;
  const int tmp = i / 103;
  const int r = tmp % 135;
  const int b = tmp / 135;
  const int rs = (r * 143) / 135, re = ((r + 1) * 143 + 134) / 135;
  const int cs = (j * 111) / 103, ce = ((j + 1) * 111 + 102) / 103;
  float s = 0.f;
  for (int rr = rs; rr < re; ++rr)
    for (int cc = cs; cc < ce; ++cc)
      s += o3[(size_t)b * FLATIN + rr * 111 + cc];
  out[i] = s / (float)((re - rs) * (ce - cs));
}

// ---------------------------------------------------------------------------
extern "C" void kernel_launch(void* const* d_in, const int* in_sizes, int n_in,
                              void* d_out, int out_size, void* d_ws, size_t ws_size,
                              hipStream_t stream)
{
  (void)in_sizes; (void)n_in; (void)out_size; (void)ws_size;

  const float* x          = (const float*)d_in[0];
  const float* fc1_w      = (const float*)d_in[1];
  const float* fc1_b      = (const float*)d_in[2];
  const float* fc2_w      = (const float*)d_in[3];
  const float* fc2_b      = (const float*)d_in[4];
  const float* fc3_w      = (const float*)d_in[5];
  const float* fc3_b      = (const float*)d_in[6];
  const float* out1_w     = (const float*)d_in[7];
  const float* out1_b     = (const float*)d_in[8];
  const float* out2_w     = (const float*)d_in[9];
  const float* out2_b     = (const float*)d_in[10];
  const float* out3_w     = (const float*)d_in[11];
  const float* out3_b     = (const float*)d_in[12];
  const float* enc_qkv_w  = (const float*)d_in[13];
  const float* enc_qkv_b  = (const float*)d_in[14];
  const float* enc_proj_w = (const float*)d_in[15];
  const float* enc_proj_b = (const float*)d_in[16];
  const float* enc_ff1_w  = (const float*)d_in[17];
  const float* enc_ff1_b  = (const float*)d_in[18];
  const float* enc_ff2_w  = (const float*)d_in[19];
  const float* enc_ff2_b  = (const float*)d_in[20];
  const float* enc_ln1_g  = (const float*)d_in[21];
  const float* enc_ln1_b  = (const float*)d_in[22];
  const float* enc_ln2_g  = (const float*)d_in[23];
  const float* enc_ln2_b  = (const float*)d_in[24];
  const float* enc_lnf_g  = (const float*)d_in[25];
  const float* enc_lnf_b  = (const float*)d_in[26];
  const float* dec_sa_qkv_w  = (const float*)d_in[27];
  const float* dec_sa_qkv_b  = (const float*)d_in[28];
  const float* dec_sa_proj_w = (const float*)d_in[29];
  const float* dec_sa_proj_b = (const float*)d_in[30];
  const float* dec_ca_qkv_w  = (const float*)d_in[31];
  const float* dec_ca_qkv_b  = (const float*)d_in[32];
  const float* dec_ca_proj_w = (const float*)d_in[33];
  const float* dec_ca_proj_b = (const float*)d_in[34];
  const float* dec_ff1_w  = (const float*)d_in[35];
  const float* dec_ff1_b  = (const float*)d_in[36];
  const float* dec_ff2_w  = (const float*)d_in[37];
  const float* dec_ff2_b  = (const float*)d_in[38];
  const float* dec_ln1_g  = (const float*)d_in[39];
  const float* dec_ln1_b  = (const float*)d_in[40];
  const float* dec_ln2_g  = (const float*)d_in[41];
  const float* dec_ln2_b  = (const float*)d_in[42];
  const float* dec_ln3_g  = (const float*)d_in[43];
  const float* dec_ln3_b  = (const float*)d_in[44];
  const float* dec_lnf_g  = (const float*)d_in[45];
  const float* dec_lnf_b  = (const float*)d_in[46];

  char* wsp = (char*)d_ws;
  size_t off = 0;
  auto alloc = [&](size_t nbytes) -> char* {
    char* p = wsp + off;
    off += (nbytes + 255) & ~(size_t)255;
    return p;
  };

  __hip_bfloat16* xb     = (__hip_bfloat16*)alloc((size_t)MPAD * KPAD1 * 2);
  __hip_bfloat16* Wb1    = (__hip_bfloat16*)alloc((size_t)4096 * KPAD1 * 2);
  __hip_bfloat16* Wb2    = (__hip_bfloat16*)alloc((size_t)2048 * 4096 * 2);
  __hip_bfloat16* Wb3    = (__hip_bfloat16*)alloc((size_t)512 * 2048 * 2);
  __hip_bfloat16* Wqkvb  = (__hip_bfloat16*)alloc((size_t)2 * 1536 * 512 * 2);
  __hip_bfloat16* Wprojb = (__hip_bfloat16*)alloc((size_t)2 * 512 * 512 * 2);
  __hip_bfloat16* Wff1b  = (__hip_bfloat16*)alloc((size_t)2 * 1024 * 512 * 2);
  __hip_bfloat16* Wff2b  = (__hip_bfloat16*)alloc((size_t)2 * 512 * 1024 * 2);
  __hip_bfloat16* Wdkvb  = (__hip_bfloat16*)alloc((size_t)2 * 1536 * 512 * 2);
  int*   nz      = (int*)alloc(ROWS * 4);
  int*   padmask = (int*)alloc(ROWS * 4);
  int*   idx     = (int*)alloc(MPAD * 4);
  int*   pos     = (int*)alloc(ROWS * 4);
  int*   cnt     = (int*)alloc(256);
  float* pe      = (float*)alloc((size_t)SEQ * 512 * 4);
  __hip_bfloat16* h1c = (__hip_bfloat16*)alloc((size_t)MPAD * 4096 * 2);
  __hip_bfloat16* h2c = (__hip_bfloat16*)alloc((size_t)MPAD * 2048 * 2);
  float* h3c = (float*)alloc((size_t)MPAD * 512 * 4);
  float* hf  = (float*)alloc((size_t)ROWS * 512 * 4);
  __hip_bfloat16* hb = (__hip_bfloat16*)alloc((size_t)ROWS * 512 * 2);
  float* qkvbuf = (float*)alloc((size_t)ROWS * 1536 * 4);
  __hip_bfloat16* attnb = (__hip_bfloat16*)alloc((size_t)ROWS * 512 * 2);
  float* pjf  = (float*)alloc((size_t)ROWS * 512 * 4);
  __hip_bfloat16* f1b = (__hip_bfloat16*)alloc((size_t)ROWS * 1024 * 2);
  float* f2f  = (float*)alloc((size_t)ROWS * 512 * 4);
  float* memf = (float*)alloc((size_t)ROWS * 512 * 4);
  __hip_bfloat16* memb = (__hip_bfloat16*)alloc((size_t)ROWS * 512 * 2);
  float* kvbuf = (float*)alloc((size_t)ROWS * 1024 * 4);
  float* tbuf = (float*)alloc(32 * 512 * 4);
  float* tv   = (float*)alloc(32 * 512 * 4);
  float* so   = (float*)alloc(32 * 512 * 4);
  float* qdv  = (float*)alloc(32 * 512 * 4);
  float* cav  = (float*)alloc(32 * 512 * 4);
  float* cov  = (float*)alloc(32 * 512 * 4);
  float* tf1  = (float*)alloc(32 * 1024 * 4);
  float* tf2  = (float*)alloc(32 * 512 * 4);
  float* o1   = (float*)alloc(32 * 2048 * 4);
  float* o2   = (float*)alloc(32 * 4096 * 4);
  float* o3   = (float*)alloc((size_t)32 * FLATIN * 4);

  // ---- phase 0: conversions, mask, compaction, PE ----
  conv_x_kernel<<<MPAD, 256, 0, stream>>>(x, xb, nz);
  mask_kernel<<<1, 64, 0, stream>>>(nz, padmask);
  compact_kernel<<<1, 256, 0, stream>>>(nz, idx, pos, cnt);
  pe_kernel<<<(SEQ * 512 + 255) / 256, 256, 0, stream>>>(pe);

  auto cvt = [&](const float* in, __hip_bfloat16* out, int rows, int cin, int cout) {
    cvt_pad_kernel<<<dim3((cout / 2 + 255) / 256, rows), 256, 0, stream>>>(in, out, cin, cout);
  };
  cvt(fc1_w, Wb1, 4096, FLATIN, KPAD1);
  cvt(fc2_w, Wb2, 2048, 4096, 4096);
  cvt(fc3_w, Wb3, 512, 2048, 2048);
  cvt(enc_qkv_w, Wqkvb, 2 * 1536, 512, 512);
  cvt(enc_proj_w, Wprojb, 2 * 512, 512, 512);
  cvt(enc_ff1_w, Wff1b, 2 * 1024, 512, 512);
  cvt(enc_ff2_w, Wff2b, 2 * 512, 1024, 1024);
  cvt(dec_ca_qkv_w, Wdkvb, 2 * 1536, 512, 512);

  // ---- phase 1: input MLP on compact rows ----
  gemm_bf16<1, 1, 0, 1><<<26 * 32, 256, 0, stream>>>(xb, Wb1, fc1_b, idx, cnt,
      nullptr, h1c, KPAD1, 4096, 32);
  gemm_bf16<1, 0, 0, 1><<<26 * 16, 256, 0, stream>>>(h1c, Wb2, fc2_b, nullptr, cnt,
      nullptr, h2c, 4096, 2048, 16);
  gemm_bf16<1, 0, 1, 0><<<26 * 4, 256, 0, stream>>>(h2c, Wb3, fc3_b, nullptr, cnt,
      h3c, nullptr, 2048, 512, 4);
  scatter_pe_kernel<<<ROWS, 256, 0, stream>>>(h3c, pos, pe, hf, hb);

  // ---- phase 2: encoder ----
  for (int L = 0; L < 2; ++L) {
    gemm_bf16<0, 0, 1, 0><<<25 * 12, 256, 0, stream>>>(
        hb, Wqkvb + (size_t)L * 1536 * 512, enc_qkv_b + L * 1536, nullptr, nullptr,
        qkvbuf, nullptr, 512, 1536, 12);
    enc_attn_kernel<<<dim3(128, 4), 256, 0, stream>>>(qkvbuf, padmask, attnb);
    gemm_bf16<0, 0, 1, 0><<<25 * 4, 256, 0, stream>>>(
        attnb, Wprojb + (size_t)L * 512 * 512, enc_proj_b + L * 512, nullptr, nullptr,
        pjf, nullptr, 512, 512, 4);
    ln_kernel<<<ROWS, 256, 0, stream>>>(hf, pjf, enc_ln1_g + L * 512, enc_ln1_b + L * 512, hf, hb);
    gemm_bf16<1, 0, 0, 1><<<25 * 8, 256, 0, stream>>>(
        hb, Wff1b + (size_t)L * 1024 * 512, enc_ff1_b + L * 1024, nullptr, nullptr,
        nullptr, f1b, 512, 1024, 8);
    gemm_bf16<0, 0, 1, 0><<<25 * 4, 256, 0, stream>>>(
        f1b, Wff2b + (size_t)L * 512 * 1024, enc_ff2_b + L * 512, nullptr, nullptr,
        f2f, nullptr, 1024, 512, 4);
    ln_kernel<<<ROWS, 256, 0, stream>>>(hf, f2f, enc_ln2_g + L * 512, enc_ln2_b + L * 512, hf, hb);
  }
  ln_kernel<<<ROWS, 256, 0, stream>>>(hf, nullptr, enc_lnf_g, enc_lnf_b, memf, memb);

  // ---- phase 3: decoder (Sq=1; self-attn softmax over 1 key == 1 -> out=V) ----
  fill_kernel<<<(32 * 512 + 255) / 256, 256, 0, stream>>>(tbuf, 32 * 512, 1.0f);
  for (int L = 0; L < 2; ++L) {
    sgemm32<0><<<8, 256, 0, stream>>>(tbuf, dec_sa_qkv_w + (size_t)L * 1536 * 512 + (size_t)1024 * 512,
                                      dec_sa_qkv_b + L * 1536 + 1024, tv, 512, 512);
    sgemm32<0><<<8, 256, 0, stream>>>(tv, dec_sa_proj_w + (size_t)L * 512 * 512,
                                      dec_sa_proj_b + L * 512, so, 512, 512);
    ln_kernel<<<32, 256, 0, stream>>>(tbuf, so, dec_ln1_g + L * 512, dec_ln1_b + L * 512, tbuf, nullptr);

    sgemm32<0><<<8, 256, 0, stream>>>(tbuf, dec_ca_qkv_w + (size_t)L * 1536 * 512,
                                      dec_ca_qkv_b + L * 1536, qdv, 512, 512);
    gemm_bf16<0, 0, 1, 0><<<25 * 8, 256, 0, stream>>>(
        memb, Wdkvb + ((size_t)L * 1536 + 512) * 512, dec_ca_qkv_b + L * 1536 + 512,
        nullptr, nullptr, kvbuf, nullptr, 512, 1024, 8);
    dec_attn_kernel<<<128, 256, 0, stream>>>(qdv, kvbuf, cav);
    sgemm32<0><<<8, 256, 0, stream>>>(cav, dec_ca_proj_w + (size_t)L * 512 * 512,
                                      dec_ca_proj_b + L * 512, cov, 512, 512);
    ln_kernel<<<32, 256, 0, stream>>>(tbuf, cov, dec_ln2_g + L * 512, dec_ln2_b + L * 512, tbuf, nullptr);

    sgemm32<1><<<16, 256, 0, stream>>>(tbuf, dec_ff1_w + (size_t)L * 1024 * 512,
                                       dec_ff1_b + L * 1024, tf1, 1024, 512);
    sgemm32<0><<<8, 256, 0, stream>>>(tf1, dec_ff2_w + (size_t)L * 512 * 1024,
                                      dec_ff2_b + L * 512, tf2, 512, 1024);
    ln_kernel<<<32, 256, 0, stream>>>(tbuf, tf2, dec_ln3_g + L * 512, dec_ln3_b + L * 512, tbuf, nullptr);
  }
  ln_kernel<<<32, 256, 0, stream>>>(tbuf, nullptr, dec_lnf_g, dec_lnf_b, tbuf, nullptr);

  // ---- phase 4: output MLP + pool ----
  sgemm32<1><<<32, 256, 0, stream>>>(tbuf, out1_w, out1_b, o1, 2048, 512);
  sgemm32<1><<<64, 256, 0, stream>>>(o1, out2_w, out2_b, o2, 4096, 2048);
  sgemm32<1><<<249, 256, 0, stream>>>(o2, out3_w, out3_b, o3, FLATIN, 4096);
  pool_kernel<<<(32 * 135 * 103 + 255) / 256, 256, 0, stream>>>(o3, (float*)d_out);
}

// Round 4
// 2868.658 us; speedup vs baseline: 1.0541x; 1.0523x over previous
//
#include <hip/hip_runtime.h>
#include <hip/hip_bf16.h>

// ---------------------------------------------------------------------------
// Sizes
#define SEQ   100
#define BATCH 32
#define NH    4
#define HDIM  128
#define DMODEL 512
#define FLATIN 15873
#define KPAD1  16384        // FLATIN padded so K splits evenly by 4
#define ROWS   3200         // BATCH*SEQ
#define MPAD   3328         // ROWS (+1 zero row) padded to multiple of 128

typedef __attribute__((ext_vector_type(8))) short short8;
typedef __attribute__((ext_vector_type(4))) short short4v;
typedef __attribute__((ext_vector_type(4))) float f32x4;

__device__ __forceinline__ void gload_lds16(const void* g, void* l) {
  __builtin_amdgcn_global_load_lds((const __attribute__((address_space(1))) void*)g,
                                   (__attribute__((address_space(3))) void*)l, 16, 0, 0);
}

// bijective XCD chunk swizzle (m204)
__device__ __forceinline__ int xcd_swizzle(int id, int nwg) {
  const int q = nwg >> 3, r = nwg & 7;
  const int x = id & 7, p = id >> 3;
  return (x < r ? x * (q + 1) : r * (q + 1) + (x - r) * q) + p;
}

// ---------------------------------------------------------------------------
// bf16 MFMA GEMM, split-K, partial-output: P[ks][m][n] = sum_{k in slice} A*W
// A: M x K bf16 (lda=K), W: N x K bf16 (ldb=K). K % (64*ksl) == 0.
// grid = mtiles * ntile * ksl (1-D), block = 256 (4 waves, 2x2, 64x64/wave).
// Linearization m-major: ntk = ntile*ksl consecutive ids share the A panel.
// GATHER: A row = idx[m0+row]. cnt: blocks with m0 >= cnt[0] exit.
template<int GATHER>
__global__ __launch_bounds__(256)
void gemm_bf16(const __hip_bfloat16* __restrict__ A, const __hip_bfloat16* __restrict__ W,
               const int* __restrict__ idx, const int* __restrict__ cnt,
               float* __restrict__ P,
               int K, int ldc, int ntk, int ksl, size_t pstride)
{
  __shared__ __align__(16) short lds[16384];     // As 128x64 | Bs 128x64 (32KB)
  short* As = lds;
  short* Bs = lds + 8192;
  const int wg = xcd_swizzle(blockIdx.x, gridDim.x);
  const int mt = wg / ntk;
  const int rem = wg - mt * ntk;
  const int nt = rem / ksl;
  const int ks = rem - nt * ksl;
  const int m0 = mt << 7;
  const int n0 = nt << 7;
  if (cnt && m0 >= cnt[0]) return;
  const int Klen = K / ksl;
  const int kbeg = ks * Klen;
  const int kend = kbeg + Klen;

  const int tid  = threadIdx.x;
  const int lane = tid & 63;
  const int wid  = tid >> 6;
  const int wr = (wid >> 1) << 6;
  const int wc = (wid & 1) << 6;

  f32x4 acc[4][4];
#pragma unroll
  for (int i = 0; i < 4; ++i)
#pragma unroll
    for (int j = 0; j < 4; ++j) acc[i][j] = (f32x4){0.f, 0.f, 0.f, 0.f};

  const int srow = (wid << 3) + (lane >> 3);   // 0..31
  const int scs  = lane & 7;                   // 16B chunk slot
  const int gcol = ((scs ^ (srow & 7)) << 3);  // inverse-swizzled source col

  const __hip_bfloat16* arow[4];
  const __hip_bfloat16* brow[4];
#pragma unroll
  for (int j = 0; j < 4; ++j) {
    const int row = (j << 5) + srow;
    const int gr = GATHER ? idx[m0 + row] : (m0 + row);
    arow[j] = A + (size_t)gr * K + gcol;
    brow[j] = W + (size_t)(n0 + row) * K + gcol;
  }

  for (int k0 = kbeg; k0 < kend; k0 += 64) {
    __syncthreads();
#pragma unroll
    for (int j = 0; j < 4; ++j) {
      short* la = As + (((j << 2) + wid) << 9);          // wave-uniform base
      short* lb = Bs + (((j << 2) + wid) << 9);
      gload_lds16(arow[j] + k0, la);
      gload_lds16(brow[j] + k0, lb);
    }
    __syncthreads();
#pragma unroll
    for (int kk = 0; kk < 2; ++kk) {
      short8 af[4], bfv[4];
#pragma unroll
      for (int i = 0; i < 4; ++i) {
        const int mr = wr + (i << 4) + (lane & 15);
        const int cg = (kk << 2) + (lane >> 4);
        af[i]  = *(const short8*)(As + mr * 64 + ((cg ^ (mr & 7)) << 3));
        const int nr = wc + (i << 4) + (lane & 15);
        bfv[i] = *(const short8*)(Bs + nr * 64 + ((cg ^ (nr & 7)) << 3));
      }
#pragma unroll
      for (int i = 0; i < 4; ++i)
#pragma unroll
        for (int j = 0; j < 4; ++j)
          acc[i][j] = __builtin_amdgcn_mfma_f32_16x16x32_bf16(af[i], bfv[j], acc[i][j], 0, 0, 0);
    }
  }

  // epilogue: C/D mapping col = lane&15, row = (lane>>4)*4 + r   [m89/m91]
  float* Pout = P + (size_t)ks * pstride;
  const int fr = lane & 15, fq = lane >> 4;
#pragma unroll
  for (int j = 0; j < 4; ++j) {
    const int n = n0 + wc + (j << 4) + fr;
#pragma unroll
    for (int i = 0; i < 4; ++i) {
#pragma unroll
      for (int r = 0; r < 4; ++r) {
        const int m = m0 + wr + (i << 4) + (fq << 2) + r;
        Pout[(size_t)m * ldc + n] = acc[i][j][r];
      }
    }
  }
}

// ---------------------------------------------------------------------------
// Split-K reduce: C = sum_ks P[ks] + bias [, relu]; fp32 and/or bf16 out.
// grid = (ceil(N/1024), rows), block 256, float4 per thread.
template<int RELU, int OF32, int OB16>
__global__ __launch_bounds__(256)
void reduce_kernel(const float* __restrict__ P, size_t pstride, int ksl,
                   const float* __restrict__ bias, float* __restrict__ Cf,
                   __hip_bfloat16* __restrict__ Cb, int N,
                   const int* __restrict__ cnt)
{
  const int row = blockIdx.y;
  if (cnt) { const int cp = (cnt[0] + 127) & ~127; if (row >= cp) return; }
  const int n = (blockIdx.x * 256 + threadIdx.x) * 4;
  if (n >= N) return;
  const size_t o = (size_t)row * N + n;
  const float4 b4 = *(const float4*)(bias + n);
  float4 s = *(const float4*)(P + o);
  for (int k = 1; k < ksl; ++k) {
    const float4 p = *(const float4*)(P + (size_t)k * pstride + o);
    s.x += p.x; s.y += p.y; s.z += p.z; s.w += p.w;
  }
  s.x += b4.x; s.y += b4.y; s.z += b4.z; s.w += b4.w;
  if (RELU) {
    s.x = fmaxf(s.x, 0.f); s.y = fmaxf(s.y, 0.f);
    s.z = fmaxf(s.z, 0.f); s.w = fmaxf(s.w, 0.f);
  }
  if (OF32) *(float4*)(Cf + o) = s;
  if (OB16) {
    union { short4v v; __hip_bfloat16 h[4]; } u;
    u.h[0] = __float2bfloat16(s.x);
    u.h[1] = __float2bfloat16(s.y);
    u.h[2] = __float2bfloat16(s.z);
    u.h[3] = __float2bfloat16(s.w);
    *(short4v*)(Cb + o) = u.v;
  }
}

// ---------------------------------------------------------------------------
// x (B,S,143,111) fp32 -> xb (MPAD x KPAD1) bf16 (zero pad), nz flags
__global__ __launch_bounds__(256)
void conv_x_kernel(const float* __restrict__ x, __hip_bfloat16* __restrict__ xb,
                   int* __restrict__ nz)
{
  __shared__ int sred[4];
  const int m = blockIdx.x;               // 0..MPAD-1
  const int valid = (m < ROWS);
  const float* src = x + (size_t)m * FLATIN;
  __hip_bfloat16* dst = xb + (size_t)m * KPAD1;
  int any = 0;
  for (int c = threadIdx.x; c < (KPAD1 >> 1); c += 256) {
    const int c0 = 2 * c;
    const float v0 = (valid && c0 < FLATIN) ? src[c0] : 0.f;
    const float v1 = (valid && c0 + 1 < FLATIN) ? src[c0 + 1] : 0.f;
    any |= (v0 != 0.f) | (v1 != 0.f);
    __hip_bfloat162 pr;
    pr.x = __float2bfloat16(v0);
    pr.y = __float2bfloat16(v1);
    *(__hip_bfloat162*)(dst + c0) = pr;
  }
  any = __any(any) ? 1 : 0;
  if ((threadIdx.x & 63) == 0) sred[threadIdx.x >> 6] = any;
  __syncthreads();
  if (valid && threadIdx.x == 0) nz[m] = sred[0] | sred[1] | sred[2] | sred[3];
}

// padding[b,s] = (s>0) && !any(nz[b,k] for k>=s)
__global__ void mask_kernel(const int* __restrict__ nz, int* __restrict__ pad)
{
  const int b = threadIdx.x;
  if (b >= 32) return;
  int any = 0;
  for (int s = 99; s >= 0; --s) {
    any |= nz[b * 100 + s];
    pad[b * 100 + s] = (s > 0 && !any) ? 1 : 0;
  }
}

// Compaction: idx[p] = p-th nonzero row; pos[m] = compact slot (zero -> count);
// cnt[0] = count+1 (canonical zero row gathers xb row 3200 = zeros).
__global__ __launch_bounds__(256)
void compact_kernel(const int* __restrict__ nz, int* __restrict__ idx,
                    int* __restrict__ pos, int* __restrict__ cnt)
{
  __shared__ int wsum[4];
  __shared__ int total;
  const int t = threadIdx.x;
  int loc[13];
  int c = 0;
#pragma unroll
  for (int i = 0; i < 13; ++i) {
    const int m = t * 13 + i;
    loc[i] = (m < ROWS) ? nz[m] : 0;
    c += loc[i];
  }
  int v = c;
#pragma unroll
  for (int o = 1; o < 64; o <<= 1) {
    const int u = __shfl_up(v, o);
    if ((t & 63) >= o) v += u;
  }
  if ((t & 63) == 63) wsum[t >> 6] = v;
  __syncthreads();
  int wbase = 0;
  for (int w = 0; w < (t >> 6); ++w) wbase += wsum[w];
  int p = wbase + v - c;                 // exclusive prefix
#pragma unroll
  for (int i = 0; i < 13; ++i) {
    const int m = t * 13 + i;
    if (m < ROWS) {
      if (loc[i]) { idx[p] = m; pos[m] = p; ++p; }
      else pos[m] = -1;
    }
  }
  if (t == 255) total = p;
  __syncthreads();
  const int count = total;
  if (t == 0) cnt[0] = count + 1;
  for (int i = count + t; i < MPAD; i += 256) idx[i] = ROWS;
  for (int m = t; m < ROWS; m += 256) if (pos[m] < 0) pos[m] = count;
}

__global__ void pe_kernel(float* __restrict__ pe)
{
  const int i = blockIdx.x * 256 + threadIdx.x;
  if (i >= SEQ * 512) return;
  const int s = i >> 9, d = i & 511;
  const int d2 = d >> 1;
  const float div = expf((float)(2 * d2) * (-logf(10000.f) / 512.f));
  const float arg = (float)s * div;
  pe[i] = (d & 1) ? cosf(arg) : sinf(arg);
}

// fp32 -> bf16 pairwise, optional column pad (cout even, pad cols are 0)
__global__ __launch_bounds__(256)
void cvt_pad_kernel(const float* __restrict__ in, __hip_bfloat16* __restrict__ out,
                    int cin, int cout)
{
  const int c = (blockIdx.x * 256 + threadIdx.x) * 2;
  const int r = blockIdx.y;
  if (c >= cout) return;
  const float v0 = (c < cin) ? in[(size_t)r * cin + c] : 0.f;
  const float v1 = (c + 1 < cin) ? in[(size_t)r * cin + c + 1] : 0.f;
  __hip_bfloat162 pr;
  pr.x = __float2bfloat16(v0);
  pr.y = __float2bfloat16(v1);
  *(__hip_bfloat162*)(out + (size_t)r * cout + c) = pr;
}

__global__ void fill_kernel(float* __restrict__ p, int n, float v)
{
  const int i = blockIdx.x * 256 + threadIdx.x;
  if (i < n) p[i] = v;
}

// fc3 reduce + bias + relu + scatter to (s*32+b) + PE; fp32 + bf16 mirrors
__global__ __launch_bounds__(256)
void scatter_pe_reduce(const float* __restrict__ P, size_t pstride, int ksl,
                       const int* __restrict__ pos, const float* __restrict__ bias,
                       const float* __restrict__ pe, float* __restrict__ hf,
                       __hip_bfloat16* __restrict__ hb)
{
  const int m = blockIdx.x;               // orig row b*100+s
  const int s = m % 100, b = m / 100;
  const int src = pos[m];
  const int t = threadIdx.x;
  const size_t sb = (size_t)src * 512;
  const size_t db = (size_t)(s * 32 + b) * 512;
#pragma unroll
  for (int u = 0; u < 2; ++u) {
    const int d = t + u * 256;
    float v = bias[d];
    for (int k = 0; k < ksl; ++k) v += P[(size_t)k * pstride + sb + d];
    v = fmaxf(v, 0.f) + pe[s * 512 + d];
    hf[db + d] = v;
    hb[db + d] = __float2bfloat16(v);
  }
}

// ---------------------------------------------------------------------------
// LayerNorm over D=512
__global__ __launch_bounds__(256)
void ln_kernel(const float* __restrict__ x, const float* __restrict__ res,
               const float* __restrict__ g, const float* __restrict__ bta,
               float* __restrict__ y, __hip_bfloat16* __restrict__ yb)
{
  __shared__ float rs[4], rss[4];
  const int row = blockIdx.x;
  const int t = threadIdx.x;
  const size_t base = (size_t)row * 512;
  float v0 = x[base + t];
  float v1 = x[base + t + 256];
  if (res) { v0 += res[base + t]; v1 += res[base + t + 256]; }
  float s = v0 + v1, ss = v0 * v0 + v1 * v1;
#pragma unroll
  for (int o = 32; o > 0; o >>= 1) { s += __shfl_xor(s, o); ss += __shfl_xor(ss, o); }
  if ((t & 63) == 0) { rs[t >> 6] = s; rss[t >> 6] = ss; }
  __syncthreads();
  s = rs[0] + rs[1] + rs[2] + rs[3];
  ss = rss[0] + rss[1] + rss[2] + rss[3];
  const float mean = s * (1.f / 512.f);
  const float var = ss * (1.f / 512.f) - mean * mean;
  const float inv = rsqrtf(var + 1e-5f);
  const float o0 = (v0 - mean) * inv * g[t] + bta[t];
  const float o1 = (v1 - mean) * inv * g[t + 256] + bta[t + 256];
  y[base + t] = o0;
  y[base + t + 256] = o1;
  if (yb) {
    yb[base + t] = __float2bfloat16(o0);
    yb[base + t + 256] = __float2bfloat16(o1);
  }
}

// ---------------------------------------------------------------------------
// Encoder self-attention. qkv: (3200 rows = s*32+b, 1536) fp32: q|k|v.
__global__ __launch_bounds__(256)
void enc_attn_kernel(const float* __restrict__ qkv, const int* __restrict__ pad,
                     __hip_bfloat16* __restrict__ ob)
{
  __shared__ float Ks[100][129];
  __shared__ float Qs[128];
  __shared__ float Ps[100];
  __shared__ float red[4];
  const int bh = blockIdx.x;
  const int b = bh >> 2, h = bh & 3;
  const int q0 = blockIdx.y * 25;
  const int t = threadIdx.x;
  for (int i = t; i < 12800; i += 256) {
    const int s = i >> 7, d = i & 127;
    Ks[s][d] = qkv[(size_t)(s * 32 + b) * 1536 + 512 + h * 128 + d];
  }
  const int masked = (t < 100) ? pad[b * 100 + t] : 0;
  const float scale = 0.08838834764831845f;
  for (int qi = 0; qi < 25; ++qi) {
    const int q = q0 + qi;
    __syncthreads();
    if (t < 128) Qs[t] = qkv[(size_t)(q * 32 + b) * 1536 + h * 128 + t];
    __syncthreads();
    float sc = -3e38f;
    if (t < 100) {
      const float* kr = &Ks[t][0];
      float a = 0.f;
#pragma unroll 16
      for (int d = 0; d < 128; ++d) a += Qs[d] * kr[d];
      sc = masked ? -1e9f : (a * scale);
    }
    float mx = sc;
#pragma unroll
    for (int o = 32; o > 0; o >>= 1) mx = fmaxf(mx, __shfl_xor(mx, o));
    if ((t & 63) == 0) red[t >> 6] = mx;
    __syncthreads();
    mx = fmaxf(fmaxf(red[0], red[1]), fmaxf(red[2], red[3]));
    const float e = (t < 100) ? expf(sc - mx) : 0.f;
    float sm = e;
#pragma unroll
    for (int o = 32; o > 0; o >>= 1) sm += __shfl_xor(sm, o);
    __syncthreads();
    if ((t & 63) == 0) red[t >> 6] = sm;
    __syncthreads();
    sm = red[0] + red[1] + red[2] + red[3];
    if (t < 100) Ps[t] = e;
    __syncthreads();
    if (t < 128) {
      float a = 0.f;
      const float* vb = qkv + 1024 + h * 128 + t;
      for (int k = 0; k < 100; ++k) a += Ps[k] * vb[(size_t)(k * 32 + b) * 1536];
      ob[(size_t)(q * 32 + b) * 512 + h * 128 + t] = __float2bfloat16(a / sm);
    }
  }
}

// Decoder cross-attention (Sq=1). qd: (32 x 512). kv: (3200 x 1024) k|v.
__global__ __launch_bounds__(256)
void dec_attn_kernel(const float* __restrict__ qd, const float* __restrict__ kv,
                     float* __restrict__ ca)
{
  __shared__ float Qs[128];
  __shared__ float Ps[100];
  __shared__ float red[4];
  const int bh = blockIdx.x;
  const int b = bh >> 2, h = bh & 3;
  const int t = threadIdx.x;
  if (t < 128) Qs[t] = qd[b * 512 + h * 128 + t];
  __syncthreads();
  float sc = -3e38f;
  if (t < 100) {
    const float* kr = kv + (size_t)(t * 32 + b) * 1024 + h * 128;
    float a = 0.f;
#pragma unroll 16
    for (int d = 0; d < 128; ++d) a += Qs[d] * kr[d];
    sc = a * 0.08838834764831845f;
  }
  float mx = sc;
#pragma unroll
  for (int o = 32; o > 0; o >>= 1) mx = fmaxf(mx, __shfl_xor(mx, o));
  if ((t & 63) == 0) red[t >> 6] = mx;
  __syncthreads();
  mx = fmaxf(fmaxf(red[0], red[1]), fmaxf(red[2], red[3]));
  const float e = (t < 100) ? expf(sc - mx) : 0.f;
  float sm = e;
#pragma unroll
  for (int o = 32; o > 0; o >>= 1) sm += __shfl_xor(sm, o);
  __syncthreads();
  if ((t & 63) == 0) red[t >> 6] = sm;
  __syncthreads();
  sm = red[0] + red[1] + red[2] + red[3];
  if (t < 100) Ps[t] = e;
  __syncthreads();
  if (t < 128) {
    float a = 0.f;
    const float* vb = kv + 512 + h * 128 + t;
    for (int k = 0; k < 100; ++k) a += Ps[k] * vb[(size_t)(k * 32 + b) * 1024];
    ca[b * 512 + h * 128 + t] = a / sm;
  }
}

// ---------------------------------------------------------------------------
// Small fp32 GEMM, M=32: C(32,N) = A(32,K) @ W(N,K)^T + bias [, relu]
template<int RELU>
__global__ __launch_bounds__(256)
void sgemm32(const float* __restrict__ A, const float* __restrict__ W,
             const float* __restrict__ bias, float* __restrict__ C, int N, int K)
{
  const int t = threadIdx.x;
  const int n = t & 63;
  const int mg = __builtin_amdgcn_readfirstlane(t >> 6);
  const int gn = blockIdx.x * 64 + n;
  const size_t wrow = (gn < N) ? (size_t)gn : 0;
  const float4* wp = (const float4*)(W + wrow * K);
  const float* Abase = A + (size_t)mg * 8 * K;
  float acc[8] = {0.f, 0.f, 0.f, 0.f, 0.f, 0.f, 0.f, 0.f};
  const int nk4 = K >> 2;
  for (int k4 = 0; k4 < nk4; ++k4) {
    const float4 wv = wp[k4];
#pragma unroll
    for (int i = 0; i < 8; ++i) {
      const float4 av = *(const float4*)(Abase + (size_t)i * K + k4 * 4);
      acc[i] += av.x * wv.x + av.y * wv.y + av.z * wv.z + av.w * wv.w;
    }
  }
  if (gn < N) {
    const float bb = bias[gn];
#pragma unroll
    for (int i = 0; i < 8; ++i) {
      float v = acc[i] + bb;
      if (RELU) v = fmaxf(v, 0.f);
      C[(size_t)(mg * 8 + i) * N + gn] = v;
    }
  }
}

// ---------------------------------------------------------------------------
// Adaptive avg pool (143,111) -> (135,103), fp32
__global__ __launch_bounds__(256)
void pool_kernel(const float* __restrict__ o3, float* __restrict__ out)
{
  const int i = blockIdx.x * 256 + threadIdx.x;
  if (i >= 32 * 135 * 103) return;
  const int j = i % 103;
  const int tmp = i / 103;
  const int r = tmp % 135;
  const int b = tmp / 135;
  const int rs = (r * 143) / 135, re = ((r + 1) * 143 + 134) / 135;
  const int cs = (j * 111) / 103, ce = ((j + 1) * 111 + 102) / 103;
  float s = 0.f;
  for (int rr = rs; rr < re; ++rr)
    for (int cc = cs; cc < ce; ++cc)
      s += o3[(size_t)b * FLATIN + rr * 111 + cc];
  out[i] = s / (float)((re - rs) * (ce - cs));
}

// ---------------------------------------------------------------------------
extern "C" void kernel_launch(void* const* d_in, const int* in_sizes, int n_in,
                              void* d_out, int out_size, void* d_ws, size_t ws_size,
                              hipStream_t stream)
{
  (void)in_sizes; (void)n_in; (void)out_size; (void)ws_size;

  const float* x          = (const float*)d_in[0];
  const float* fc1_w      = (const float*)d_in[1];
  const float* fc1_b      = (const float*)d_in[2];
  const float* fc2_w      = (const float*)d_in[3];
  const float* fc2_b      = (const float*)d_in[4];
  const float* fc3_w      = (const float*)d_in[5];
  const float* fc3_b      = (const float*)d_in[6];
  const float* out1_w     = (const float*)d_in[7];
  const float* out1_b     = (const float*)d_in[8];
  const float* out2_w     = (const float*)d_in[9];
  const float* out2_b     = (const float*)d_in[10];
  const float* out3_w     = (const float*)d_in[11];
  const float* out3_b     = (const float*)d_in[12];
  const float* enc_qkv_w  = (const float*)d_in[13];
  const float* enc_qkv_b  = (const float*)d_in[14];
  const float* enc_proj_w = (const float*)d_in[15];
  const float* enc_proj_b = (const float*)d_in[16];
  const float* enc_ff1_w  = (const float*)d_in[17];
  const float* enc_ff1_b  = (const float*)d_in[18];
  const float* enc_ff2_w  = (const float*)d_in[19];
  const float* enc_ff2_b  = (const float*)d_in[20];
  const float* enc_ln1_g  = (const float*)d_in[21];
  const float* enc_ln1_b  = (const float*)d_in[22];
  const float* enc_ln2_g  = (const float*)d_in[23];
  const float* enc_ln2_b  = (const float*)d_in[24];
  const float* enc_lnf_g  = (const float*)d_in[25];
  const float* enc_lnf_b  = (const float*)d_in[26];
  const float* dec_sa_qkv_w  = (const float*)d_in[27];
  const float* dec_sa_qkv_b  = (const float*)d_in[28];
  const float* dec_sa_proj_w = (const float*)d_in[29];
  const float* dec_sa_proj_b = (const float*)d_in[30];
  const float* dec_ca_qkv_w  = (const float*)d_in[31];
  const float* dec_ca_qkv_b  = (const float*)d_in[32];
  const float* dec_ca_proj_w = (const float*)d_in[33];
  const float* dec_ca_proj_b = (const float*)d_in[34];
  const float* dec_ff1_w  = (const float*)d_in[35];
  const float* dec_ff1_b  = (const float*)d_in[36];
  const float* dec_ff2_w  = (const float*)d_in[37];
  const float* dec_ff2_b  = (const float*)d_in[38];
  const float* dec_ln1_g  = (const float*)d_in[39];
  const float* dec_ln1_b  = (const float*)d_in[40];
  const float* dec_ln2_g  = (const float*)d_in[41];
  const float* dec_ln2_b  = (const float*)d_in[42];
  const float* dec_ln3_g  = (const float*)d_in[43];
  const float* dec_ln3_b  = (const float*)d_in[44];
  const float* dec_lnf_g  = (const float*)d_in[45];
  const float* dec_lnf_b  = (const float*)d_in[46];

  char* wsp = (char*)d_ws;
  size_t off = 0;
  auto alloc = [&](size_t nbytes) -> char* {
    char* p = wsp + off;
    off += (nbytes + 255) & ~(size_t)255;
    return p;
  };

  __hip_bfloat16* xb     = (__hip_bfloat16*)alloc((size_t)MPAD * KPAD1 * 2);
  __hip_bfloat16* Wb1    = (__hip_bfloat16*)alloc((size_t)4096 * KPAD1 * 2);
  __hip_bfloat16* Wb2    = (__hip_bfloat16*)alloc((size_t)2048 * 4096 * 2);
  __hip_bfloat16* Wb3    = (__hip_bfloat16*)alloc((size_t)512 * 2048 * 2);
  __hip_bfloat16* Wqkvb  = (__hip_bfloat16*)alloc((size_t)2 * 1536 * 512 * 2);
  __hip_bfloat16* Wprojb = (__hip_bfloat16*)alloc((size_t)2 * 512 * 512 * 2);
  __hip_bfloat16* Wff1b  = (__hip_bfloat16*)alloc((size_t)2 * 1024 * 512 * 2);
  __hip_bfloat16* Wff2b  = (__hip_bfloat16*)alloc((size_t)2 * 512 * 1024 * 2);
  __hip_bfloat16* Wdkvb  = (__hip_bfloat16*)alloc((size_t)2 * 1536 * 512 * 2);
  int*   nz      = (int*)alloc(ROWS * 4);
  int*   padmask = (int*)alloc(ROWS * 4);
  int*   idx     = (int*)alloc(MPAD * 4);
  int*   pos     = (int*)alloc(ROWS * 4);
  int*   cnt     = (int*)alloc(256);
  float* pe      = (float*)alloc((size_t)SEQ * 512 * 4);
  __hip_bfloat16* h1c = (__hip_bfloat16*)alloc((size_t)MPAD * 4096 * 2);
  __hip_bfloat16* h2c = (__hip_bfloat16*)alloc((size_t)MPAD * 2048 * 2);
  float* hf  = (float*)alloc((size_t)ROWS * 512 * 4);
  __hip_bfloat16* hb = (__hip_bfloat16*)alloc((size_t)ROWS * 512 * 2);
  float* qkvbuf = (float*)alloc((size_t)ROWS * 1536 * 4);
  __hip_bfloat16* attnb = (__hip_bfloat16*)alloc((size_t)ROWS * 512 * 2);
  float* pjf  = (float*)alloc((size_t)ROWS * 512 * 4);
  __hip_bfloat16* f1b = (__hip_bfloat16*)alloc((size_t)ROWS * 1024 * 2);
  float* f2f  = (float*)alloc((size_t)ROWS * 512 * 4);
  float* memf = (float*)alloc((size_t)ROWS * 512 * 4);
  __hip_bfloat16* memb = (__hip_bfloat16*)alloc((size_t)ROWS * 512 * 2);
  float* kvbuf = (float*)alloc((size_t)ROWS * 1024 * 4);
  float* tbuf = (float*)alloc(32 * 512 * 4);
  float* tv   = (float*)alloc(32 * 512 * 4);
  float* so   = (float*)alloc(32 * 512 * 4);
  float* qdv  = (float*)alloc(32 * 512 * 4);
  float* cav  = (float*)alloc(32 * 512 * 4);
  float* cov  = (float*)alloc(32 * 512 * 4);
  float* tf1  = (float*)alloc(32 * 1024 * 4);
  float* tf2  = (float*)alloc(32 * 512 * 4);
  float* o1   = (float*)alloc(32 * 2048 * 4);
  float* o2   = (float*)alloc(32 * 4096 * 4);
  float* o3   = (float*)alloc((size_t)32 * FLATIN * 4);
  // split-K partial buffers (time-shared)
  float* fcP  = (float*)alloc((size_t)4 * MPAD * 4096 * 4);   // 218 MB
  float* encP = (float*)alloc((size_t)2 * ROWS * 1536 * 4);   // 39 MB

  const size_t psF1 = (size_t)MPAD * 4096;
  const size_t psF2 = (size_t)MPAD * 2048;
  const size_t psF3 = (size_t)MPAD * 512;

  // ---- phase 0: conversions, mask, compaction, PE ----
  conv_x_kernel<<<MPAD, 256, 0, stream>>>(x, xb, nz);
  mask_kernel<<<1, 64, 0, stream>>>(nz, padmask);
  compact_kernel<<<1, 256, 0, stream>>>(nz, idx, pos, cnt);
  pe_kernel<<<(SEQ * 512 + 255) / 256, 256, 0, stream>>>(pe);

  auto cvt = [&](const float* in, __hip_bfloat16* out, int rows, int cin, int cout) {
    cvt_pad_kernel<<<dim3((cout / 2 + 255) / 256, rows), 256, 0, stream>>>(in, out, cin, cout);
  };
  cvt(fc1_w, Wb1, 4096, FLATIN, KPAD1);
  cvt(fc2_w, Wb2, 2048, 4096, 4096);
  cvt(fc3_w, Wb3, 512, 2048, 2048);
  cvt(enc_qkv_w, Wqkvb, 2 * 1536, 512, 512);
  cvt(enc_proj_w, Wprojb, 2 * 512, 512, 512);
  cvt(enc_ff1_w, Wff1b, 2 * 1024, 512, 512);
  cvt(enc_ff2_w, Wff2b, 2 * 512, 1024, 1024);
  cvt(dec_ca_qkv_w, Wdkvb, 2 * 1536, 512, 512);

  // ---- phase 1: input MLP on compact rows (split-K everywhere) ----
  gemm_bf16<1><<<26 * 32 * 4, 256, 0, stream>>>(xb, Wb1, idx, cnt, fcP,
      KPAD1, 4096, 32 * 4, 4, psF1);
  reduce_kernel<1, 0, 1><<<dim3(4, MPAD), 256, 0, stream>>>(fcP, psF1, 4,
      fc1_b, nullptr, h1c, 4096, cnt);
  gemm_bf16<0><<<26 * 16 * 4, 256, 0, stream>>>(h1c, Wb2, nullptr, cnt, fcP,
      4096, 2048, 16 * 4, 4, psF2);
  reduce_kernel<1, 0, 1><<<dim3(2, MPAD), 256, 0, stream>>>(fcP, psF2, 4,
      fc2_b, nullptr, h2c, 2048, cnt);
  gemm_bf16<0><<<26 * 4 * 8, 256, 0, stream>>>(h2c, Wb3, nullptr, cnt, fcP,
      2048, 512, 4 * 8, 8, psF3);
  scatter_pe_reduce<<<ROWS, 256, 0, stream>>>(fcP, psF3, 8, pos, fc3_b, pe, hf, hb);

  // ---- phase 2: encoder ----
  for (int L = 0; L < 2; ++L) {
    gemm_bf16<0><<<25 * 12 * 2, 256, 0, stream>>>(hb, Wqkvb + (size_t)L * 1536 * 512,
        nullptr, nullptr, encP, 512, 1536, 12 * 2, 2, (size_t)ROWS * 1536);
    reduce_kernel<0, 1, 0><<<dim3(2, ROWS), 256, 0, stream>>>(encP, (size_t)ROWS * 1536, 2,
        enc_qkv_b + L * 1536, qkvbuf, nullptr, 1536, nullptr);
    enc_attn_kernel<<<dim3(128, 4), 256, 0, stream>>>(qkvbuf, padmask, attnb);
    gemm_bf16<0><<<25 * 4 * 4, 256, 0, stream>>>(attnb, Wprojb + (size_t)L * 512 * 512,
        nullptr, nullptr, encP, 512, 512, 4 * 4, 4, (size_t)ROWS * 512);
    reduce_kernel<0, 1, 0><<<dim3(1, ROWS), 256, 0, stream>>>(encP, (size_t)ROWS * 512, 4,
        enc_proj_b + L * 512, pjf, nullptr, 512, nullptr);
    ln_kernel<<<ROWS, 256, 0, stream>>>(hf, pjf, enc_ln1_g + L * 512, enc_ln1_b + L * 512, hf, hb);
    gemm_bf16<0><<<25 * 8 * 2, 256, 0, stream>>>(hb, Wff1b + (size_t)L * 1024 * 512,
        nullptr, nullptr, encP, 512, 1024, 8 * 2, 2, (size_t)ROWS * 1024);
    reduce_kernel<1, 0, 1><<<dim3(1, ROWS), 256, 0, stream>>>(encP, (size_t)ROWS * 1024, 2,
        enc_ff1_b + L * 1024, nullptr, f1b, 1024, nullptr);
    gemm_bf16<0><<<25 * 4 * 4, 256, 0, stream>>>(f1b, Wff2b + (size_t)L * 512 * 1024,
        nullptr, nullptr, encP, 1024, 512, 4 * 4, 4, (size_t)ROWS * 512);
    reduce_kernel<0, 1, 0><<<dim3(1, ROWS), 256, 0, stream>>>(encP, (size_t)ROWS * 512, 4,
        enc_ff2_b + L * 512, f2f, nullptr, 512, nullptr);
    ln_kernel<<<ROWS, 256, 0, stream>>>(hf, f2f, enc_ln2_g + L * 512, enc_ln2_b + L * 512, hf, hb);
  }
  ln_kernel<<<ROWS, 256, 0, stream>>>(hf, nullptr, enc_lnf_g, enc_lnf_b, memf, memb);

  // ---- phase 3: decoder (Sq=1; self-attn softmax over 1 key == 1 -> out=V) ----
  fill_kernel<<<(32 * 512 + 255) / 256, 256, 0, stream>>>(tbuf, 32 * 512, 1.0f);
  for (int L = 0; L < 2; ++L) {
    sgemm32<0><<<8, 256, 0, stream>>>(tbuf, dec_sa_qkv_w + (size_t)L * 1536 * 512 + (size_t)1024 * 512,
                                      dec_sa_qkv_b + L * 1536 + 1024, tv, 512, 512);
    sgemm32<0><<<8, 256, 0, stream>>>(tv, dec_sa_proj_w + (size_t)L * 512 * 512,
                                      dec_sa_proj_b + L * 512, so, 512, 512);
    ln_kernel<<<32, 256, 0, stream>>>(tbuf, so, dec_ln1_g + L * 512, dec_ln1_b + L * 512, tbuf, nullptr);

    sgemm32<0><<<8, 256, 0, stream>>>(tbuf, dec_ca_qkv_w + (size_t)L * 1536 * 512,
                                      dec_ca_qkv_b + L * 1536, qdv, 512, 512);
    gemm_bf16<0><<<25 * 8 * 2, 256, 0, stream>>>(memb, Wdkvb + ((size_t)L * 1536 + 512) * 512,
        nullptr, nullptr, encP, 512, 1024, 8 * 2, 2, (size_t)ROWS * 1024);
    reduce_kernel<0, 1, 0><<<dim3(1, ROWS), 256, 0, stream>>>(encP, (size_t)ROWS * 1024, 2,
        dec_ca_qkv_b + L * 1536 + 512, kvbuf, nullptr, 1024, nullptr);
    dec_attn_kernel<<<128, 256, 0, stream>>>(qdv, kvbuf, cav);
    sgemm32<0><<<8, 256, 0, stream>>>(cav, dec_ca_proj_w + (size_t)L * 512 * 512,
                                      dec_ca_proj_b + L * 512, cov, 512, 512);
    ln_kernel<<<32, 256, 0, stream>>>(tbuf, cov, dec_ln2_g + L * 512, dec_ln2_b + L * 512, tbuf, nullptr);

    sgemm32<1><<<16, 256, 0, stream>>>(tbuf, dec_ff1_w + (size_t)L * 1024 * 512,
                                       dec_ff1_b + L * 1024, tf1, 1024, 512);
    sgemm32<0><<<8, 256, 0, stream>>>(tf1, dec_ff2_w + (size_t)L * 512 * 1024,
                                      dec_ff2_b + L * 512, tf2, 512, 1024);
    ln_kernel<<<32, 256, 0, stream>>>(tbuf, tf2, dec_ln3_g + L * 512, dec_ln3_b + L * 512, tbuf, nullptr);
  }
  ln_kernel<<<32, 256, 0, stream>>>(tbuf, nullptr, dec_lnf_g, dec_lnf_b, tbuf, nullptr);

  // ---- phase 4: output MLP + pool ----
  sgemm32<1><<<32, 256, 0, stream>>>(tbuf, out1_w, out1_b, o1, 2048, 512);
  sgemm32<1><<<64, 256, 0, stream>>>(o1, out2_w, out2_b, o2, 4096, 2048);
  sgemm32<1><<<249, 256, 0, stream>>>(o2, out3_w, out3_b, o3, FLATIN, 4096);
  pool_kernel<<<(32 * 135 * 103 + 255) / 256, 256, 0, stream>>>(o3, (float*)d_out);
}

// Round 5
// 2544.407 us; speedup vs baseline: 1.1885x; 1.1274x over previous
//
#include <hip/hip_runtime.h>
#include <hip/hip_bf16.h>

// ---------------------------------------------------------------------------
// Sizes
#define SEQ   100
#define BATCH 32
#define NH    4
#define HDIM  128
#define DMODEL 512
#define FLATIN 15873
#define KPAD1  16384        // FLATIN padded so K splits evenly by 4
#define ROWS   3200         // BATCH*SEQ
#define MPAD   3328         // ROWS (+1 zero row) padded to multiple of 128

typedef __attribute__((ext_vector_type(8))) short short8;
typedef __attribute__((ext_vector_type(4))) short short4v;
typedef __attribute__((ext_vector_type(4))) float f32x4;

__device__ __forceinline__ void gload_lds16(const void* g, void* l) {
  __builtin_amdgcn_global_load_lds((const __attribute__((address_space(1))) void*)g,
                                   (__attribute__((address_space(3))) void*)l, 16, 0, 0);
}

// bijective XCD chunk swizzle (m204)
__device__ __forceinline__ int xcd_swizzle(int id, int nwg) {
  const int q = nwg >> 3, r = nwg & 7;
  const int x = id & 7, p = id >> 3;
  return (x < r ? x * (q + 1) : r * (q + 1) + (x - r) * q) + p;
}

// ---------------------------------------------------------------------------
// bf16 MFMA GEMM, split-K, partial-output: P[ks][m][n] = sum_{k in slice} A*W
// A: M x K bf16 (lda=K), W: N x K bf16 (ldb=K). K % (64*ksl) == 0.
// grid = mtiles * ntile * ksl (1-D), block = 256 (4 waves, 2x2, 64x64/wave).
// Linearization mt-MINOR: wg%mtiles = mt, wg/mtiles = (nt,ks). Consecutive
// ids share the W panel K-slice (L2-resident) and spread active mts evenly
// across XCD chunks (early-exit blocks interleave, no idle XCDs).
// GATHER: A row = idx[m0+row]. cnt: blocks with m0 >= cnt[0] exit.
template<int GATHER>
__global__ __launch_bounds__(256)
void gemm_bf16(const __hip_bfloat16* __restrict__ A, const __hip_bfloat16* __restrict__ W,
               const int* __restrict__ idx, const int* __restrict__ cnt,
               float* __restrict__ P,
               int K, int ldc, int mtiles, int ksl, size_t pstride)
{
  __shared__ __align__(16) short lds[16384];     // As 128x64 | Bs 128x64 (32KB)
  short* As = lds;
  short* Bs = lds + 8192;
  const int wg = xcd_swizzle(blockIdx.x, gridDim.x);
  const int mt = wg % mtiles;
  const int g  = wg / mtiles;
  const int nt = g / ksl;
  const int ks = g % ksl;
  const int m0 = mt << 7;
  const int n0 = nt << 7;
  if (cnt && m0 >= cnt[0]) return;
  const int Klen = K / ksl;
  const int kbeg = ks * Klen;
  const int kend = kbeg + Klen;

  const int tid  = threadIdx.x;
  const int lane = tid & 63;
  const int wid  = tid >> 6;
  const int wr = (wid >> 1) << 6;
  const int wc = (wid & 1) << 6;

  f32x4 acc[4][4];
#pragma unroll
  for (int i = 0; i < 4; ++i)
#pragma unroll
    for (int j = 0; j < 4; ++j) acc[i][j] = (f32x4){0.f, 0.f, 0.f, 0.f};

  const int srow = (wid << 3) + (lane >> 3);   // 0..31
  const int scs  = lane & 7;                   // 16B chunk slot
  const int gcol = ((scs ^ (srow & 7)) << 3);  // inverse-swizzled source col

  const __hip_bfloat16* arow[4];
  const __hip_bfloat16* brow[4];
#pragma unroll
  for (int j = 0; j < 4; ++j) {
    const int row = (j << 5) + srow;
    const int gr = GATHER ? idx[m0 + row] : (m0 + row);
    arow[j] = A + (size_t)gr * K + gcol;
    brow[j] = W + (size_t)(n0 + row) * K + gcol;
  }

  for (int k0 = kbeg; k0 < kend; k0 += 64) {
    __syncthreads();
#pragma unroll
    for (int j = 0; j < 4; ++j) {
      short* la = As + (((j << 2) + wid) << 9);          // wave-uniform base
      short* lb = Bs + (((j << 2) + wid) << 9);
      gload_lds16(arow[j] + k0, la);
      gload_lds16(brow[j] + k0, lb);
    }
    __syncthreads();
#pragma unroll
    for (int kk = 0; kk < 2; ++kk) {
      short8 af[4], bfv[4];
#pragma unroll
      for (int i = 0; i < 4; ++i) {
        const int mr = wr + (i << 4) + (lane & 15);
        const int cg = (kk << 2) + (lane >> 4);
        af[i]  = *(const short8*)(As + mr * 64 + ((cg ^ (mr & 7)) << 3));
        const int nr = wc + (i << 4) + (lane & 15);
        bfv[i] = *(const short8*)(Bs + nr * 64 + ((cg ^ (nr & 7)) << 3));
      }
#pragma unroll
      for (int i = 0; i < 4; ++i)
#pragma unroll
        for (int j = 0; j < 4; ++j)
          acc[i][j] = __builtin_amdgcn_mfma_f32_16x16x32_bf16(af[i], bfv[j], acc[i][j], 0, 0, 0);
    }
  }

  // epilogue: C/D mapping col = lane&15, row = (lane>>4)*4 + r   [m89/m91]
  float* Pout = P + (size_t)ks * pstride;
  const int fr = lane & 15, fq = lane >> 4;
#pragma unroll
  for (int j = 0; j < 4; ++j) {
    const int n = n0 + wc + (j << 4) + fr;
#pragma unroll
    for (int i = 0; i < 4; ++i) {
#pragma unroll
      for (int r = 0; r < 4; ++r) {
        const int m = m0 + wr + (i << 4) + (fq << 2) + r;
        Pout[(size_t)m * ldc + n] = acc[i][j][r];
      }
    }
  }
}

// ---------------------------------------------------------------------------
// Split-K reduce: C = sum_ks P[ks] + bias [, relu]; fp32 and/or bf16 out.
// grid = (ceil(N/1024), rows), block 256, float4 per thread.
template<int RELU, int OF32, int OB16>
__global__ __launch_bounds__(256)
void reduce_kernel(const float* __restrict__ P, size_t pstride, int ksl,
                   const float* __restrict__ bias, float* __restrict__ Cf,
                   __hip_bfloat16* __restrict__ Cb, int N,
                   const int* __restrict__ cnt)
{
  const int row = blockIdx.y;
  if (cnt) { const int cp = (cnt[0] + 127) & ~127; if (row >= cp) return; }
  const int n = (blockIdx.x * 256 + threadIdx.x) * 4;
  if (n >= N) return;
  const size_t o = (size_t)row * N + n;
  const float4 b4 = *(const float4*)(bias + n);
  float4 s = *(const float4*)(P + o);
  for (int k = 1; k < ksl; ++k) {
    const float4 p = *(const float4*)(P + (size_t)k * pstride + o);
    s.x += p.x; s.y += p.y; s.z += p.z; s.w += p.w;
  }
  s.x += b4.x; s.y += b4.y; s.z += b4.z; s.w += b4.w;
  if (RELU) {
    s.x = fmaxf(s.x, 0.f); s.y = fmaxf(s.y, 0.f);
    s.z = fmaxf(s.z, 0.f); s.w = fmaxf(s.w, 0.f);
  }
  if (OF32) *(float4*)(Cf + o) = s;
  if (OB16) {
    union { short4v v; __hip_bfloat16 h[4]; } u;
    u.h[0] = __float2bfloat16(s.x);
    u.h[1] = __float2bfloat16(s.y);
    u.h[2] = __float2bfloat16(s.z);
    u.h[3] = __float2bfloat16(s.w);
    *(short4v*)(Cb + o) = u.v;
  }
}

// ---------------------------------------------------------------------------
// x (B,S,143,111) fp32 -> xb (MPAD x KPAD1) bf16 (zero pad), nz flags
__global__ __launch_bounds__(256)
void conv_x_kernel(const float* __restrict__ x, __hip_bfloat16* __restrict__ xb,
                   int* __restrict__ nz)
{
  __shared__ int sred[4];
  const int m = blockIdx.x;               // 0..MPAD-1
  const int valid = (m < ROWS);
  const float* src = x + (size_t)m * FLATIN;
  __hip_bfloat16* dst = xb + (size_t)m * KPAD1;
  int any = 0;
  for (int c = threadIdx.x; c < (KPAD1 >> 1); c += 256) {
    const int c0 = 2 * c;
    const float v0 = (valid && c0 < FLATIN) ? src[c0] : 0.f;
    const float v1 = (valid && c0 + 1 < FLATIN) ? src[c0 + 1] : 0.f;
    any |= (v0 != 0.f) | (v1 != 0.f);
    __hip_bfloat162 pr;
    pr.x = __float2bfloat16(v0);
    pr.y = __float2bfloat16(v1);
    *(__hip_bfloat162*)(dst + c0) = pr;
  }
  any = __any(any) ? 1 : 0;
  if ((threadIdx.x & 63) == 0) sred[threadIdx.x >> 6] = any;
  __syncthreads();
  if (valid && threadIdx.x == 0) nz[m] = sred[0] | sred[1] | sred[2] | sred[3];
}

// padding[b,s] = (s>0) && !any(nz[b,k] for k>=s)
__global__ void mask_kernel(const int* __restrict__ nz, int* __restrict__ pad)
{
  const int b = threadIdx.x;
  if (b >= 32) return;
  int any = 0;
  for (int s = 99; s >= 0; --s) {
    any |= nz[b * 100 + s];
    pad[b * 100 + s] = (s > 0 && !any) ? 1 : 0;
  }
}

// Compaction: idx[p] = p-th nonzero row; pos[m] = compact slot (zero -> count);
// cnt[0] = count+1 (canonical zero row gathers xb row 3200 = zeros).
__global__ __launch_bounds__(256)
void compact_kernel(const int* __restrict__ nz, int* __restrict__ idx,
                    int* __restrict__ pos, int* __restrict__ cnt)
{
  __shared__ int wsum[4];
  __shared__ int total;
  const int t = threadIdx.x;
  int loc[13];
  int c = 0;
#pragma unroll
  for (int i = 0; i < 13; ++i) {
    const int m = t * 13 + i;
    loc[i] = (m < ROWS) ? nz[m] : 0;
    c += loc[i];
  }
  int v = c;
#pragma unroll
  for (int o = 1; o < 64; o <<= 1) {
    const int u = __shfl_up(v, o);
    if ((t & 63) >= o) v += u;
  }
  if ((t & 63) == 63) wsum[t >> 6] = v;
  __syncthreads();
  int wbase = 0;
  for (int w = 0; w < (t >> 6); ++w) wbase += wsum[w];
  int p = wbase + v - c;                 // exclusive prefix
#pragma unroll
  for (int i = 0; i < 13; ++i) {
    const int m = t * 13 + i;
    if (m < ROWS) {
      if (loc[i]) { idx[p] = m; pos[m] = p; ++p; }
      else pos[m] = -1;
    }
  }
  if (t == 255) total = p;
  __syncthreads();
  const int count = total;
  if (t == 0) cnt[0] = count + 1;
  for (int i = count + t; i < MPAD; i += 256) idx[i] = ROWS;
  for (int m = t; m < ROWS; m += 256) if (pos[m] < 0) pos[m] = count;
}

__global__ void pe_kernel(float* __restrict__ pe)
{
  const int i = blockIdx.x * 256 + threadIdx.x;
  if (i >= SEQ * 512) return;
  const int s = i >> 9, d = i & 511;
  const int d2 = d >> 1;
  const float div = expf((float)(2 * d2) * (-logf(10000.f) / 512.f));
  const float arg = (float)s * div;
  pe[i] = (d & 1) ? cosf(arg) : sinf(arg);
}

// fp32 -> bf16 pairwise, optional column pad (cout even, pad cols are 0)
__global__ __launch_bounds__(256)
void cvt_pad_kernel(const float* __restrict__ in, __hip_bfloat16* __restrict__ out,
                    int cin, int cout)
{
  const int c = (blockIdx.x * 256 + threadIdx.x) * 2;
  const int r = blockIdx.y;
  if (c >= cout) return;
  const float v0 = (c < cin) ? in[(size_t)r * cin + c] : 0.f;
  const float v1 = (c + 1 < cin) ? in[(size_t)r * cin + c + 1] : 0.f;
  __hip_bfloat162 pr;
  pr.x = __float2bfloat16(v0);
  pr.y = __float2bfloat16(v1);
  *(__hip_bfloat162*)(out + (size_t)r * cout + c) = pr;
}

__global__ void fill_kernel(float* __restrict__ p, int n, float v)
{
  const int i = blockIdx.x * 256 + threadIdx.x;
  if (i < n) p[i] = v;
}

// fc3 reduce + bias + relu + scatter to (s*32+b) + PE; fp32 + bf16 mirrors
__global__ __launch_bounds__(256)
void scatter_pe_reduce(const float* __restrict__ P, size_t pstride, int ksl,
                       const int* __restrict__ pos, const float* __restrict__ bias,
                       const float* __restrict__ pe, float* __restrict__ hf,
                       __hip_bfloat16* __restrict__ hb)
{
  const int m = blockIdx.x;               // orig row b*100+s
  const int s = m % 100, b = m / 100;
  const int src = pos[m];
  const int t = threadIdx.x;
  const size_t sb = (size_t)src * 512;
  const size_t db = (size_t)(s * 32 + b) * 512;
#pragma unroll
  for (int u = 0; u < 2; ++u) {
    const int d = t + u * 256;
    float v = bias[d];
    for (int k = 0; k < ksl; ++k) v += P[(size_t)k * pstride + sb + d];
    v = fmaxf(v, 0.f) + pe[s * 512 + d];
    hf[db + d] = v;
    hb[db + d] = __float2bfloat16(v);
  }
}

// ---------------------------------------------------------------------------
// LayerNorm over D=512
__global__ __launch_bounds__(256)
void ln_kernel(const float* __restrict__ x, const float* __restrict__ res,
               const float* __restrict__ g, const float* __restrict__ bta,
               float* __restrict__ y, __hip_bfloat16* __restrict__ yb)
{
  __shared__ float rs[4], rss[4];
  const int row = blockIdx.x;
  const int t = threadIdx.x;
  const size_t base = (size_t)row * 512;
  float v0 = x[base + t];
  float v1 = x[base + t + 256];
  if (res) { v0 += res[base + t]; v1 += res[base + t + 256]; }
  float s = v0 + v1, ss = v0 * v0 + v1 * v1;
#pragma unroll
  for (int o = 32; o > 0; o >>= 1) { s += __shfl_xor(s, o); ss += __shfl_xor(ss, o); }
  if ((t & 63) == 0) { rs[t >> 6] = s; rss[t >> 6] = ss; }
  __syncthreads();
  s = rs[0] + rs[1] + rs[2] + rs[3];
  ss = rss[0] + rss[1] + rss[2] + rss[3];
  const float mean = s * (1.f / 512.f);
  const float var = ss * (1.f / 512.f) - mean * mean;
  const float inv = rsqrtf(var + 1e-5f);
  const float o0 = (v0 - mean) * inv * g[t] + bta[t];
  const float o1 = (v1 - mean) * inv * g[t + 256] + bta[t + 256];
  y[base + t] = o0;
  y[base + t + 256] = o1;
  if (yb) {
    yb[base + t] = __float2bfloat16(o0);
    yb[base + t + 256] = __float2bfloat16(o1);
  }
}

// ---------------------------------------------------------------------------
// Encoder self-attention. qkv: (3200 rows = s*32+b, 1536) fp32: q|k|v.
__global__ __launch_bounds__(256)
void enc_attn_kernel(const float* __restrict__ qkv, const int* __restrict__ pad,
                     __hip_bfloat16* __restrict__ ob)
{
  __shared__ float Ks[100][129];
  __shared__ float Qs[128];
  __shared__ float Ps[100];
  __shared__ float red[4];
  const int bh = blockIdx.x;
  const int b = bh >> 2, h = bh & 3;
  const int q0 = blockIdx.y * 25;
  const int t = threadIdx.x;
  for (int i = t; i < 12800; i += 256) {
    const int s = i >> 7, d = i & 127;
    Ks[s][d] = qkv[(size_t)(s * 32 + b) * 1536 + 512 + h * 128 + d];
  }
  const int masked = (t < 100) ? pad[b * 100 + t] : 0;
  const float scale = 0.08838834764831845f;
  for (int qi = 0; qi < 25; ++qi) {
    const int q = q0 + qi;
    __syncthreads();
    if (t < 128) Qs[t] = qkv[(size_t)(q * 32 + b) * 1536 + h * 128 + t];
    __syncthreads();
    float sc = -3e38f;
    if (t < 100) {
      const float* kr = &Ks[t][0];
      float a = 0.f;
#pragma unroll 16
      for (int d = 0; d < 128; ++d) a += Qs[d] * kr[d];
      sc = masked ? -1e9f : (a * scale);
    }
    float mx = sc;
#pragma unroll
    for (int o = 32; o > 0; o >>= 1) mx = fmaxf(mx, __shfl_xor(mx, o));
    if ((t & 63) == 0) red[t >> 6] = mx;
    __syncthreads();
    mx = fmaxf(fmaxf(red[0], red[1]), fmaxf(red[2], red[3]));
    const float e = (t < 100) ? expf(sc - mx) : 0.f;
    float sm = e;
#pragma unroll
    for (int o = 32; o > 0; o >>= 1) sm += __shfl_xor(sm, o);
    __syncthreads();
    if ((t & 63) == 0) red[t >> 6] = sm;
    __syncthreads();
    sm = red[0] + red[1] + red[2] + red[3];
    if (t < 100) Ps[t] = e;
    __syncthreads();
    if (t < 128) {
      float a = 0.f;
      const float* vb = qkv + 1024 + h * 128 + t;
      for (int k = 0; k < 100; ++k) a += Ps[k] * vb[(size_t)(k * 32 + b) * 1536];
      ob[(size_t)(q * 32 + b) * 512 + h * 128 + t] = __float2bfloat16(a / sm);
    }
  }
}

// Decoder cross-attention (Sq=1). qd: (32 x 512). kv: (3200 x 1024) k|v.
__global__ __launch_bounds__(256)
void dec_attn_kernel(const float* __restrict__ qd, const float* __restrict__ kv,
                     float* __restrict__ ca)
{
  __shared__ float Qs[128];
  __shared__ float Ps[100];
  __shared__ float red[4];
  const int bh = blockIdx.x;
  const int b = bh >> 2, h = bh & 3;
  const int t = threadIdx.x;
  if (t < 128) Qs[t] = qd[b * 512 + h * 128 + t];
  __syncthreads();
  float sc = -3e38f;
  if (t < 100) {
    const float* kr = kv + (size_t)(t * 32 + b) * 1024 + h * 128;
    float a = 0.f;
#pragma unroll 16
    for (int d = 0; d < 128; ++d) a += Qs[d] * kr[d];
    sc = a * 0.08838834764831845f;
  }
  float mx = sc;
#pragma unroll
  for (int o = 32; o > 0; o >>= 1) mx = fmaxf(mx, __shfl_xor(mx, o));
  if ((t & 63) == 0) red[t >> 6] = mx;
  __syncthreads();
  mx = fmaxf(fmaxf(red[0], red[1]), fmaxf(red[2], red[3]));
  const float e = (t < 100) ? expf(sc - mx) : 0.f;
  float sm = e;
#pragma unroll
  for (int o = 32; o > 0; o >>= 1) sm += __shfl_xor(sm, o);
  __syncthreads();
  if ((t & 63) == 0) red[t >> 6] = sm;
  __syncthreads();
  sm = red[0] + red[1] + red[2] + red[3];
  if (t < 100) Ps[t] = e;
  __syncthreads();
  if (t < 128) {
    float a = 0.f;
    const float* vb = kv + 512 + h * 128 + t;
    for (int k = 0; k < 100; ++k) a += Ps[k] * vb[(size_t)(k * 32 + b) * 1024];
    ca[b * 512 + h * 128 + t] = a / sm;
  }
}

// ---------------------------------------------------------------------------
// Small fp32 GEMM, M=32: C(32,N) = A(32,K) @ W(N,K)^T + bias [, relu]
template<int RELU>
__global__ __launch_bounds__(256)
void sgemm32(const float* __restrict__ A, const float* __restrict__ W,
             const float* __restrict__ bias, float* __restrict__ C, int N, int K)
{
  const int t = threadIdx.x;
  const int n = t & 63;
  const int mg = __builtin_amdgcn_readfirstlane(t >> 6);
  const int gn = blockIdx.x * 64 + n;
  const size_t wrow = (gn < N) ? (size_t)gn : 0;
  const float4* wp = (const float4*)(W + wrow * K);
  const float* Abase = A + (size_t)mg * 8 * K;
  float acc[8] = {0.f, 0.f, 0.f, 0.f, 0.f, 0.f, 0.f, 0.f};
  const int nk4 = K >> 2;
  for (int k4 = 0; k4 < nk4; ++k4) {
    const float4 wv = wp[k4];
#pragma unroll
    for (int i = 0; i < 8; ++i) {
      const float4 av = *(const float4*)(Abase + (size_t)i * K + k4 * 4);
      acc[i] += av.x * wv.x + av.y * wv.y + av.z * wv.z + av.w * wv.w;
    }
  }
  if (gn < N) {
    const float bb = bias[gn];
#pragma unroll
    for (int i = 0; i < 8; ++i) {
      float v = acc[i] + bb;
      if (RELU) v = fmaxf(v, 0.f);
      C[(size_t)(mg * 8 + i) * N + gn] = v;
    }
  }
}

// ---------------------------------------------------------------------------
// Adaptive avg pool (143,111) -> (135,103), fp32
__global__ __launch_bounds__(256)
void pool_kernel(const float* __restrict__ o3, float* __restrict__ out)
{
  const int i = blockIdx.x * 256 + threadIdx.x;
  if (i >= 32 * 135 * 103) return;
  const int j = i % 103;
  const int tmp = i / 103;
  const int r = tmp % 135;
  const int b = tmp / 135;
  const int rs = (r * 143) / 135, re = ((r + 1) * 143 + 134) / 135;
  const int cs = (j * 111) / 103, ce = ((j + 1) * 111 + 102) / 103;
  float s = 0.f;
  for (int rr = rs; rr < re; ++rr)
    for (int cc = cs; cc < ce; ++cc)
      s += o3[(size_t)b * FLATIN + rr * 111 + cc];
  out[i] = s / (float)((re - rs) * (ce - cs));
}

// ---------------------------------------------------------------------------
extern "C" void kernel_launch(void* const* d_in, const int* in_sizes, int n_in,
                              void* d_out, int out_size, void* d_ws, size_t ws_size,
                              hipStream_t stream)
{
  (void)in_sizes; (void)n_in; (void)out_size; (void)ws_size;

  const float* x          = (const float*)d_in[0];
  const float* fc1_w      = (const float*)d_in[1];
  const float* fc1_b      = (const float*)d_in[2];
  const float* fc2_w      = (const float*)d_in[3];
  const float* fc2_b      = (const float*)d_in[4];
  const float* fc3_w      = (const float*)d_in[5];
  const float* fc3_b      = (const float*)d_in[6];
  const float* out1_w     = (const float*)d_in[7];
  const float* out1_b     = (const float*)d_in[8];
  const float* out2_w     = (const float*)d_in[9];
  const float* out2_b     = (const float*)d_in[10];
  const float* out3_w     = (const float*)d_in[11];
  const float* out3_b     = (const float*)d_in[12];
  const float* enc_qkv_w  = (const float*)d_in[13];
  const float* enc_qkv_b  = (const float*)d_in[14];
  const float* enc_proj_w = (const float*)d_in[15];
  const float* enc_proj_b = (const float*)d_in[16];
  const float* enc_ff1_w  = (const float*)d_in[17];
  const float* enc_ff1_b  = (const float*)d_in[18];
  const float* enc_ff2_w  = (const float*)d_in[19];
  const float* enc_ff2_b  = (const float*)d_in[20];
  const float* enc_ln1_g  = (const float*)d_in[21];
  const float* enc_ln1_b  = (const float*)d_in[22];
  const float* enc_ln2_g  = (const float*)d_in[23];
  const float* enc_ln2_b  = (const float*)d_in[24];
  const float* enc_lnf_g  = (const float*)d_in[25];
  const float* enc_lnf_b  = (const float*)d_in[26];
  const float* dec_sa_qkv_w  = (const float*)d_in[27];
  const float* dec_sa_qkv_b  = (const float*)d_in[28];
  const float* dec_sa_proj_w = (const float*)d_in[29];
  const float* dec_sa_proj_b = (const float*)d_in[30];
  const float* dec_ca_qkv_w  = (const float*)d_in[31];
  const float* dec_ca_qkv_b  = (const float*)d_in[32];
  const float* dec_ca_proj_w = (const float*)d_in[33];
  const float* dec_ca_proj_b = (const float*)d_in[34];
  const float* dec_ff1_w  = (const float*)d_in[35];
  const float* dec_ff1_b  = (const float*)d_in[36];
  const float* dec_ff2_w  = (const float*)d_in[37];
  const float* dec_ff2_b  = (const float*)d_in[38];
  const float* dec_ln1_g  = (const float*)d_in[39];
  const float* dec_ln1_b  = (const float*)d_in[40];
  const float* dec_ln2_g  = (const float*)d_in[41];
  const float* dec_ln2_b  = (const float*)d_in[42];
  const float* dec_ln3_g  = (const float*)d_in[43];
  const float* dec_ln3_b  = (const float*)d_in[44];
  const float* dec_lnf_g  = (const float*)d_in[45];
  const float* dec_lnf_b  = (const float*)d_in[46];

  char* wsp = (char*)d_ws;
  size_t off = 0;
  auto alloc = [&](size_t nbytes) -> char* {
    char* p = wsp + off;
    off += (nbytes + 255) & ~(size_t)255;
    return p;
  };

  __hip_bfloat16* xb     = (__hip_bfloat16*)alloc((size_t)MPAD * KPAD1 * 2);
  __hip_bfloat16* Wb1    = (__hip_bfloat16*)alloc((size_t)4096 * KPAD1 * 2);
  __hip_bfloat16* Wb2    = (__hip_bfloat16*)alloc((size_t)2048 * 4096 * 2);
  __hip_bfloat16* Wb3    = (__hip_bfloat16*)alloc((size_t)512 * 2048 * 2);
  __hip_bfloat16* Wqkvb  = (__hip_bfloat16*)alloc((size_t)2 * 1536 * 512 * 2);
  __hip_bfloat16* Wprojb = (__hip_bfloat16*)alloc((size_t)2 * 512 * 512 * 2);
  __hip_bfloat16* Wff1b  = (__hip_bfloat16*)alloc((size_t)2 * 1024 * 512 * 2);
  __hip_bfloat16* Wff2b  = (__hip_bfloat16*)alloc((size_t)2 * 512 * 1024 * 2);
  __hip_bfloat16* Wdkvb  = (__hip_bfloat16*)alloc((size_t)2 * 1536 * 512 * 2);
  int*   nz      = (int*)alloc(ROWS * 4);
  int*   padmask = (int*)alloc(ROWS * 4);
  int*   idx     = (int*)alloc(MPAD * 4);
  int*   pos     = (int*)alloc(ROWS * 4);
  int*   cnt     = (int*)alloc(256);
  float* pe      = (float*)alloc((size_t)SEQ * 512 * 4);
  __hip_bfloat16* h1c = (__hip_bfloat16*)alloc((size_t)MPAD * 4096 * 2);
  __hip_bfloat16* h2c = (__hip_bfloat16*)alloc((size_t)MPAD * 2048 * 2);
  float* hf  = (float*)alloc((size_t)ROWS * 512 * 4);
  __hip_bfloat16* hb = (__hip_bfloat16*)alloc((size_t)ROWS * 512 * 2);
  float* qkvbuf = (float*)alloc((size_t)ROWS * 1536 * 4);
  __hip_bfloat16* attnb = (__hip_bfloat16*)alloc((size_t)ROWS * 512 * 2);
  float* pjf  = (float*)alloc((size_t)ROWS * 512 * 4);
  __hip_bfloat16* f1b = (__hip_bfloat16*)alloc((size_t)ROWS * 1024 * 2);
  float* f2f  = (float*)alloc((size_t)ROWS * 512 * 4);
  float* memf = (float*)alloc((size_t)ROWS * 512 * 4);
  __hip_bfloat16* memb = (__hip_bfloat16*)alloc((size_t)ROWS * 512 * 2);
  float* kvbuf = (float*)alloc((size_t)ROWS * 1024 * 4);
  float* tbuf = (float*)alloc(32 * 512 * 4);
  float* tv   = (float*)alloc(32 * 512 * 4);
  float* so   = (float*)alloc(32 * 512 * 4);
  float* qdv  = (float*)alloc(32 * 512 * 4);
  float* cav  = (float*)alloc(32 * 512 * 4);
  float* cov  = (float*)alloc(32 * 512 * 4);
  float* tf1  = (float*)alloc(32 * 1024 * 4);
  float* tf2  = (float*)alloc(32 * 512 * 4);
  float* o1   = (float*)alloc(32 * 2048 * 4);
  float* o2   = (float*)alloc(32 * 4096 * 4);
  float* o3   = (float*)alloc((size_t)32 * FLATIN * 4);
  // split-K partial buffers (time-shared)
  float* fcP  = (float*)alloc((size_t)4 * MPAD * 4096 * 4);   // 218 MB
  float* encP = (float*)alloc((size_t)2 * ROWS * 1536 * 4);   // 39 MB

  const size_t psF1 = (size_t)MPAD * 4096;
  const size_t psF2 = (size_t)MPAD * 2048;
  const size_t psF3 = (size_t)MPAD * 512;

  // ---- phase 0: conversions, mask, compaction, PE ----
  conv_x_kernel<<<MPAD, 256, 0, stream>>>(x, xb, nz);
  mask_kernel<<<1, 64, 0, stream>>>(nz, padmask);
  compact_kernel<<<1, 256, 0, stream>>>(nz, idx, pos, cnt);
  pe_kernel<<<(SEQ * 512 + 255) / 256, 256, 0, stream>>>(pe);

  auto cvt = [&](const float* in, __hip_bfloat16* out, int rows, int cin, int cout) {
    cvt_pad_kernel<<<dim3((cout / 2 + 255) / 256, rows), 256, 0, stream>>>(in, out, cin, cout);
  };
  cvt(fc1_w, Wb1, 4096, FLATIN, KPAD1);
  cvt(fc2_w, Wb2, 2048, 4096, 4096);
  cvt(fc3_w, Wb3, 512, 2048, 2048);
  cvt(enc_qkv_w, Wqkvb, 2 * 1536, 512, 512);
  cvt(enc_proj_w, Wprojb, 2 * 512, 512, 512);
  cvt(enc_ff1_w, Wff1b, 2 * 1024, 512, 512);
  cvt(enc_ff2_w, Wff2b, 2 * 512, 1024, 1024);
  cvt(dec_ca_qkv_w, Wdkvb, 2 * 1536, 512, 512);

  // ---- phase 1: input MLP on compact rows (split-K everywhere) ----
  gemm_bf16<1><<<26 * 32 * 4, 256, 0, stream>>>(xb, Wb1, idx, cnt, fcP,
      KPAD1, 4096, 26, 4, psF1);
  reduce_kernel<1, 0, 1><<<dim3(4, MPAD), 256, 0, stream>>>(fcP, psF1, 4,
      fc1_b, nullptr, h1c, 4096, cnt);
  gemm_bf16<0><<<26 * 16 * 4, 256, 0, stream>>>(h1c, Wb2, nullptr, cnt, fcP,
      4096, 2048, 26, 4, psF2);
  reduce_kernel<1, 0, 1><<<dim3(2, MPAD), 256, 0, stream>>>(fcP, psF2, 4,
      fc2_b, nullptr, h2c, 2048, cnt);
  gemm_bf16<0><<<26 * 4 * 8, 256, 0, stream>>>(h2c, Wb3, nullptr, cnt, fcP,
      2048, 512, 26, 8, psF3);
  scatter_pe_reduce<<<ROWS, 256, 0, stream>>>(fcP, psF3, 8, pos, fc3_b, pe, hf, hb);

  // ---- phase 2: encoder ----
  for (int L = 0; L < 2; ++L) {
    gemm_bf16<0><<<25 * 12 * 2, 256, 0, stream>>>(hb, Wqkvb + (size_t)L * 1536 * 512,
        nullptr, nullptr, encP, 512, 1536, 25, 2, (size_t)ROWS * 1536);
    reduce_kernel<0, 1, 0><<<dim3(2, ROWS), 256, 0, stream>>>(encP, (size_t)ROWS * 1536, 2,
        enc_qkv_b + L * 1536, qkvbuf, nullptr, 1536, nullptr);
    enc_attn_kernel<<<dim3(128, 4), 256, 0, stream>>>(qkvbuf, padmask, attnb);
    gemm_bf16<0><<<25 * 4 * 4, 256, 0, stream>>>(attnb, Wprojb + (size_t)L * 512 * 512,
        nullptr, nullptr, encP, 512, 512, 25, 4, (size_t)ROWS * 512);
    reduce_kernel<0, 1, 0><<<dim3(1, ROWS), 256, 0, stream>>>(encP, (size_t)ROWS * 512, 4,
        enc_proj_b + L * 512, pjf, nullptr, 512, nullptr);
    ln_kernel<<<ROWS, 256, 0, stream>>>(hf, pjf, enc_ln1_g + L * 512, enc_ln1_b + L * 512, hf, hb);
    gemm_bf16<0><<<25 * 8 * 2, 256, 0, stream>>>(hb, Wff1b + (size_t)L * 1024 * 512,
        nullptr, nullptr, encP, 512, 1024, 25, 2, (size_t)ROWS * 1024);
    reduce_kernel<1, 0, 1><<<dim3(1, ROWS), 256, 0, stream>>>(encP, (size_t)ROWS * 1024, 2,
        enc_ff1_b + L * 1024, nullptr, f1b, 1024, nullptr);
    gemm_bf16<0><<<25 * 4 * 4, 256, 0, stream>>>(f1b, Wff2b + (size_t)L * 512 * 1024,
        nullptr, nullptr, encP, 1024, 512, 25, 4, (size_t)ROWS * 512);
    reduce_kernel<0, 1, 0><<<dim3(1, ROWS), 256, 0, stream>>>(encP, (size_t)ROWS * 512, 4,
        enc_ff2_b + L * 512, f2f, nullptr, 512, nullptr);
    ln_kernel<<<ROWS, 256, 0, stream>>>(hf, f2f, enc_ln2_g + L * 512, enc_ln2_b + L * 512, hf, hb);
  }
  ln_kernel<<<ROWS, 256, 0, stream>>>(hf, nullptr, enc_lnf_g, enc_lnf_b, memf, memb);

  // ---- phase 3: decoder (Sq=1; self-attn softmax over 1 key == 1 -> out=V) ----
  fill_kernel<<<(32 * 512 + 255) / 256, 256, 0, stream>>>(tbuf, 32 * 512, 1.0f);
  for (int L = 0; L < 2; ++L) {
    sgemm32<0><<<8, 256, 0, stream>>>(tbuf, dec_sa_qkv_w + (size_t)L * 1536 * 512 + (size_t)1024 * 512,
                                      dec_sa_qkv_b + L * 1536 + 1024, tv, 512, 512);
    sgemm32<0><<<8, 256, 0, stream>>>(tv, dec_sa_proj_w + (size_t)L * 512 * 512,
                                      dec_sa_proj_b + L * 512, so, 512, 512);
    ln_kernel<<<32, 256, 0, stream>>>(tbuf, so, dec_ln1_g + L * 512, dec_ln1_b + L * 512, tbuf, nullptr);

    sgemm32<0><<<8, 256, 0, stream>>>(tbuf, dec_ca_qkv_w + (size_t)L * 1536 * 512,
                                      dec_ca_qkv_b + L * 1536, qdv, 512, 512);
    gemm_bf16<0><<<25 * 8 * 2, 256, 0, stream>>>(memb, Wdkvb + ((size_t)L * 1536 + 512) * 512,
        nullptr, nullptr, encP, 512, 1024, 25, 2, (size_t)ROWS * 1024);
    reduce_kernel<0, 1, 0><<<dim3(1, ROWS), 256, 0, stream>>>(encP, (size_t)ROWS * 1024, 2,
        dec_ca_qkv_b + L * 1536 + 512, kvbuf, nullptr, 1024, nullptr);
    dec_attn_kernel<<<128, 256, 0, stream>>>(qdv, kvbuf, cav);
    sgemm32<0><<<8, 256, 0, stream>>>(cav, dec_ca_proj_w + (size_t)L * 512 * 512,
                                      dec_ca_proj_b + L * 512, cov, 512, 512);
    ln_kernel<<<32, 256, 0, stream>>>(tbuf, cov, dec_ln2_g + L * 512, dec_ln2_b + L * 512, tbuf, nullptr);

    sgemm32<1><<<16, 256, 0, stream>>>(tbuf, dec_ff1_w + (size_t)L * 1024 * 512,
                                       dec_ff1_b + L * 1024, tf1, 1024, 512);
    sgemm32<0><<<8, 256, 0, stream>>>(tf1, dec_ff2_w + (size_t)L * 512 * 1024,
                                      dec_ff2_b + L * 512, tf2, 512, 1024);
    ln_kernel<<<32, 256, 0, stream>>>(tbuf, tf2, dec_ln3_g + L * 512, dec_ln3_b + L * 512, tbuf, nullptr);
  }
  ln_kernel<<<32, 256, 0, stream>>>(tbuf, nullptr, dec_lnf_g, dec_lnf_b, tbuf, nullptr);

  // ---- phase 4: output MLP + pool ----
  sgemm32<1><<<32, 256, 0, stream>>>(tbuf, out1_w, out1_b, o1, 2048, 512);
  sgemm32<1><<<64, 256, 0, stream>>>(o1, out2_w, out2_b, o2, 4096, 2048);
  sgemm32<1><<<249, 256, 0, stream>>>(o2, out3_w, out3_b, o3, FLATIN, 4096);
  pool_kernel<<<(32 * 135 * 103 + 255) / 256, 256, 0, stream>>>(o3, (float*)d_out);
}

// Round 6
// 2089.181 us; speedup vs baseline: 1.4474x; 1.2179x over previous
//
#include <hip/hip_runtime.h>
#include <hip/hip_bf16.h>

// ---------------------------------------------------------------------------
// Sizes
#define SEQ   100
#define BATCH 32
#define NH    4
#define HDIM  128
#define DMODEL 512
#define FLATIN 15873
#define KPAD1  16384        // FLATIN padded so K splits evenly
#define ROWS   3200         // BATCH*SEQ
#define MPAD   3328         // ROWS (+1 zero row) padded to multiple of 128
#define NOUT3  16000        // FLATIN padded to multiple of 128

typedef __attribute__((ext_vector_type(8))) short short8;
typedef __attribute__((ext_vector_type(4))) short short4v;
typedef __attribute__((ext_vector_type(4))) float f32x4;

__device__ __forceinline__ void gload_lds16(const void* g, void* l) {
  __builtin_amdgcn_global_load_lds((const __attribute__((address_space(1))) void*)g,
                                   (__attribute__((address_space(3))) void*)l, 16, 0, 0);
}

// bijective XCD chunk swizzle (m204)
__device__ __forceinline__ int xcd_swizzle(int id, int nwg) {
  const int q = nwg >> 3, r = nwg & 7;
  const int x = id & 7, p = id >> 3;
  return (x < r ? x * (q + 1) : r * (q + 1) + (x - r) * q) + p;
}

// ---------------------------------------------------------------------------
// bf16 MFMA GEMM, split-K, partial-output: P[ks][m][n] = sum_{k in slice} A*W
// A: M x K bf16 (lda=K), W: N x K bf16 (ldb=K). K % (64*ksl) == 0.
// grid = mtiles * ntile * ksl (1-D), block = 256 (4 waves, 2x2, 64x64/wave).
// Linearization mt-MINOR: wg%mtiles = mt, wg/mtiles = (nt,ks). Consecutive
// ids share the W panel K-slice (L2-resident) and spread active mts evenly
// across XCD chunks (early-exit blocks interleave, no idle XCDs).
// GATHER: A row = idx[m0+row]. cnt: blocks with m0 >= cnt[0] exit.
template<int GATHER>
__global__ __launch_bounds__(256)
void gemm_bf16(const __hip_bfloat16* __restrict__ A, const __hip_bfloat16* __restrict__ W,
               const int* __restrict__ idx, const int* __restrict__ cnt,
               float* __restrict__ P,
               int K, int ldc, int mtiles, int ksl, size_t pstride)
{
  __shared__ __align__(16) short lds[16384];     // As 128x64 | Bs 128x64 (32KB)
  short* As = lds;
  short* Bs = lds + 8192;
  const int wg = xcd_swizzle(blockIdx.x, gridDim.x);
  const int mt = wg % mtiles;
  const int g  = wg / mtiles;
  const int nt = g / ksl;
  const int ks = g % ksl;
  const int m0 = mt << 7;
  const int n0 = nt << 7;
  if (cnt && m0 >= cnt[0]) return;
  const int Klen = K / ksl;
  const int kbeg = ks * Klen;
  const int kend = kbeg + Klen;

  const int tid  = threadIdx.x;
  const int lane = tid & 63;
  const int wid  = tid >> 6;
  const int wr = (wid >> 1) << 6;
  const int wc = (wid & 1) << 6;

  f32x4 acc[4][4];
#pragma unroll
  for (int i = 0; i < 4; ++i)
#pragma unroll
    for (int j = 0; j < 4; ++j) acc[i][j] = (f32x4){0.f, 0.f, 0.f, 0.f};

  const int srow = (wid << 3) + (lane >> 3);   // 0..31
  const int scs  = lane & 7;                   // 16B chunk slot
  const int gcol = ((scs ^ (srow & 7)) << 3);  // inverse-swizzled source col

  const __hip_bfloat16* arow[4];
  const __hip_bfloat16* brow[4];
#pragma unroll
  for (int j = 0; j < 4; ++j) {
    const int row = (j << 5) + srow;
    const int gr = GATHER ? idx[m0 + row] : (m0 + row);
    arow[j] = A + (size_t)gr * K + gcol;
    brow[j] = W + (size_t)(n0 + row) * K + gcol;
  }

  for (int k0 = kbeg; k0 < kend; k0 += 64) {
    __syncthreads();
#pragma unroll
    for (int j = 0; j < 4; ++j) {
      short* la = As + (((j << 2) + wid) << 9);          // wave-uniform base
      short* lb = Bs + (((j << 2) + wid) << 9);
      gload_lds16(arow[j] + k0, la);
      gload_lds16(brow[j] + k0, lb);
    }
    __syncthreads();
#pragma unroll
    for (int kk = 0; kk < 2; ++kk) {
      short8 af[4], bfv[4];
#pragma unroll
      for (int i = 0; i < 4; ++i) {
        const int mr = wr + (i << 4) + (lane & 15);
        const int cg = (kk << 2) + (lane >> 4);
        af[i]  = *(const short8*)(As + mr * 64 + ((cg ^ (mr & 7)) << 3));
        const int nr = wc + (i << 4) + (lane & 15);
        bfv[i] = *(const short8*)(Bs + nr * 64 + ((cg ^ (nr & 7)) << 3));
      }
#pragma unroll
      for (int i = 0; i < 4; ++i)
#pragma unroll
        for (int j = 0; j < 4; ++j)
          acc[i][j] = __builtin_amdgcn_mfma_f32_16x16x32_bf16(af[i], bfv[j], acc[i][j], 0, 0, 0);
    }
  }

  // epilogue: C/D mapping col = lane&15, row = (lane>>4)*4 + r   [m89/m91]
  float* Pout = P + (size_t)ks * pstride;
  const int fr = lane & 15, fq = lane >> 4;
#pragma unroll
  for (int j = 0; j < 4; ++j) {
    const int n = n0 + wc + (j << 4) + fr;
#pragma unroll
    for (int i = 0; i < 4; ++i) {
#pragma unroll
      for (int r = 0; r < 4; ++r) {
        const int m = m0 + wr + (i << 4) + (fq << 2) + r;
        Pout[(size_t)m * ldc + n] = acc[i][j][r];
      }
    }
  }
}

// ---------------------------------------------------------------------------
// Split-K reduce: C = sum_ks P[ks] + bias [, relu]; fp32 and/or bf16 out.
// grid = (ceil(N/1024), rows), block 256, float4 per thread.
template<int RELU, int OF32, int OB16>
__global__ __launch_bounds__(256)
void reduce_kernel(const float* __restrict__ P, size_t pstride, int ksl,
                   const float* __restrict__ bias, float* __restrict__ Cf,
                   __hip_bfloat16* __restrict__ Cb, int N,
                   const int* __restrict__ cnt)
{
  const int row = blockIdx.y;
  if (cnt) { const int cp = (cnt[0] + 127) & ~127; if (row >= cp) return; }
  const int n = (blockIdx.x * 256 + threadIdx.x) * 4;
  if (n >= N) return;
  const size_t o = (size_t)row * N + n;
  const float4 b4 = *(const float4*)(bias + n);
  float4 s = *(const float4*)(P + o);
  for (int k = 1; k < ksl; ++k) {
    const float4 p = *(const float4*)(P + (size_t)k * pstride + o);
    s.x += p.x; s.y += p.y; s.z += p.z; s.w += p.w;
  }
  s.x += b4.x; s.y += b4.y; s.z += b4.z; s.w += b4.w;
  if (RELU) {
    s.x = fmaxf(s.x, 0.f); s.y = fmaxf(s.y, 0.f);
    s.z = fmaxf(s.z, 0.f); s.w = fmaxf(s.w, 0.f);
  }
  if (OF32) *(float4*)(Cf + o) = s;
  if (OB16) {
    union { short4v v; __hip_bfloat16 h[4]; } u;
    u.h[0] = __float2bfloat16(s.x);
    u.h[1] = __float2bfloat16(s.y);
    u.h[2] = __float2bfloat16(s.z);
    u.h[3] = __float2bfloat16(s.w);
    *(short4v*)(Cb + o) = u.v;
  }
}

// ---------------------------------------------------------------------------
// x (B,S,143,111) fp32 -> xb (MPAD x KPAD1) bf16 (zero pad), nz flags
__global__ __launch_bounds__(256)
void conv_x_kernel(const float* __restrict__ x, __hip_bfloat16* __restrict__ xb,
                   int* __restrict__ nz)
{
  __shared__ int sred[4];
  const int m = blockIdx.x;               // 0..MPAD-1
  const int valid = (m < ROWS);
  const float* src = x + (size_t)m * FLATIN;
  __hip_bfloat16* dst = xb + (size_t)m * KPAD1;
  int any = 0;
  for (int c = threadIdx.x; c < (KPAD1 >> 1); c += 256) {
    const int c0 = 2 * c;
    const float v0 = (valid && c0 < FLATIN) ? src[c0] : 0.f;
    const float v1 = (valid && c0 + 1 < FLATIN) ? src[c0 + 1] : 0.f;
    any |= (v0 != 0.f) | (v1 != 0.f);
    __hip_bfloat162 pr;
    pr.x = __float2bfloat16(v0);
    pr.y = __float2bfloat16(v1);
    *(__hip_bfloat162*)(dst + c0) = pr;
  }
  any = __any(any) ? 1 : 0;
  if ((threadIdx.x & 63) == 0) sred[threadIdx.x >> 6] = any;
  __syncthreads();
  if (valid && threadIdx.x == 0) nz[m] = sred[0] | sred[1] | sred[2] | sred[3];
}

// padding[b,s] = (s>0) && !any(nz[b,k] for k>=s)
__global__ void mask_kernel(const int* __restrict__ nz, int* __restrict__ pad)
{
  const int b = threadIdx.x;
  if (b >= 32) return;
  int any = 0;
  for (int s = 99; s >= 0; --s) {
    any |= nz[b * 100 + s];
    pad[b * 100 + s] = (s > 0 && !any) ? 1 : 0;
  }
}

// Compaction: idx[p] = p-th nonzero row; pos[m] = compact slot (zero -> count);
// cnt[0] = count+1 (canonical zero row gathers xb row 3200 = zeros).
__global__ __launch_bounds__(256)
void compact_kernel(const int* __restrict__ nz, int* __restrict__ idx,
                    int* __restrict__ pos, int* __restrict__ cnt)
{
  __shared__ int wsum[4];
  __shared__ int total;
  const int t = threadIdx.x;
  int loc[13];
  int c = 0;
#pragma unroll
  for (int i = 0; i < 13; ++i) {
    const int m = t * 13 + i;
    loc[i] = (m < ROWS) ? nz[m] : 0;
    c += loc[i];
  }
  int v = c;
#pragma unroll
  for (int o = 1; o < 64; o <<= 1) {
    const int u = __shfl_up(v, o);
    if ((t & 63) >= o) v += u;
  }
  if ((t & 63) == 63) wsum[t >> 6] = v;
  __syncthreads();
  int wbase = 0;
  for (int w = 0; w < (t >> 6); ++w) wbase += wsum[w];
  int p = wbase + v - c;                 // exclusive prefix
#pragma unroll
  for (int i = 0; i < 13; ++i) {
    const int m = t * 13 + i;
    if (m < ROWS) {
      if (loc[i]) { idx[p] = m; pos[m] = p; ++p; }
      else pos[m] = -1;
    }
  }
  if (t == 255) total = p;
  __syncthreads();
  const int count = total;
  if (t == 0) cnt[0] = count + 1;
  for (int i = count + t; i < MPAD; i += 256) idx[i] = ROWS;
  for (int m = t; m < ROWS; m += 256) if (pos[m] < 0) pos[m] = count;
}

__global__ void pe_kernel(float* __restrict__ pe)
{
  const int i = blockIdx.x * 256 + threadIdx.x;
  if (i >= SEQ * 512) return;
  const int s = i >> 9, d = i & 511;
  const int d2 = d >> 1;
  const float div = expf((float)(2 * d2) * (-logf(10000.f) / 512.f));
  const float arg = (float)s * div;
  pe[i] = (d & 1) ? cosf(arg) : sinf(arg);
}

// fp32 -> bf16 pairwise with row AND column zero-pad (rows >= rin -> 0)
__global__ __launch_bounds__(256)
void cvt_pad_kernel(const float* __restrict__ in, __hip_bfloat16* __restrict__ out,
                    int rin, int cin, int cout)
{
  const int c = (blockIdx.x * 256 + threadIdx.x) * 2;
  const int r = blockIdx.y;
  if (c >= cout) return;
  const int rv = (r < rin);
  const float v0 = (rv && c < cin) ? in[(size_t)r * cin + c] : 0.f;
  const float v1 = (rv && c + 1 < cin) ? in[(size_t)r * cin + c + 1] : 0.f;
  __hip_bfloat162 pr;
  pr.x = __float2bfloat16(v0);
  pr.y = __float2bfloat16(v1);
  *(__hip_bfloat162*)(out + (size_t)r * cout + c) = pr;
}

__global__ void fill_kernel(float* __restrict__ p, int n, float v)
{
  const int i = blockIdx.x * 256 + threadIdx.x;
  if (i < n) p[i] = v;
}

// fc3 reduce + bias + relu + scatter to (s*32+b) + PE; fp32 + bf16 mirrors
__global__ __launch_bounds__(256)
void scatter_pe_reduce(const float* __restrict__ P, size_t pstride, int ksl,
                       const int* __restrict__ pos, const float* __restrict__ bias,
                       const float* __restrict__ pe, float* __restrict__ hf,
                       __hip_bfloat16* __restrict__ hb)
{
  const int m = blockIdx.x;               // orig row b*100+s
  const int s = m % 100, b = m / 100;
  const int src = pos[m];
  const int t = threadIdx.x;
  const size_t sb = (size_t)src * 512;
  const size_t db = (size_t)(s * 32 + b) * 512;
#pragma unroll
  for (int u = 0; u < 2; ++u) {
    const int d = t + u * 256;
    float v = bias[d];
    for (int k = 0; k < ksl; ++k) v += P[(size_t)k * pstride + sb + d];
    v = fmaxf(v, 0.f) + pe[s * 512 + d];
    hf[db + d] = v;
    hb[db + d] = __float2bfloat16(v);
  }
}

// ---------------------------------------------------------------------------
// LayerNorm over D=512
__global__ __launch_bounds__(256)
void ln_kernel(const float* __restrict__ x, const float* __restrict__ res,
               const float* __restrict__ g, const float* __restrict__ bta,
               float* __restrict__ y, __hip_bfloat16* __restrict__ yb)
{
  __shared__ float rs[4], rss[4];
  const int row = blockIdx.x;
  const int t = threadIdx.x;
  const size_t base = (size_t)row * 512;
  float v0 = x[base + t];
  float v1 = x[base + t + 256];
  if (res) { v0 += res[base + t]; v1 += res[base + t + 256]; }
  float s = v0 + v1, ss = v0 * v0 + v1 * v1;
#pragma unroll
  for (int o = 32; o > 0; o >>= 1) { s += __shfl_xor(s, o); ss += __shfl_xor(ss, o); }
  if ((t & 63) == 0) { rs[t >> 6] = s; rss[t >> 6] = ss; }
  __syncthreads();
  s = rs[0] + rs[1] + rs[2] + rs[3];
  ss = rss[0] + rss[1] + rss[2] + rss[3];
  const float mean = s * (1.f / 512.f);
  const float var = ss * (1.f / 512.f) - mean * mean;
  const float inv = rsqrtf(var + 1e-5f);
  const float o0 = (v0 - mean) * inv * g[t] + bta[t];
  const float o1 = (v1 - mean) * inv * g[t + 256] + bta[t + 256];
  y[base + t] = o0;
  y[base + t + 256] = o1;
  if (yb) {
    yb[base + t] = __float2bfloat16(o0);
    yb[base + t + 256] = __float2bfloat16(o1);
  }
}

// ---------------------------------------------------------------------------
// Encoder self-attention. qkv: (3200 rows = s*32+b, 1536) fp32: q|k|v.
__global__ __launch_bounds__(256)
void enc_attn_kernel(const float* __restrict__ qkv, const int* __restrict__ pad,
                     __hip_bfloat16* __restrict__ ob)
{
  __shared__ float Ks[100][129];
  __shared__ float Qs[128];
  __shared__ float Ps[100];
  __shared__ float red[4];
  const int bh = blockIdx.x;
  const int b = bh >> 2, h = bh & 3;
  const int q0 = blockIdx.y * 25;
  const int t = threadIdx.x;
  for (int i = t; i < 12800; i += 256) {
    const int s = i >> 7, d = i & 127;
    Ks[s][d] = qkv[(size_t)(s * 32 + b) * 1536 + 512 + h * 128 + d];
  }
  const int masked = (t < 100) ? pad[b * 100 + t] : 0;
  const float scale = 0.08838834764831845f;
  for (int qi = 0; qi < 25; ++qi) {
    const int q = q0 + qi;
    __syncthreads();
    if (t < 128) Qs[t] = qkv[(size_t)(q * 32 + b) * 1536 + h * 128 + t];
    __syncthreads();
    float sc = -3e38f;
    if (t < 100) {
      const float* kr = &Ks[t][0];
      float a = 0.f;
#pragma unroll 16
      for (int d = 0; d < 128; ++d) a += Qs[d] * kr[d];
      sc = masked ? -1e9f : (a * scale);
    }
    float mx = sc;
#pragma unroll
    for (int o = 32; o > 0; o >>= 1) mx = fmaxf(mx, __shfl_xor(mx, o));
    if ((t & 63) == 0) red[t >> 6] = mx;
    __syncthreads();
    mx = fmaxf(fmaxf(red[0], red[1]), fmaxf(red[2], red[3]));
    const float e = (t < 100) ? expf(sc - mx) : 0.f;
    float sm = e;
#pragma unroll
    for (int o = 32; o > 0; o >>= 1) sm += __shfl_xor(sm, o);
    __syncthreads();
    if ((t & 63) == 0) red[t >> 6] = sm;
    __syncthreads();
    sm = red[0] + red[1] + red[2] + red[3];
    if (t < 100) Ps[t] = e;
    __syncthreads();
    if (t < 128) {
      float a = 0.f;
      const float* vb = qkv + 1024 + h * 128 + t;
      for (int k = 0; k < 100; ++k) a += Ps[k] * vb[(size_t)(k * 32 + b) * 1536];
      ob[(size_t)(q * 32 + b) * 512 + h * 128 + t] = __float2bfloat16(a / sm);
    }
  }
}

// Decoder cross-attention (Sq=1). qd: (32 x 512). kv: (3200 x 1024) k|v.
__global__ __launch_bounds__(256)
void dec_attn_kernel(const float* __restrict__ qd, const float* __restrict__ kv,
                     float* __restrict__ ca)
{
  __shared__ float Qs[128];
  __shared__ float Ps[100];
  __shared__ float red[4];
  const int bh = blockIdx.x;
  const int b = bh >> 2, h = bh & 3;
  const int t = threadIdx.x;
  if (t < 128) Qs[t] = qd[b * 512 + h * 128 + t];
  __syncthreads();
  float sc = -3e38f;
  if (t < 100) {
    const float* kr = kv + (size_t)(t * 32 + b) * 1024 + h * 128;
    float a = 0.f;
#pragma unroll 16
    for (int d = 0; d < 128; ++d) a += Qs[d] * kr[d];
    sc = a * 0.08838834764831845f;
  }
  float mx = sc;
#pragma unroll
  for (int o = 32; o > 0; o >>= 1) mx = fmaxf(mx, __shfl_xor(mx, o));
  if ((t & 63) == 0) red[t >> 6] = mx;
  __syncthreads();
  mx = fmaxf(fmaxf(red[0], red[1]), fmaxf(red[2], red[3]));
  const float e = (t < 100) ? expf(sc - mx) : 0.f;
  float sm = e;
#pragma unroll
  for (int o = 32; o > 0; o >>= 1) sm += __shfl_xor(sm, o);
  __syncthreads();
  if ((t & 63) == 0) red[t >> 6] = sm;
  __syncthreads();
  sm = red[0] + red[1] + red[2] + red[3];
  if (t < 100) Ps[t] = e;
  __syncthreads();
  if (t < 128) {
    float a = 0.f;
    const float* vb = kv + 512 + h * 128 + t;
    for (int k = 0; k < 100; ++k) a += Ps[k] * vb[(size_t)(k * 32 + b) * 1024];
    ca[b * 512 + h * 128 + t] = a / sm;
  }
}

// ---------------------------------------------------------------------------
// Small fp32 GEMM, M=32: C(32,N) = A(32,K) @ W(N,K)^T + bias [, relu]
template<int RELU>
__global__ __launch_bounds__(256)
void sgemm32(const float* __restrict__ A, const float* __restrict__ W,
             const float* __restrict__ bias, float* __restrict__ C, int N, int K)
{
  const int t = threadIdx.x;
  const int n = t & 63;
  const int mg = __builtin_amdgcn_readfirstlane(t >> 6);
  const int gn = blockIdx.x * 64 + n;
  const size_t wrow = (gn < N) ? (size_t)gn : 0;
  const float4* wp = (const float4*)(W + wrow * K);
  const float* Abase = A + (size_t)mg * 8 * K;
  float acc[8] = {0.f, 0.f, 0.f, 0.f, 0.f, 0.f, 0.f, 0.f};
  const int nk4 = K >> 2;
  for (int k4 = 0; k4 < nk4; ++k4) {
    const float4 wv = wp[k4];
#pragma unroll
    for (int i = 0; i < 8; ++i) {
      const float4 av = *(const float4*)(Abase + (size_t)i * K + k4 * 4);
      acc[i] += av.x * wv.x + av.y * wv.y + av.z * wv.z + av.w * wv.w;
    }
  }
  if (gn < N) {
    const float bb = bias[gn];
#pragma unroll
    for (int i = 0; i < 8; ++i) {
      float v = acc[i] + bb;
      if (RELU) v = fmaxf(v, 0.f);
      C[(size_t)(mg * 8 + i) * N + gn] = v;
    }
  }
}

// ---------------------------------------------------------------------------
// Adaptive avg pool (143,111) -> (135,103), fp32; o3p row stride NOUT3
__global__ __launch_bounds__(256)
void pool_kernel(const float* __restrict__ o3p, float* __restrict__ out)
{
  const int i = blockIdx.x * 256 + threadIdx.x;
  if (i >= 32 * 135 * 103) return;
  const int j = i % 103;
  const int tmp = i / 103;
  const int r = tmp % 135;
  const int b = tmp / 135;
  const int rs = (r * 143) / 135, re = ((r + 1) * 143 + 134) / 135;
  const int cs = (j * 111) / 103, ce = ((j + 1) * 111 + 102) / 103;
  float s = 0.f;
  for (int rr = rs; rr < re; ++rr)
    for (int cc = cs; cc < ce; ++cc)
      s += o3p[(size_t)b * NOUT3 + rr * 111 + cc];
  out[i] = s / (float)((re - rs) * (ce - cs));
}

// ---------------------------------------------------------------------------
extern "C" void kernel_launch(void* const* d_in, const int* in_sizes, int n_in,
                              void* d_out, int out_size, void* d_ws, size_t ws_size,
                              hipStream_t stream)
{
  (void)in_sizes; (void)n_in; (void)out_size; (void)ws_size;

  const float* x          = (const float*)d_in[0];
  const float* fc1_w      = (const float*)d_in[1];
  const float* fc1_b      = (const float*)d_in[2];
  const float* fc2_w      = (const float*)d_in[3];
  const float* fc2_b      = (const float*)d_in[4];
  const float* fc3_w      = (const float*)d_in[5];
  const float* fc3_b      = (const float*)d_in[6];
  const float* out1_w     = (const float*)d_in[7];
  const float* out1_b     = (const float*)d_in[8];
  const float* out2_w     = (const float*)d_in[9];
  const float* out2_b     = (const float*)d_in[10];
  const float* out3_w     = (const float*)d_in[11];
  const float* out3_b     = (const float*)d_in[12];
  const float* enc_qkv_w  = (const float*)d_in[13];
  const float* enc_qkv_b  = (const float*)d_in[14];
  const float* enc_proj_w = (const float*)d_in[15];
  const float* enc_proj_b = (const float*)d_in[16];
  const float* enc_ff1_w  = (const float*)d_in[17];
  const float* enc_ff1_b  = (const float*)d_in[18];
  const float* enc_ff2_w  = (const float*)d_in[19];
  const float* enc_ff2_b  = (const float*)d_in[20];
  const float* enc_ln1_g  = (const float*)d_in[21];
  const float* enc_ln1_b  = (const float*)d_in[22];
  const float* enc_ln2_g  = (const float*)d_in[23];
  const float* enc_ln2_b  = (const float*)d_in[24];
  const float* enc_lnf_g  = (const float*)d_in[25];
  const float* enc_lnf_b  = (const float*)d_in[26];
  const float* dec_sa_qkv_w  = (const float*)d_in[27];
  const float* dec_sa_qkv_b  = (const float*)d_in[28];
  const float* dec_sa_proj_w = (const float*)d_in[29];
  const float* dec_sa_proj_b = (const float*)d_in[30];
  const float* dec_ca_qkv_w  = (const float*)d_in[31];
  const float* dec_ca_qkv_b  = (const float*)d_in[32];
  const float* dec_ca_proj_w = (const float*)d_in[33];
  const float* dec_ca_proj_b = (const float*)d_in[34];
  const float* dec_ff1_w  = (const float*)d_in[35];
  const float* dec_ff1_b  = (const float*)d_in[36];
  const float* dec_ff2_w  = (const float*)d_in[37];
  const float* dec_ff2_b  = (const float*)d_in[38];
  const float* dec_ln1_g  = (const float*)d_in[39];
  const float* dec_ln1_b  = (const float*)d_in[40];
  const float* dec_ln2_g  = (const float*)d_in[41];
  const float* dec_ln2_b  = (const float*)d_in[42];
  const float* dec_ln3_g  = (const float*)d_in[43];
  const float* dec_ln3_b  = (const float*)d_in[44];
  const float* dec_lnf_g  = (const float*)d_in[45];
  const float* dec_lnf_b  = (const float*)d_in[46];

  char* wsp = (char*)d_ws;
  size_t off = 0;
  auto alloc = [&](size_t nbytes) -> char* {
    char* p = wsp + off;
    off += (nbytes + 255) & ~(size_t)255;
    return p;
  };

  __hip_bfloat16* xb     = (__hip_bfloat16*)alloc((size_t)MPAD * KPAD1 * 2);
  __hip_bfloat16* Wb1    = (__hip_bfloat16*)alloc((size_t)4096 * KPAD1 * 2);
  __hip_bfloat16* Wb2    = (__hip_bfloat16*)alloc((size_t)2048 * 4096 * 2);
  __hip_bfloat16* Wb3    = (__hip_bfloat16*)alloc((size_t)512 * 2048 * 2);
  __hip_bfloat16* Wqkvb  = (__hip_bfloat16*)alloc((size_t)2 * 1536 * 512 * 2);
  __hip_bfloat16* Wprojb = (__hip_bfloat16*)alloc((size_t)2 * 512 * 512 * 2);
  __hip_bfloat16* Wff1b  = (__hip_bfloat16*)alloc((size_t)2 * 1024 * 512 * 2);
  __hip_bfloat16* Wff2b  = (__hip_bfloat16*)alloc((size_t)2 * 512 * 1024 * 2);
  __hip_bfloat16* Wdkvb  = (__hip_bfloat16*)alloc((size_t)2 * 1536 * 512 * 2);
  int*   nz      = (int*)alloc(ROWS * 4);
  int*   padmask = (int*)alloc(ROWS * 4);
  int*   idx     = (int*)alloc(MPAD * 4);
  int*   pos     = (int*)alloc(ROWS * 4);
  int*   cnt     = (int*)alloc(256);
  float* pe      = (float*)alloc((size_t)SEQ * 512 * 4);
  __hip_bfloat16* h1c = (__hip_bfloat16*)alloc((size_t)MPAD * 4096 * 2);
  __hip_bfloat16* h2c = (__hip_bfloat16*)alloc((size_t)MPAD * 2048 * 2);
  float* hf  = (float*)alloc((size_t)ROWS * 512 * 4);
  __hip_bfloat16* hb = (__hip_bfloat16*)alloc((size_t)ROWS * 512 * 2);
  float* qkvbuf = (float*)alloc((size_t)ROWS * 1536 * 4);
  __hip_bfloat16* attnb = (__hip_bfloat16*)alloc((size_t)ROWS * 512 * 2);
  float* pjf  = (float*)alloc((size_t)ROWS * 512 * 4);
  __hip_bfloat16* f1b = (__hip_bfloat16*)alloc((size_t)ROWS * 1024 * 2);
  float* f2f  = (float*)alloc((size_t)ROWS * 512 * 4);
  float* memf = (float*)alloc((size_t)ROWS * 512 * 4);
  __hip_bfloat16* memb = (__hip_bfloat16*)alloc((size_t)ROWS * 512 * 2);
  float* kvbuf = (float*)alloc((size_t)ROWS * 1024 * 4);
  float* tbuf = (float*)alloc(32 * 512 * 4);
  float* tv   = (float*)alloc(32 * 512 * 4);
  float* so   = (float*)alloc(32 * 512 * 4);
  float* qdv  = (float*)alloc(32 * 512 * 4);
  float* cav  = (float*)alloc(32 * 512 * 4);
  float* cov  = (float*)alloc(32 * 512 * 4);
  float* tf1  = (float*)alloc(32 * 1024 * 4);
  float* tf2  = (float*)alloc(32 * 512 * 4);
  float* o1   = (float*)alloc(32 * 2048 * 4);
  float* o3p  = (float*)alloc((size_t)32 * NOUT3 * 4);
  float* biasP = (float*)alloc(NOUT3 * 4);
  // split-K partial buffers (time-shared)
  float* fcP  = (float*)alloc((size_t)4 * MPAD * 4096 * 4);   // 218 MB
  float* encP = (float*)alloc((size_t)2 * ROWS * 1536 * 4);   // 39 MB

  // phase-4 aliases (fcP/encP are free after the decoder)
  float* outP = fcP;                                                        // <=33 MB
  __hip_bfloat16* Wo3b = (__hip_bfloat16*)((char*)fcP + ((size_t)48 << 20)); // 131 MB
  __hip_bfloat16* Wo2b = (__hip_bfloat16*)encP;                              // 16 MB
  __hip_bfloat16* o1b  = (__hip_bfloat16*)((char*)encP + ((size_t)20 << 20));
  __hip_bfloat16* o2b  = (__hip_bfloat16*)((char*)encP + ((size_t)22 << 20));

  const size_t psF1 = (size_t)MPAD * 4096;
  const size_t psF2 = (size_t)MPAD * 2048;
  const size_t psF3 = (size_t)MPAD * 512;

  // ---- phase 0: conversions, mask, compaction, PE ----
  conv_x_kernel<<<MPAD, 256, 0, stream>>>(x, xb, nz);
  mask_kernel<<<1, 64, 0, stream>>>(nz, padmask);
  compact_kernel<<<1, 256, 0, stream>>>(nz, idx, pos, cnt);
  pe_kernel<<<(SEQ * 512 + 255) / 256, 256, 0, stream>>>(pe);

  auto cvt = [&](const float* in, __hip_bfloat16* out, int rin, int rout, int cin, int cout) {
    cvt_pad_kernel<<<dim3((cout / 2 + 255) / 256, rout), 256, 0, stream>>>(in, out, rin, cin, cout);
  };
  cvt(fc1_w, Wb1, 4096, 4096, FLATIN, KPAD1);
  cvt(fc2_w, Wb2, 2048, 2048, 4096, 4096);
  cvt(fc3_w, Wb3, 512, 512, 2048, 2048);
  cvt(enc_qkv_w, Wqkvb, 2 * 1536, 2 * 1536, 512, 512);
  cvt(enc_proj_w, Wprojb, 2 * 512, 2 * 512, 512, 512);
  cvt(enc_ff1_w, Wff1b, 2 * 1024, 2 * 1024, 512, 512);
  cvt(enc_ff2_w, Wff2b, 2 * 512, 2 * 512, 1024, 1024);
  cvt(dec_ca_qkv_w, Wdkvb, 2 * 1536, 2 * 1536, 512, 512);

  // ---- phase 1: input MLP on compact rows (split-K) ----
  gemm_bf16<1><<<26 * 32 * 2, 256, 0, stream>>>(xb, Wb1, idx, cnt, fcP,
      KPAD1, 4096, 26, 2, psF1);
  reduce_kernel<1, 0, 1><<<dim3(4, MPAD), 256, 0, stream>>>(fcP, psF1, 2,
      fc1_b, nullptr, h1c, 4096, cnt);
  gemm_bf16<0><<<26 * 16 * 2, 256, 0, stream>>>(h1c, Wb2, nullptr, cnt, fcP,
      4096, 2048, 26, 2, psF2);
  reduce_kernel<1, 0, 1><<<dim3(2, MPAD), 256, 0, stream>>>(fcP, psF2, 2,
      fc2_b, nullptr, h2c, 2048, cnt);
  gemm_bf16<0><<<26 * 4 * 8, 256, 0, stream>>>(h2c, Wb3, nullptr, cnt, fcP,
      2048, 512, 26, 8, psF3);
  scatter_pe_reduce<<<ROWS, 256, 0, stream>>>(fcP, psF3, 8, pos, fc3_b, pe, hf, hb);

  // ---- phase 2: encoder ----
  for (int L = 0; L < 2; ++L) {
    gemm_bf16<0><<<25 * 12 * 2, 256, 0, stream>>>(hb, Wqkvb + (size_t)L * 1536 * 512,
        nullptr, nullptr, encP, 512, 1536, 25, 2, (size_t)ROWS * 1536);
    reduce_kernel<0, 1, 0><<<dim3(2, ROWS), 256, 0, stream>>>(encP, (size_t)ROWS * 1536, 2,
        enc_qkv_b + L * 1536, qkvbuf, nullptr, 1536, nullptr);
    enc_attn_kernel<<<dim3(128, 4), 256, 0, stream>>>(qkvbuf, padmask, attnb);
    gemm_bf16<0><<<25 * 4 * 4, 256, 0, stream>>>(attnb, Wprojb + (size_t)L * 512 * 512,
        nullptr, nullptr, encP, 512, 512, 25, 4, (size_t)ROWS * 512);
    reduce_kernel<0, 1, 0><<<dim3(1, ROWS), 256, 0, stream>>>(encP, (size_t)ROWS * 512, 4,
        enc_proj_b + L * 512, pjf, nullptr, 512, nullptr);
    ln_kernel<<<ROWS, 256, 0, stream>>>(hf, pjf, enc_ln1_g + L * 512, enc_ln1_b + L * 512, hf, hb);
    gemm_bf16<0><<<25 * 8 * 2, 256, 0, stream>>>(hb, Wff1b + (size_t)L * 1024 * 512,
        nullptr, nullptr, encP, 512, 1024, 25, 2, (size_t)ROWS * 1024);
    reduce_kernel<1, 0, 1><<<dim3(1, ROWS), 256, 0, stream>>>(encP, (size_t)ROWS * 1024, 2,
        enc_ff1_b + L * 1024, nullptr, f1b, 1024, nullptr);
    gemm_bf16<0><<<25 * 4 * 4, 256, 0, stream>>>(f1b, Wff2b + (size_t)L * 512 * 1024,
        nullptr, nullptr, encP, 1024, 512, 25, 4, (size_t)ROWS * 512);
    reduce_kernel<0, 1, 0><<<dim3(1, ROWS), 256, 0, stream>>>(encP, (size_t)ROWS * 512, 4,
        enc_ff2_b + L * 512, f2f, nullptr, 512, nullptr);
    ln_kernel<<<ROWS, 256, 0, stream>>>(hf, f2f, enc_ln2_g + L * 512, enc_ln2_b + L * 512, hf, hb);
  }
  ln_kernel<<<ROWS, 256, 0, stream>>>(hf, nullptr, enc_lnf_g, enc_lnf_b, memf, memb);

  // ---- phase 3: decoder (Sq=1; self-attn softmax over 1 key == 1 -> out=V) ----
  fill_kernel<<<(32 * 512 + 255) / 256, 256, 0, stream>>>(tbuf, 32 * 512, 1.0f);
  for (int L = 0; L < 2; ++L) {
    sgemm32<0><<<8, 256, 0, stream>>>(tbuf, dec_sa_qkv_w + (size_t)L * 1536 * 512 + (size_t)1024 * 512,
                                      dec_sa_qkv_b + L * 1536 + 1024, tv, 512, 512);
    sgemm32<0><<<8, 256, 0, stream>>>(tv, dec_sa_proj_w + (size_t)L * 512 * 512,
                                      dec_sa_proj_b + L * 512, so, 512, 512);
    ln_kernel<<<32, 256, 0, stream>>>(tbuf, so, dec_ln1_g + L * 512, dec_ln1_b + L * 512, tbuf, nullptr);

    sgemm32<0><<<8, 256, 0, stream>>>(tbuf, dec_ca_qkv_w + (size_t)L * 1536 * 512,
                                      dec_ca_qkv_b + L * 1536, qdv, 512, 512);
    gemm_bf16<0><<<25 * 8 * 2, 256, 0, stream>>>(memb, Wdkvb + ((size_t)L * 1536 + 512) * 512,
        nullptr, nullptr, encP, 512, 1024, 25, 2, (size_t)ROWS * 1024);
    reduce_kernel<0, 1, 0><<<dim3(1, ROWS), 256, 0, stream>>>(encP, (size_t)ROWS * 1024, 2,
        dec_ca_qkv_b + L * 1536 + 512, kvbuf, nullptr, 1024, nullptr);
    dec_attn_kernel<<<128, 256, 0, stream>>>(qdv, kvbuf, cav);
    sgemm32<0><<<8, 256, 0, stream>>>(cav, dec_ca_proj_w + (size_t)L * 512 * 512,
                                      dec_ca_proj_b + L * 512, cov, 512, 512);
    ln_kernel<<<32, 256, 0, stream>>>(tbuf, cov, dec_ln2_g + L * 512, dec_ln2_b + L * 512, tbuf, nullptr);

    sgemm32<1><<<16, 256, 0, stream>>>(tbuf, dec_ff1_w + (size_t)L * 1024 * 512,
                                       dec_ff1_b + L * 1024, tf1, 1024, 512);
    sgemm32<0><<<8, 256, 0, stream>>>(tf1, dec_ff2_w + (size_t)L * 512 * 1024,
                                      dec_ff2_b + L * 512, tf2, 512, 1024);
    ln_kernel<<<32, 256, 0, stream>>>(tbuf, tf2, dec_ln3_g + L * 512, dec_ln3_b + L * 512, tbuf, nullptr);
  }
  ln_kernel<<<32, 256, 0, stream>>>(tbuf, nullptr, dec_lnf_g, dec_lnf_b, tbuf, nullptr);

  // ---- phase 4: output MLP (out1 fp32; out2/out3 bf16 MFMA, M=128 pad) ----
  sgemm32<1><<<32, 256, 0, stream>>>(tbuf, out1_w, out1_b, o1, 2048, 512);
  cvt(o1, o1b, 32, 128, 2048, 2048);                // A2: 128x2048, pad rows 0
  cvt(out2_w, Wo2b, 4096, 4096, 2048, 2048);
  cvt(out3_w, Wo3b, FLATIN, NOUT3, 4096, 4096);     // pad rows 0
  fill_kernel<<<(NOUT3 + 255) / 256, 256, 0, stream>>>(biasP, NOUT3, 0.f);
  hipMemcpyAsync(biasP, out3_b, (size_t)FLATIN * sizeof(float),
                 hipMemcpyDeviceToDevice, stream);

  // out2: C(128,4096) = o1b(128,2048) @ Wo2b^T
  gemm_bf16<0><<<32 * 4, 256, 0, stream>>>(o1b, Wo2b, nullptr, nullptr, outP,
      2048, 4096, 1, 4, (size_t)128 * 4096);
  reduce_kernel<1, 0, 1><<<dim3(4, 128), 256, 0, stream>>>(outP, (size_t)128 * 4096, 4,
      out2_b, nullptr, o2b, 4096, nullptr);
  // out3: C(128,16000) = o2b(128,4096) @ Wo3b^T ; keep rows 0..31
  gemm_bf16<0><<<125 * 4, 256, 0, stream>>>(o2b, Wo3b, nullptr, nullptr, outP,
      4096, NOUT3, 1, 4, (size_t)128 * NOUT3);
  reduce_kernel<1, 1, 0><<<dim3(16, 32), 256, 0, stream>>>(outP, (size_t)128 * NOUT3, 4,
      biasP, o3p, nullptr, NOUT3, nullptr);

  pool_kernel<<<(32 * 135 * 103 + 255) / 256, 256, 0, stream>>>(o3p, (float*)d_out);
}

// Round 7
// 1744.282 us; speedup vs baseline: 1.7337x; 1.1977x over previous
//
#include <hip/hip_runtime.h>
#include <hip/hip_bf16.h>

// ---------------------------------------------------------------------------
#define SEQ   100
#define BATCH 32
#define FLATIN 15873
#define KPAD1  16384
#define ROWS   3200
#define MPAD   3328
#define NOUT3  16000

typedef __attribute__((ext_vector_type(8))) short short8;
typedef __attribute__((ext_vector_type(4))) short short4v;
typedef __attribute__((ext_vector_type(4))) float f32x4;

__device__ __forceinline__ void gload_lds16(const void* g, void* l) {
  __builtin_amdgcn_global_load_lds((const __attribute__((address_space(1))) void*)g,
                                   (__attribute__((address_space(3))) void*)l, 16, 0, 0);
}

// bijective XCD chunk swizzle (m204)
__device__ __forceinline__ int xcd_swizzle(int id, int nwg) {
  const int q = nwg >> 3, r = nwg & 7;
  const int x = id & 7, p = id >> 3;
  return (x < r ? x * (q + 1) : r * (q + 1) + (x - r) * q) + p;
}

// ---------------------------------------------------------------------------
// Shared GEMM body: stage 128x64 A/B tiles (both-sides chunk swizzle), MFMA.
#define GEMM_BODY(KBEG, KEND)                                                   \
  const int tid  = threadIdx.x;                                                 \
  const int lane = tid & 63;                                                    \
  const int wid  = tid >> 6;                                                    \
  const int wr = (wid >> 1) << 6;                                               \
  const int wc = (wid & 1) << 6;                                                \
  f32x4 acc[4][4];                                                              \
  _Pragma("unroll") for (int i = 0; i < 4; ++i)                                 \
  _Pragma("unroll") for (int j = 0; j < 4; ++j)                                 \
      acc[i][j] = (f32x4){0.f, 0.f, 0.f, 0.f};                                  \
  const int srow = (wid << 3) + (lane >> 3);                                    \
  const int scs  = lane & 7;                                                    \
  const int gcol = ((scs ^ (srow & 7)) << 3);                                   \
  const __hip_bfloat16* arow[4];                                                \
  const __hip_bfloat16* brow[4];                                                \
  _Pragma("unroll") for (int j = 0; j < 4; ++j) {                               \
    const int row = (j << 5) + srow;                                            \
    const int gr = GATHER ? idx[m0 + row] : (m0 + row);                         \
    arow[j] = A + (size_t)gr * K + gcol;                                        \
    brow[j] = W + (size_t)(n0 + row) * K + gcol;                                \
  }                                                                             \
  for (int k0 = (KBEG); k0 < (KEND); k0 += 64) {                                \
    __syncthreads();                                                            \
    _Pragma("unroll") for (int j = 0; j < 4; ++j) {                             \
      short* la = As + (((j << 2) + wid) << 9);                                 \
      short* lb = Bs + (((j << 2) + wid) << 9);                                 \
      gload_lds16(arow[j] + k0, la);                                            \
      gload_lds16(brow[j] + k0, lb);                                            \
    }                                                                           \
    __syncthreads();                                                            \
    _Pragma("unroll") for (int kk = 0; kk < 2; ++kk) {                          \
      short8 af[4], bfv[4];                                                     \
      _Pragma("unroll") for (int i = 0; i < 4; ++i) {                           \
        const int mr = wr + (i << 4) + (lane & 15);                             \
        const int cg = (kk << 2) + (lane >> 4);                                 \
        af[i]  = *(const short8*)(As + mr * 64 + ((cg ^ (mr & 7)) << 3));       \
        const int nr = wc + (i << 4) + (lane & 15);                             \
        bfv[i] = *(const short8*)(Bs + nr * 64 + ((cg ^ (nr & 7)) << 3));       \
      }                                                                         \
      _Pragma("unroll") for (int i = 0; i < 4; ++i)                             \
      _Pragma("unroll") for (int j = 0; j < 4; ++j)                             \
          acc[i][j] = __builtin_amdgcn_mfma_f32_16x16x32_bf16(af[i], bfv[j],    \
                                                              acc[i][j], 0,0,0);\
    }                                                                           \
  }

// Split-K partial-output GEMM (fc1/fc2/fc3, out2/out3). mt-minor linearization.
template<int GATHER>
__global__ __launch_bounds__(256)
void gemm_bf16(const __hip_bfloat16* __restrict__ A, const __hip_bfloat16* __restrict__ W,
               const int* __restrict__ idx, const int* __restrict__ cnt,
               float* __restrict__ P,
               int K, int ldc, int mtiles, int ksl, size_t pstride)
{
  __shared__ __align__(16) short lds[16384];
  short* As = lds;
  short* Bs = lds + 8192;
  const int wg = xcd_swizzle(blockIdx.x, gridDim.x);
  const int mt = wg % mtiles;
  const int g  = wg / mtiles;
  const int nt = g / ksl;
  const int ks = g % ksl;
  const int m0 = mt << 7;
  const int n0 = nt << 7;
  if (cnt && m0 >= cnt[0]) return;
  const int Klen = K / ksl;
  const int kbeg = ks * Klen;

  GEMM_BODY(kbeg, kbeg + Klen)

  float* Pout = P + (size_t)ks * pstride;
  const int fr = lane & 15, fq = lane >> 4;
#pragma unroll
  for (int j = 0; j < 4; ++j) {
    const int n = n0 + wc + (j << 4) + fr;
#pragma unroll
    for (int i = 0; i < 4; ++i)
#pragma unroll
      for (int r = 0; r < 4; ++r) {
        const int m = m0 + wr + (i << 4) + (fq << 2) + r;
        Pout[(size_t)m * ldc + n] = acc[i][j][r];
      }
  }
}

// Direct GEMM with fused bias/relu epilogue (encoder + decoder KV).
template<int RELU, int OF32, int OB16>
__global__ __launch_bounds__(256)
void gemm_direct(const __hip_bfloat16* __restrict__ A, const __hip_bfloat16* __restrict__ W,
                 const float* __restrict__ bias, float* __restrict__ Cf,
                 __hip_bfloat16* __restrict__ Cb, int K, int ldc, int mtiles)
{
  __shared__ __align__(16) short lds[16384];
  short* As = lds;
  short* Bs = lds + 8192;
  const int GATHER = 0;
  const int* idx = nullptr;
  const int wg = xcd_swizzle(blockIdx.x, gridDim.x);
  const int m0 = (wg % mtiles) << 7;
  const int n0 = (wg / mtiles) << 7;

  GEMM_BODY(0, K)

  const int fr = lane & 15, fq = lane >> 4;
#pragma unroll
  for (int j = 0; j < 4; ++j) {
    const int n = n0 + wc + (j << 4) + fr;
    const float bb = bias[n];
#pragma unroll
    for (int i = 0; i < 4; ++i)
#pragma unroll
      for (int r = 0; r < 4; ++r) {
        const int m = m0 + wr + (i << 4) + (fq << 2) + r;
        float v = acc[i][j][r] + bb;
        if (RELU) v = fmaxf(v, 0.f);
        if (OF32) Cf[(size_t)m * ldc + n] = v;
        if (OB16) Cb[(size_t)m * ldc + n] = __float2bfloat16(v);
      }
  }
}

// ---------------------------------------------------------------------------
// Split-K reduce: C = sum_ks P[ks] + bias [, relu]
template<int RELU, int OF32, int OB16>
__global__ __launch_bounds__(256)
void reduce_kernel(const float* __restrict__ P, size_t pstride, int ksl,
                   const float* __restrict__ bias, float* __restrict__ Cf,
                   __hip_bfloat16* __restrict__ Cb, int N,
                   const int* __restrict__ cnt)
{
  const int row = blockIdx.y;
  if (cnt) { const int cp = (cnt[0] + 127) & ~127; if (row >= cp) return; }
  const int n = (blockIdx.x * 256 + threadIdx.x) * 4;
  if (n >= N) return;
  const size_t o = (size_t)row * N + n;
  const float4 b4 = *(const float4*)(bias + n);
  float4 s = *(const float4*)(P + o);
  for (int k = 1; k < ksl; ++k) {
    const float4 p = *(const float4*)(P + (size_t)k * pstride + o);
    s.x += p.x; s.y += p.y; s.z += p.z; s.w += p.w;
  }
  s.x += b4.x; s.y += b4.y; s.z += b4.z; s.w += b4.w;
  if (RELU) {
    s.x = fmaxf(s.x, 0.f); s.y = fmaxf(s.y, 0.f);
    s.z = fmaxf(s.z, 0.f); s.w = fmaxf(s.w, 0.f);
  }
  if (OF32) *(float4*)(Cf + o) = s;
  if (OB16) {
    union { short4v v; __hip_bfloat16 h[4]; } u;
    u.h[0] = __float2bfloat16(s.x);
    u.h[1] = __float2bfloat16(s.y);
    u.h[2] = __float2bfloat16(s.z);
    u.h[3] = __float2bfloat16(s.w);
    *(short4v*)(Cb + o) = u.v;
  }
}

// ---------------------------------------------------------------------------
__global__ __launch_bounds__(256)
void conv_x_kernel(const float* __restrict__ x, __hip_bfloat16* __restrict__ xb,
                   int* __restrict__ nz)
{
  __shared__ int sred[4];
  const int m = blockIdx.x;
  const int valid = (m < ROWS);
  const float* src = x + (size_t)m * FLATIN;
  __hip_bfloat16* dst = xb + (size_t)m * KPAD1;
  int any = 0;
  for (int c = threadIdx.x; c < (KPAD1 >> 1); c += 256) {
    const int c0 = 2 * c;
    const float v0 = (valid && c0 < FLATIN) ? src[c0] : 0.f;
    const float v1 = (valid && c0 + 1 < FLATIN) ? src[c0 + 1] : 0.f;
    any |= (v0 != 0.f) | (v1 != 0.f);
    __hip_bfloat162 pr;
    pr.x = __float2bfloat16(v0);
    pr.y = __float2bfloat16(v1);
    *(__hip_bfloat162*)(dst + c0) = pr;
  }
  any = __any(any) ? 1 : 0;
  if ((threadIdx.x & 63) == 0) sred[threadIdx.x >> 6] = any;
  __syncthreads();
  if (valid && threadIdx.x == 0) nz[m] = sred[0] | sred[1] | sred[2] | sred[3];
}

__global__ void mask_kernel(const int* __restrict__ nz, int* __restrict__ pad)
{
  const int b = threadIdx.x;
  if (b >= 32) return;
  int any = 0;
  for (int s = 99; s >= 0; --s) {
    any |= nz[b * 100 + s];
    pad[b * 100 + s] = (s > 0 && !any) ? 1 : 0;
  }
}

__global__ __launch_bounds__(256)
void compact_kernel(const int* __restrict__ nz, int* __restrict__ idx,
                    int* __restrict__ pos, int* __restrict__ cnt)
{
  __shared__ int wsum[4];
  __shared__ int total;
  const int t = threadIdx.x;
  int loc[13];
  int c = 0;
#pragma unroll
  for (int i = 0; i < 13; ++i) {
    const int m = t * 13 + i;
    loc[i] = (m < ROWS) ? nz[m] : 0;
    c += loc[i];
  }
  int v = c;
#pragma unroll
  for (int o = 1; o < 64; o <<= 1) {
    const int u = __shfl_up(v, o);
    if ((t & 63) >= o) v += u;
  }
  if ((t & 63) == 63) wsum[t >> 6] = v;
  __syncthreads();
  int wbase = 0;
  for (int w = 0; w < (t >> 6); ++w) wbase += wsum[w];
  int p = wbase + v - c;
#pragma unroll
  for (int i = 0; i < 13; ++i) {
    const int m = t * 13 + i;
    if (m < ROWS) {
      if (loc[i]) { idx[p] = m; pos[m] = p; ++p; }
      else pos[m] = -1;
    }
  }
  if (t == 255) total = p;
  __syncthreads();
  const int count = total;
  if (t == 0) cnt[0] = count + 1;
  for (int i = count + t; i < MPAD; i += 256) idx[i] = ROWS;
  for (int m = t; m < ROWS; m += 256) if (pos[m] < 0) pos[m] = count;
}

__global__ void pe_kernel(float* __restrict__ pe)
{
  const int i = blockIdx.x * 256 + threadIdx.x;
  if (i >= SEQ * 512) return;
  const int s = i >> 9, d = i & 511;
  const int d2 = d >> 1;
  const float div = expf((float)(2 * d2) * (-logf(10000.f) / 512.f));
  const float arg = (float)s * div;
  pe[i] = (d & 1) ? cosf(arg) : sinf(arg);
}

// fp32 -> bf16 pairwise with row AND column zero-pad
__global__ __launch_bounds__(256)
void cvt_pad_kernel(const float* __restrict__ in, __hip_bfloat16* __restrict__ out,
                    int rin, int cin, int cout)
{
  const int c = (blockIdx.x * 256 + threadIdx.x) * 2;
  const int r = blockIdx.y;
  if (c >= cout) return;
  const int rv = (r < rin);
  const float v0 = (rv && c < cin) ? in[(size_t)r * cin + c] : 0.f;
  const float v1 = (rv && c + 1 < cin) ? in[(size_t)r * cin + c + 1] : 0.f;
  __hip_bfloat162 pr;
  pr.x = __float2bfloat16(v0);
  pr.y = __float2bfloat16(v1);
  *(__hip_bfloat162*)(out + (size_t)r * cout + c) = pr;
}

// Multi-segment flat fp32->bf16 (counts must be multiples of 2048)
struct CvtArgs {
  const float* src[8];
  __hip_bfloat16* dst[8];
  int cum[8];     // start chunk of each segment
};
__global__ __launch_bounds__(256)
void cvt_multi_kernel(CvtArgs a)
{
  const int bid = blockIdx.x;
  int seg = 0;
#pragma unroll
  for (int i = 1; i < 8; ++i) if (bid >= a.cum[i]) seg = i;
  const size_t e0 = ((size_t)(bid - a.cum[seg]) << 11) + (threadIdx.x << 3);
  const float4 v0 = *(const float4*)(a.src[seg] + e0);
  const float4 v1 = *(const float4*)(a.src[seg] + e0 + 4);
  union { short4v v; __hip_bfloat16 h[4]; } u0, u1;
  u0.h[0] = __float2bfloat16(v0.x); u0.h[1] = __float2bfloat16(v0.y);
  u0.h[2] = __float2bfloat16(v0.z); u0.h[3] = __float2bfloat16(v0.w);
  u1.h[0] = __float2bfloat16(v1.x); u1.h[1] = __float2bfloat16(v1.y);
  u1.h[2] = __float2bfloat16(v1.z); u1.h[3] = __float2bfloat16(v1.w);
  *(short4v*)(a.dst[seg] + e0) = u0.v;
  *(short4v*)(a.dst[seg] + e0 + 4) = u1.v;
}

__global__ void fill_kernel(float* __restrict__ p, int n, float v)
{
  const int i = blockIdx.x * 256 + threadIdx.x;
  if (i < n) p[i] = v;
}

// fc3 reduce + bias + relu + scatter + PE
__global__ __launch_bounds__(256)
void scatter_pe_reduce(const float* __restrict__ P, size_t pstride, int ksl,
                       const int* __restrict__ pos, const float* __restrict__ bias,
                       const float* __restrict__ pe, float* __restrict__ hf,
                       __hip_bfloat16* __restrict__ hb)
{
  const int m = blockIdx.x;
  const int s = m % 100, b = m / 100;
  const int src = pos[m];
  const int t = threadIdx.x;
  const size_t sb = (size_t)src * 512;
  const size_t db = (size_t)(s * 32 + b) * 512;
#pragma unroll
  for (int u = 0; u < 2; ++u) {
    const int d = t + u * 256;
    float v = bias[d];
    for (int k = 0; k < ksl; ++k) v += P[(size_t)k * pstride + sb + d];
    v = fmaxf(v, 0.f) + pe[s * 512 + d];
    hf[db + d] = v;
    hb[db + d] = __float2bfloat16(v);
  }
}

// ---------------------------------------------------------------------------
// LayerNorm over D=512 (encoder)
__global__ __launch_bounds__(256)
void ln_kernel(const float* __restrict__ x, const float* __restrict__ res,
               const float* __restrict__ g, const float* __restrict__ bta,
               float* __restrict__ y, __hip_bfloat16* __restrict__ yb)
{
  __shared__ float rs[4], rss[4];
  const int row = blockIdx.x;
  const int t = threadIdx.x;
  const size_t base = (size_t)row * 512;
  float v0 = x[base + t];
  float v1 = x[base + t + 256];
  if (res) { v0 += res[base + t]; v1 += res[base + t + 256]; }
  float s = v0 + v1, ss = v0 * v0 + v1 * v1;
#pragma unroll
  for (int o = 32; o > 0; o >>= 1) { s += __shfl_xor(s, o); ss += __shfl_xor(ss, o); }
  if ((t & 63) == 0) { rs[t >> 6] = s; rss[t >> 6] = ss; }
  __syncthreads();
  s = rs[0] + rs[1] + rs[2] + rs[3];
  ss = rss[0] + rss[1] + rss[2] + rss[3];
  const float mean = s * (1.f / 512.f);
  const float var = ss * (1.f / 512.f) - mean * mean;
  const float inv = rsqrtf(var + 1e-5f);
  const float o0 = (v0 - mean) * inv * g[t] + bta[t];
  const float o1 = (v1 - mean) * inv * g[t + 256] + bta[t + 256];
  y[base + t] = o0;
  y[base + t + 256] = o1;
  if (yb) {
    yb[base + t] = __float2bfloat16(o0);
    yb[base + t + 256] = __float2bfloat16(o1);
  }
}

// ---------------------------------------------------------------------------
// Encoder self-attention (unchanged)
__global__ __launch_bounds__(256)
void enc_attn_kernel(const float* __restrict__ qkv, const int* __restrict__ pad,
                     __hip_bfloat16* __restrict__ ob)
{
  __shared__ float Ks[100][129];
  __shared__ float Qs[128];
  __shared__ float Ps[100];
  __shared__ float red[4];
  const int bh = blockIdx.x;
  const int b = bh >> 2, h = bh & 3;
  const int q0 = blockIdx.y * 25;
  const int t = threadIdx.x;
  for (int i = t; i < 12800; i += 256) {
    const int s = i >> 7, d = i & 127;
    Ks[s][d] = qkv[(size_t)(s * 32 + b) * 1536 + 512 + h * 128 + d];
  }
  const int masked = (t < 100) ? pad[b * 100 + t] : 0;
  const float scale = 0.08838834764831845f;
  for (int qi = 0; qi < 25; ++qi) {
    const int q = q0 + qi;
    __syncthreads();
    if (t < 128) Qs[t] = qkv[(size_t)(q * 32 + b) * 1536 + h * 128 + t];
    __syncthreads();
    float sc = -3e38f;
    if (t < 100) {
      const float* kr = &Ks[t][0];
      float a = 0.f;
#pragma unroll 16
      for (int d = 0; d < 128; ++d) a += Qs[d] * kr[d];
      sc = masked ? -1e9f : (a * scale);
    }
    float mx = sc;
#pragma unroll
    for (int o = 32; o > 0; o >>= 1) mx = fmaxf(mx, __shfl_xor(mx, o));
    if ((t & 63) == 0) red[t >> 6] = mx;
    __syncthreads();
    mx = fmaxf(fmaxf(red[0], red[1]), fmaxf(red[2], red[3]));
    const float e = (t < 100) ? expf(sc - mx) : 0.f;
    float sm = e;
#pragma unroll
    for (int o = 32; o > 0; o >>= 1) sm += __shfl_xor(sm, o);
    __syncthreads();
    if ((t & 63) == 0) red[t >> 6] = sm;
    __syncthreads();
    sm = red[0] + red[1] + red[2] + red[3];
    if (t < 100) Ps[t] = e;
    __syncthreads();
    if (t < 128) {
      float a = 0.f;
      const float* vb = qkv + 1024 + h * 128 + t;
      for (int k = 0; k < 100; ++k) a += Ps[k] * vb[(size_t)(k * 32 + b) * 1536];
      ob[(size_t)(q * 32 + b) * 512 + h * 128 + t] = __float2bfloat16(a / sm);
    }
  }
}

// Decoder cross-attention (Sq=1)
__global__ __launch_bounds__(256)
void dec_attn_kernel(const float* __restrict__ qd, const float* __restrict__ kv,
                     float* __restrict__ ca)
{
  __shared__ float Qs[128];
  __shared__ float Ps[100];
  __shared__ float red[4];
  const int bh = blockIdx.x;
  const int b = bh >> 2, h = bh & 3;
  const int t = threadIdx.x;
  if (t < 128) Qs[t] = qd[b * 512 + h * 128 + t];
  __syncthreads();
  float sc = -3e38f;
  if (t < 100) {
    const float* kr = kv + (size_t)(t * 32 + b) * 1024 + h * 128;
    float a = 0.f;
#pragma unroll 16
    for (int d = 0; d < 128; ++d) a += Qs[d] * kr[d];
    sc = a * 0.08838834764831845f;
  }
  float mx = sc;
#pragma unroll
  for (int o = 32; o > 0; o >>= 1) mx = fmaxf(mx, __shfl_xor(mx, o));
  if ((t & 63) == 0) red[t >> 6] = mx;
  __syncthreads();
  mx = fmaxf(fmaxf(red[0], red[1]), fmaxf(red[2], red[3]));
  const float e = (t < 100) ? expf(sc - mx) : 0.f;
  float sm = e;
#pragma unroll
  for (int o = 32; o > 0; o >>= 1) sm += __shfl_xor(sm, o);
  __syncthreads();
  if ((t & 63) == 0) red[t >> 6] = sm;
  __syncthreads();
  sm = red[0] + red[1] + red[2] + red[3];
  if (t < 100) Ps[t] = e;
  __syncthreads();
  if (t < 128) {
    float a = 0.f;
    const float* vb = kv + 512 + h * 128 + t;
    for (int k = 0; k < 100; ++k) a += Ps[k] * vb[(size_t)(k * 32 + b) * 1024];
    ca[b * 512 + h * 128 + t] = a / sm;
  }
}

// ---------------------------------------------------------------------------
// Fused decoder kernels. One block per batch row r (grid 32, block 256).
// Block-level LN over 512 values (2 per thread).
#define BLOCK_LN(V0, V1, G, B, O0, O1)                                          \
  {                                                                             \
    float s_ = (V0) + (V1), ss_ = (V0) * (V0) + (V1) * (V1);                    \
    _Pragma("unroll")                                                           \
    for (int o_ = 32; o_ > 0; o_ >>= 1) {                                       \
      s_ += __shfl_xor(s_, o_); ss_ += __shfl_xor(ss_, o_);                     \
    }                                                                           \
    if ((tid & 63) == 0) { red[tid >> 6] = s_; red[4 + (tid >> 6)] = ss_; }     \
    __syncthreads();                                                            \
    s_ = red[0] + red[1] + red[2] + red[3];                                     \
    ss_ = red[4] + red[5] + red[6] + red[7];                                    \
    const float mean_ = s_ * (1.f / 512.f);                                     \
    const float inv_ = rsqrtf(ss_ * (1.f / 512.f) - mean_ * mean_ + 1e-5f);     \
    O0 = ((V0) - mean_) * inv_ * (G)[tid] + (B)[tid];                           \
    O1 = ((V1) - mean_) * inv_ * (G)[tid + 256] + (B)[tid + 256];               \
    __syncthreads();                                                            \
  }

__device__ __forceinline__ float dot512(const float* __restrict__ v,
                                        const float* __restrict__ wrow)
{
  const float4* wp = (const float4*)wrow;
  float a = 0.f;
#pragma unroll 8
  for (int k = 0; k < 128; ++k) {
    const float4 w = wp[k];
    a += v[4 * k] * w.x + v[4 * k + 1] * w.y + v[4 * k + 2] * w.z + v[4 * k + 3] * w.w;
  }
  return a;
}

// t' = LN1(t + proj(V(t))); qdv = t' @ Wq^T + bq      (decoder self-attn, Sq=1)
__global__ __launch_bounds__(256)
void dec_sa_ln_q(const float* __restrict__ t,
                 const float* __restrict__ Wv, const float* __restrict__ bv,
                 const float* __restrict__ Wp, const float* __restrict__ bp,
                 const float* __restrict__ g1, const float* __restrict__ b1,
                 const float* __restrict__ Wq, const float* __restrict__ bq,
                 float* __restrict__ tout, float* __restrict__ qdv)
{
  __shared__ float Ts[512], Vs[512];
  __shared__ float red[8];
  const int r = blockIdx.x, tid = threadIdx.x;
  Ts[tid] = t[r * 512 + tid];
  Ts[tid + 256] = t[r * 512 + tid + 256];
  __syncthreads();
  // tv = t @ Wv^T + bv
  float tv0 = dot512(Ts, Wv + (size_t)tid * 512) + bv[tid];
  float tv1 = dot512(Ts, Wv + (size_t)(tid + 256) * 512) + bv[tid + 256];
  Vs[tid] = tv0; Vs[tid + 256] = tv1;
  __syncthreads();
  // so = tv @ Wp^T + bp ; residual
  float r0 = dot512(Vs, Wp + (size_t)tid * 512) + bp[tid] + Ts[tid];
  float r1 = dot512(Vs, Wp + (size_t)(tid + 256) * 512) + bp[tid + 256] + Ts[tid + 256];
  __syncthreads();
  float o0, o1;
  BLOCK_LN(r0, r1, g1, b1, o0, o1)
  Ts[tid] = o0; Ts[tid + 256] = o1;
  tout[r * 512 + tid] = o0; tout[r * 512 + tid + 256] = o1;
  __syncthreads();
  qdv[r * 512 + tid] = dot512(Ts, Wq + (size_t)tid * 512) + bq[tid];
  qdv[r * 512 + tid + 256] = dot512(Ts, Wq + (size_t)(tid + 256) * 512) + bq[tid + 256];
}

// t' = LN3( t2 + FF(t2) ), t2 = LN2(t + proj(cav)); optional final LNf.
__global__ __launch_bounds__(256)
void dec_tail(const float* __restrict__ t, const float* __restrict__ cav,
              const float* __restrict__ Wcp, const float* __restrict__ bcp,
              const float* __restrict__ g2, const float* __restrict__ b2,
              const float* __restrict__ W1, const float* __restrict__ b1f,
              const float* __restrict__ W2, const float* __restrict__ b2f,
              const float* __restrict__ g3, const float* __restrict__ b3,
              const float* __restrict__ gf, const float* __restrict__ bf_,
              int dofinal, float* __restrict__ tout)
{
  __shared__ float Ts[512], Cs[512], F1[1024];
  __shared__ float red[8];
  const int r = blockIdx.x, tid = threadIdx.x;
  Ts[tid] = t[r * 512 + tid];
  Ts[tid + 256] = t[r * 512 + tid + 256];
  Cs[tid] = cav[r * 512 + tid];
  Cs[tid + 256] = cav[r * 512 + tid + 256];
  __syncthreads();
  // cov + residual
  float r0 = dot512(Cs, Wcp + (size_t)tid * 512) + bcp[tid] + Ts[tid];
  float r1 = dot512(Cs, Wcp + (size_t)(tid + 256) * 512) + bcp[tid + 256] + Ts[tid + 256];
  __syncthreads();
  float t20, t21;
  BLOCK_LN(r0, r1, g2, b2, t20, t21)
  Ts[tid] = t20; Ts[tid + 256] = t21;
  __syncthreads();
  // ff1 (1024 outputs, 4 per thread)
#pragma unroll
  for (int v = 0; v < 4; ++v) {
    const int n = tid + v * 256;
    F1[n] = fmaxf(dot512(Ts, W1 + (size_t)n * 512) + b1f[n], 0.f);
  }
  __syncthreads();
  // ff2 (K=1024) + residual
  const float4* w2a = (const float4*)(W2 + (size_t)tid * 1024);
  const float4* w2b = (const float4*)(W2 + (size_t)(tid + 256) * 1024);
  float a0 = 0.f, a1 = 0.f;
#pragma unroll 8
  for (int k = 0; k < 256; ++k) {
    const float4 wa = w2a[k], wb = w2b[k];
    const float f0 = F1[4 * k], f1 = F1[4 * k + 1], f2 = F1[4 * k + 2], f3 = F1[4 * k + 3];
    a0 += f0 * wa.x + f1 * wa.y + f2 * wa.z + f3 * wa.w;
    a1 += f0 * wb.x + f1 * wb.y + f2 * wb.z + f3 * wb.w;
  }
  r0 = a0 + b2f[tid] + Ts[tid];
  r1 = a1 + b2f[tid + 256] + Ts[tid + 256];
  __syncthreads();
  float o0, o1;
  BLOCK_LN(r0, r1, g3, b3, o0, o1)
  if (dofinal) {
    float f0, f1;
    BLOCK_LN(o0, o1, gf, bf_, f0, f1)
    o0 = f0; o1 = f1;
  }
  tout[r * 512 + tid] = o0;
  tout[r * 512 + tid + 256] = o1;
}

// ---------------------------------------------------------------------------
// Small fp32 GEMM, M=32 (out1 only now)
template<int RELU>
__global__ __launch_bounds__(256)
void sgemm32(const float* __restrict__ A, const float* __restrict__ W,
             const float* __restrict__ bias, float* __restrict__ C, int N, int K)
{
  const int t = threadIdx.x;
  const int n = t & 63;
  const int mg = __builtin_amdgcn_readfirstlane(t >> 6);
  const int gn = blockIdx.x * 64 + n;
  const size_t wrow = (gn < N) ? (size_t)gn : 0;
  const float4* wp = (const float4*)(W + wrow * K);
  const float* Abase = A + (size_t)mg * 8 * K;
  float acc[8] = {0.f, 0.f, 0.f, 0.f, 0.f, 0.f, 0.f, 0.f};
  const int nk4 = K >> 2;
  for (int k4 = 0; k4 < nk4; ++k4) {
    const float4 wv = wp[k4];
#pragma unroll
    for (int i = 0; i < 8; ++i) {
      const float4 av = *(const float4*)(Abase + (size_t)i * K + k4 * 4);
      acc[i] += av.x * wv.x + av.y * wv.y + av.z * wv.z + av.w * wv.w;
    }
  }
  if (gn < N) {
    const float bb = bias[gn];
#pragma unroll
    for (int i = 0; i < 8; ++i) {
      float v = acc[i] + bb;
      if (RELU) v = fmaxf(v, 0.f);
      C[(size_t)(mg * 8 + i) * N + gn] = v;
    }
  }
}

// ---------------------------------------------------------------------------
__global__ __launch_bounds__(256)
void pool_kernel(const float* __restrict__ o3p, float* __restrict__ out)
{
  const int i = blockIdx.x * 256 + threadIdx.x;
  if (i >= 32 * 135 * 103) return;
  const int j = i % 103;
  const int tmp = i / 103;
  const int r = tmp % 135;
  const int b = tmp / 135;
  const int rs = (r * 143) / 135, re = ((r + 1) * 143 + 134) / 135;
  const int cs = (j * 111) / 103, ce = ((j + 1) * 111 + 102) / 103;
  float s = 0.f;
  for (int rr = rs; rr < re; ++rr)
    for (int cc = cs; cc < ce; ++cc)
      s += o3p[(size_t)b * NOUT3 + rr * 111 + cc];
  out[i] = s / (float)((re - rs) * (ce - cs));
}

// ---------------------------------------------------------------------------
extern "C" void kernel_launch(void* const* d_in, const int* in_sizes, int n_in,
                              void* d_out, int out_size, void* d_ws, size_t ws_size,
                              hipStream_t stream)
{
  (void)in_sizes; (void)n_in; (void)out_size; (void)ws_size;

  const float* x          = (const float*)d_in[0];
  const float* fc1_w      = (const float*)d_in[1];
  const float* fc1_b      = (const float*)d_in[2];
  const float* fc2_w      = (const float*)d_in[3];
  const float* fc2_b      = (const float*)d_in[4];
  const float* fc3_w      = (const float*)d_in[5];
  const float* fc3_b      = (const float*)d_in[6];
  const float* out1_w     = (const float*)d_in[7];
  const float* out1_b     = (const float*)d_in[8];
  const float* out2_w     = (const float*)d_in[9];
  const float* out2_b     = (const float*)d_in[10];
  const float* out3_w     = (const float*)d_in[11];
  const float* out3_b     = (const float*)d_in[12];
  const float* enc_qkv_w  = (const float*)d_in[13];
  const float* enc_qkv_b  = (const float*)d_in[14];
  const float* enc_proj_w = (const float*)d_in[15];
  const float* enc_proj_b = (const float*)d_in[16];
  const float* enc_ff1_w  = (const float*)d_in[17];
  const float* enc_ff1_b  = (const float*)d_in[18];
  const float* enc_ff2_w  = (const float*)d_in[19];
  const float* enc_ff2_b  = (const float*)d_in[20];
  const float* enc_ln1_g  = (const float*)d_in[21];
  const float* enc_ln1_b  = (const float*)d_in[22];
  const float* enc_ln2_g  = (const float*)d_in[23];
  const float* enc_ln2_b  = (const float*)d_in[24];
  const float* enc_lnf_g  = (const float*)d_in[25];
  const float* enc_lnf_b  = (const float*)d_in[26];
  const float* dec_sa_qkv_w  = (const float*)d_in[27];
  const float* dec_sa_qkv_b  = (const float*)d_in[28];
  const float* dec_sa_proj_w = (const float*)d_in[29];
  const float* dec_sa_proj_b = (const float*)d_in[30];
  const float* dec_ca_qkv_w  = (const float*)d_in[31];
  const float* dec_ca_qkv_b  = (const float*)d_in[32];
  const float* dec_ca_proj_w = (const float*)d_in[33];
  const float* dec_ca_proj_b = (const float*)d_in[34];
  const float* dec_ff1_w  = (const float*)d_in[35];
  const float* dec_ff1_b  = (const float*)d_in[36];
  const float* dec_ff2_w  = (const float*)d_in[37];
  const float* dec_ff2_b  = (const float*)d_in[38];
  const float* dec_ln1_g  = (const float*)d_in[39];
  const float* dec_ln1_b  = (const float*)d_in[40];
  const float* dec_ln2_g  = (const float*)d_in[41];
  const float* dec_ln2_b  = (const float*)d_in[42];
  const float* dec_ln3_g  = (const float*)d_in[43];
  const float* dec_ln3_b  = (const float*)d_in[44];
  const float* dec_lnf_g  = (const float*)d_in[45];
  const float* dec_lnf_b  = (const float*)d_in[46];

  char* wsp = (char*)d_ws;
  size_t off = 0;
  auto alloc = [&](size_t nbytes) -> char* {
    char* p = wsp + off;
    off += (nbytes + 255) & ~(size_t)255;
    return p;
  };

  __hip_bfloat16* xb     = (__hip_bfloat16*)alloc((size_t)MPAD * KPAD1 * 2);
  __hip_bfloat16* Wb1    = (__hip_bfloat16*)alloc((size_t)4096 * KPAD1 * 2);
  __hip_bfloat16* Wb2    = (__hip_bfloat16*)alloc((size_t)2048 * 4096 * 2);
  __hip_bfloat16* Wb3    = (__hip_bfloat16*)alloc((size_t)512 * 2048 * 2);
  __hip_bfloat16* Wqkvb  = (__hip_bfloat16*)alloc((size_t)2 * 1536 * 512 * 2);
  __hip_bfloat16* Wprojb = (__hip_bfloat16*)alloc((size_t)2 * 512 * 512 * 2);
  __hip_bfloat16* Wff1b  = (__hip_bfloat16*)alloc((size_t)2 * 1024 * 512 * 2);
  __hip_bfloat16* Wff2b  = (__hip_bfloat16*)alloc((size_t)2 * 512 * 1024 * 2);
  __hip_bfloat16* Wdkvb  = (__hip_bfloat16*)alloc((size_t)2 * 1536 * 512 * 2);
  int*   nz      = (int*)alloc(ROWS * 4);
  int*   padmask = (int*)alloc(ROWS * 4);
  int*   idx     = (int*)alloc(MPAD * 4);
  int*   pos     = (int*)alloc(ROWS * 4);
  int*   cnt     = (int*)alloc(256);
  float* pe      = (float*)alloc((size_t)SEQ * 512 * 4);
  __hip_bfloat16* h1c = (__hip_bfloat16*)alloc((size_t)MPAD * 4096 * 2);
  __hip_bfloat16* h2c = (__hip_bfloat16*)alloc((size_t)MPAD * 2048 * 2);
  float* hf  = (float*)alloc((size_t)ROWS * 512 * 4);
  __hip_bfloat16* hb = (__hip_bfloat16*)alloc((size_t)ROWS * 512 * 2);
  float* qkvbuf = (float*)alloc((size_t)ROWS * 1536 * 4);
  __hip_bfloat16* attnb = (__hip_bfloat16*)alloc((size_t)ROWS * 512 * 2);
  float* pjf  = (float*)alloc((size_t)ROWS * 512 * 4);
  __hip_bfloat16* f1b = (__hip_bfloat16*)alloc((size_t)ROWS * 1024 * 2);
  float* f2f  = (float*)alloc((size_t)ROWS * 512 * 4);
  float* memf = (float*)alloc((size_t)ROWS * 512 * 4);
  __hip_bfloat16* memb = (__hip_bfloat16*)alloc((size_t)ROWS * 512 * 2);
  float* kvbuf = (float*)alloc((size_t)ROWS * 1024 * 4);
  float* tbuf = (float*)alloc(32 * 512 * 4);
  float* qdv  = (float*)alloc(32 * 512 * 4);
  float* cav  = (float*)alloc(32 * 512 * 4);
  float* o1   = (float*)alloc(32 * 2048 * 4);
  float* o3p  = (float*)alloc((size_t)32 * NOUT3 * 4);
  float* biasP = (float*)alloc(NOUT3 * 4);
  // split-K partial buffers (time-shared)
  float* fcP  = (float*)alloc((size_t)4 * MPAD * 4096 * 4);   // 218 MB
  float* encP = (float*)alloc((size_t)2 * ROWS * 1536 * 4);   // 39 MB (now aliases only)

  // phase-4 aliases
  float* outP = fcP;                                                         // <=33 MB
  __hip_bfloat16* Wo3b = (__hip_bfloat16*)((char*)fcP + ((size_t)48 << 20)); // 131 MB
  __hip_bfloat16* Wo2b = (__hip_bfloat16*)encP;                              // 16.8 MB
  __hip_bfloat16* o1b  = (__hip_bfloat16*)((char*)encP + ((size_t)20 << 20));
  __hip_bfloat16* o2b  = (__hip_bfloat16*)((char*)encP + ((size_t)22 << 20));

  const size_t psF1 = (size_t)MPAD * 4096;
  const size_t psF2 = (size_t)MPAD * 2048;
  const size_t psF3 = (size_t)MPAD * 512;

  // ---- phase 0 ----
  conv_x_kernel<<<MPAD, 256, 0, stream>>>(x, xb, nz);
  mask_kernel<<<1, 64, 0, stream>>>(nz, padmask);
  compact_kernel<<<1, 256, 0, stream>>>(nz, idx, pos, cnt);
  pe_kernel<<<(SEQ * 512 + 255) / 256, 256, 0, stream>>>(pe);

  // one dispatch for all unpadded weight conversions (counts % 2048 == 0)
  {
    CvtArgs a;
    const float* srcs[8] = { enc_qkv_w, enc_proj_w, enc_ff1_w, enc_ff2_w,
                             dec_ca_qkv_w, fc2_w, fc3_w, out2_w };
    __hip_bfloat16* dsts[8] = { Wqkvb, Wprojb, Wff1b, Wff2b, Wdkvb, Wb2, Wb3, Wo2b };
    const int counts[8] = { 2*1536*512, 2*512*512, 2*1024*512, 2*512*1024,
                            2*1536*512, 2048*4096, 512*2048, 4096*2048 };
    int c = 0;
    for (int i = 0; i < 8; ++i) { a.src[i] = srcs[i]; a.dst[i] = dsts[i];
                                  a.cum[i] = c; c += counts[i] >> 11; }
    cvt_multi_kernel<<<c, 256, 0, stream>>>(a);
  }
  cvt_pad_kernel<<<dim3(KPAD1 / 512, 4096), 256, 0, stream>>>(fc1_w, Wb1, 4096, FLATIN, KPAD1);

  // ---- phase 1: input MLP (split-K) ----
  gemm_bf16<1><<<26 * 32 * 2, 256, 0, stream>>>(xb, Wb1, idx, cnt, fcP,
      KPAD1, 4096, 26, 2, psF1);
  reduce_kernel<1, 0, 1><<<dim3(4, MPAD), 256, 0, stream>>>(fcP, psF1, 2,
      fc1_b, nullptr, h1c, 4096, cnt);
  gemm_bf16<0><<<26 * 16 * 2, 256, 0, stream>>>(h1c, Wb2, nullptr, cnt, fcP,
      4096, 2048, 26, 2, psF2);
  reduce_kernel<1, 0, 1><<<dim3(2, MPAD), 256, 0, stream>>>(fcP, psF2, 2,
      fc2_b, nullptr, h2c, 2048, cnt);
  gemm_bf16<0><<<26 * 4 * 4, 256, 0, stream>>>(h2c, Wb3, nullptr, cnt, fcP,
      2048, 512, 26, 4, psF3);
  scatter_pe_reduce<<<ROWS, 256, 0, stream>>>(fcP, psF3, 4, pos, fc3_b, pe, hf, hb);

  // ---- phase 2: encoder (direct-epilogue GEMMs) ----
  for (int L = 0; L < 2; ++L) {
    gemm_direct<0, 1, 0><<<25 * 12, 256, 0, stream>>>(hb, Wqkvb + (size_t)L * 1536 * 512,
        enc_qkv_b + L * 1536, qkvbuf, nullptr, 512, 1536, 25);
    enc_attn_kernel<<<dim3(128, 4), 256, 0, stream>>>(qkvbuf, padmask, attnb);
    gemm_direct<0, 1, 0><<<25 * 4, 256, 0, stream>>>(attnb, Wprojb + (size_t)L * 512 * 512,
        enc_proj_b + L * 512, pjf, nullptr, 512, 512, 25);
    ln_kernel<<<ROWS, 256, 0, stream>>>(hf, pjf, enc_ln1_g + L * 512, enc_ln1_b + L * 512, hf, hb);
    gemm_direct<1, 0, 1><<<25 * 8, 256, 0, stream>>>(hb, Wff1b + (size_t)L * 1024 * 512,
        enc_ff1_b + L * 1024, nullptr, f1b, 512, 1024, 25);
    gemm_direct<0, 1, 0><<<25 * 4, 256, 0, stream>>>(f1b, Wff2b + (size_t)L * 512 * 1024,
        enc_ff2_b + L * 512, f2f, nullptr, 1024, 512, 25);
    ln_kernel<<<ROWS, 256, 0, stream>>>(hf, f2f, enc_ln2_g + L * 512, enc_ln2_b + L * 512, hf, hb);
  }
  ln_kernel<<<ROWS, 256, 0, stream>>>(hf, nullptr, enc_lnf_g, enc_lnf_b, memf, memb);

  // ---- phase 3: decoder (fused; Sq=1 self-attn softmax == 1 -> out=V) ----
  fill_kernel<<<(32 * 512 + 255) / 256, 256, 0, stream>>>(tbuf, 32 * 512, 1.0f);
  for (int L = 0; L < 2; ++L) {
    dec_sa_ln_q<<<32, 256, 0, stream>>>(tbuf,
        dec_sa_qkv_w + (size_t)L * 1536 * 512 + (size_t)1024 * 512,
        dec_sa_qkv_b + L * 1536 + 1024,
        dec_sa_proj_w + (size_t)L * 512 * 512, dec_sa_proj_b + L * 512,
        dec_ln1_g + L * 512, dec_ln1_b + L * 512,
        dec_ca_qkv_w + (size_t)L * 1536 * 512, dec_ca_qkv_b + L * 1536,
        tbuf, qdv);
    gemm_direct<0, 1, 0><<<25 * 8, 256, 0, stream>>>(memb,
        Wdkvb + ((size_t)L * 1536 + 512) * 512, dec_ca_qkv_b + L * 1536 + 512,
        kvbuf, nullptr, 512, 1024, 25);
    dec_attn_kernel<<<128, 256, 0, stream>>>(qdv, kvbuf, cav);
    dec_tail<<<32, 256, 0, stream>>>(tbuf, cav,
        dec_ca_proj_w + (size_t)L * 512 * 512, dec_ca_proj_b + L * 512,
        dec_ln2_g + L * 512, dec_ln2_b + L * 512,
        dec_ff1_w + (size_t)L * 1024 * 512, dec_ff1_b + L * 1024,
        dec_ff2_w + (size_t)L * 512 * 1024, dec_ff2_b + L * 512,
        dec_ln3_g + L * 512, dec_ln3_b + L * 512,
        dec_lnf_g, dec_lnf_b, (L == 1) ? 1 : 0, tbuf);
  }

  // ---- phase 4: output MLP ----
  sgemm32<1><<<32, 256, 0, stream>>>(tbuf, out1_w, out1_b, o1, 2048, 512);
  cvt_pad_kernel<<<dim3(4, 128), 256, 0, stream>>>(o1, o1b, 32, 2048, 2048);
  cvt_pad_kernel<<<dim3(8, NOUT3), 256, 0, stream>>>(out3_w, Wo3b, FLATIN, 4096, 4096);
  fill_kernel<<<(NOUT3 + 255) / 256, 256, 0, stream>>>(biasP, NOUT3, 0.f);
  hipMemcpyAsync(biasP, out3_b, (size_t)FLATIN * sizeof(float),
                 hipMemcpyDeviceToDevice, stream);

  gemm_bf16<0><<<32 * 4, 256, 0, stream>>>(o1b, Wo2b, nullptr, nullptr, outP,
      2048, 4096, 1, 4, (size_t)128 * 4096);
  reduce_kernel<1, 0, 1><<<dim3(4, 128), 256, 0, stream>>>(outP, (size_t)128 * 4096, 4,
      out2_b, nullptr, o2b, 4096, nullptr);
  gemm_bf16<0><<<125 * 4, 256, 0, stream>>>(o2b, Wo3b, nullptr, nullptr, outP,
      4096, NOUT3, 1, 4, (size_t)128 * NOUT3);
  reduce_kernel<1, 1, 0><<<dim3(16, 32), 256, 0, stream>>>(outP, (size_t)128 * NOUT3, 4,
      biasP, o3p, nullptr, NOUT3, nullptr);

  pool_kernel<<<(32 * 135 * 103 + 255) / 256, 256, 0, stream>>>(o3p, (float*)d_out);
}